// Round 3
// baseline (2390.998 us; speedup 1.0000x reference)
//
#include <hip/hip_runtime.h>
#include <math.h>

// Problem constants
constexpr int Bc = 4;
constexpr int Sq = 2048;
constexpr int Dm = 512;     // model dim
constexpr int Mrows = Bc * Sq;   // 8192
constexpr int DH = 64;      // head dim
// heads: 8 global, 8 local, window 2

// ---------------------------------------------------------------------------
// LayerNorm (optionally fused residual add): out = LN(in [+ add]) * g + b
// one block (128 threads) per row of 512 floats (float4 per thread)
// ---------------------------------------------------------------------------
__global__ __launch_bounds__(128) void ln_kernel(
    const float* __restrict__ in, const float* __restrict__ add,
    const float* __restrict__ g, const float* __restrict__ b,
    float* __restrict__ out) {
  const int row = blockIdx.x;
  const int t = threadIdx.x;
  float4 v = reinterpret_cast<const float4*>(in + (size_t)row * Dm)[t];
  if (add != nullptr) {
    float4 a = reinterpret_cast<const float4*>(add + (size_t)row * Dm)[t];
    v.x += a.x; v.y += a.y; v.z += a.z; v.w += a.w;
  }
  float s  = v.x + v.y + v.z + v.w;
  float s2 = v.x*v.x + v.y*v.y + v.z*v.z + v.w*v.w;
  #pragma unroll
  for (int o = 32; o > 0; o >>= 1) {
    s  += __shfl_down(s, o);
    s2 += __shfl_down(s2, o);
  }
  __shared__ float rs[2], rs2[2];
  if ((t & 63) == 0) { rs[t >> 6] = s; rs2[t >> 6] = s2; }
  __syncthreads();
  const float mean = (rs[0] + rs[1]) * (1.0f / Dm);
  const float var  = (rs2[0] + rs2[1]) * (1.0f / Dm) - mean * mean;
  const float rstd = rsqrtf(var + 1e-5f);
  float4 gv = reinterpret_cast<const float4*>(g)[t];
  float4 bv = reinterpret_cast<const float4*>(b)[t];
  float4 o;
  o.x = (v.x - mean) * rstd * gv.x + bv.x;
  o.y = (v.y - mean) * rstd * gv.y + bv.y;
  o.z = (v.z - mean) * rstd * gv.z + bv.z;
  o.w = (v.w - mean) * rstd * gv.w + bv.w;
  reinterpret_cast<float4*>(out + (size_t)row * Dm)[t] = o;
}

// ---------------------------------------------------------------------------
// GEMM: C[M,N] = act(A[M,K] @ W[N,K]^T + bias[N])
// ACT: 0=none, 1=sigmoid, 2=exact gelu
// 64x64 output tile per 256-thread block, K-step 16, 4x4 per thread.
// Requires M%64==0, N%64==0, K%16==0 (always true here).
// ---------------------------------------------------------------------------
template <int ACT>
__global__ __launch_bounds__(256) void gemm_kernel(
    const float* __restrict__ A, const float* __restrict__ W,
    const float* __restrict__ bias, float* __restrict__ C, int N, int K) {
  __shared__ float sA[16][65];
  __shared__ float sW[16][65];
  const int tid = threadIdx.x;
  const int tx = tid & 15, ty = tid >> 4;
  const int m0 = blockIdx.y * 64, n0 = blockIdx.x * 64;
  const int lr = tid >> 2;          // 0..63 row within tile
  const int lc = (tid & 3) * 4;     // 0,4,8,12 k-offset
  float acc[4][4] = {};
  for (int k0 = 0; k0 < K; k0 += 16) {
    __syncthreads();
    float4 av = *reinterpret_cast<const float4*>(A + (size_t)(m0 + lr) * K + k0 + lc);
    float4 wv = *reinterpret_cast<const float4*>(W + (size_t)(n0 + lr) * K + k0 + lc);
    sA[lc+0][lr] = av.x; sA[lc+1][lr] = av.y; sA[lc+2][lr] = av.z; sA[lc+3][lr] = av.w;
    sW[lc+0][lr] = wv.x; sW[lc+1][lr] = wv.y; sW[lc+2][lr] = wv.z; sW[lc+3][lr] = wv.w;
    __syncthreads();
    #pragma unroll
    for (int kk = 0; kk < 16; ++kk) {
      float a[4], w[4];
      #pragma unroll
      for (int i = 0; i < 4; ++i) a[i] = sA[kk][ty*4 + i];
      #pragma unroll
      for (int j = 0; j < 4; ++j) w[j] = sW[kk][tx*4 + j];
      #pragma unroll
      for (int i = 0; i < 4; ++i)
        #pragma unroll
        for (int j = 0; j < 4; ++j)
          acc[i][j] = fmaf(a[i], w[j], acc[i][j]);
    }
  }
  #pragma unroll
  for (int i = 0; i < 4; ++i) {
    const int m = m0 + ty*4 + i;
    #pragma unroll
    for (int j = 0; j < 4; ++j) {
      const int n = n0 + tx*4 + j;
      float v = acc[i][j] + bias[n];
      if (ACT == 1) v = 1.0f / (1.0f + expf(-v));
      else if (ACT == 2) v = 0.5f * v * (1.0f + erff(v * 0.70710678118654752440f));
      C[(size_t)m * N + n] = v;
    }
  }
}

// ---------------------------------------------------------------------------
// Global causal attention over qkv [Mrows][1536] (q|k|v each 512, head h at
// cols h*64). One block per (b, h, 16-row q-tile). Flash-style online softmax.
// Thread (r=tid>>4, c=tid&15): owns q-row r, key lanes {c,c+16,c+32,c+48},
// output dims {c,c+16,c+32,c+48}.
// ---------------------------------------------------------------------------
__global__ __launch_bounds__(256) void attn_global_kernel(
    const float* __restrict__ qkv, float* __restrict__ out) {
  const int qt = blockIdx.x;   // q tile: 0..127
  const int h  = blockIdx.y;   // head
  const int b  = blockIdx.z;   // batch
  const int tid = threadIdx.x;
  const int r = tid >> 4, c = tid & 15;
  __shared__ float Qs[16][64];
  __shared__ float Ks[64][65];
  __shared__ float Vs[64][65];
  __shared__ float Ps[16][65];

  const size_t bbase = (size_t)b * Sq;
  {  // load Q tile (16x64)
    const int qr = tid >> 4, qc = (tid & 15) * 4;
    float4 qv = *reinterpret_cast<const float4*>(
        qkv + (bbase + qt*16 + qr) * 1536 + h*64 + qc);
    Qs[qr][qc+0] = qv.x; Qs[qr][qc+1] = qv.y; Qs[qr][qc+2] = qv.z; Qs[qr][qc+3] = qv.w;
  }
  float m = -INFINITY, l = 0.0f;
  float acc[4] = {0.f, 0.f, 0.f, 0.f};
  const int qp = qt*16 + r;
  const int ntiles = (qt*16 + 15) / 64 + 1;
  const int krow = tid >> 2;         // 0..63
  const int kcb  = (tid & 3) * 16;   // 0,16,32,48
  for (int kt = 0; kt < ntiles; ++kt) {
    __syncthreads();  // prev iter's reads of Ks/Vs (and Qs stores) done
    {  // load K/V tile (64x64 each)
      const float* kb = qkv + (bbase + kt*64 + krow) * 1536 + h*64 + kcb;
      #pragma unroll
      for (int q = 0; q < 4; ++q) {
        float4 kv = *reinterpret_cast<const float4*>(kb + 512  + q*4);
        float4 vv = *reinterpret_cast<const float4*>(kb + 1024 + q*4);
        Ks[krow][kcb+q*4+0] = kv.x; Ks[krow][kcb+q*4+1] = kv.y;
        Ks[krow][kcb+q*4+2] = kv.z; Ks[krow][kcb+q*4+3] = kv.w;
        Vs[krow][kcb+q*4+0] = vv.x; Vs[krow][kcb+q*4+1] = vv.y;
        Vs[krow][kcb+q*4+2] = vv.z; Vs[krow][kcb+q*4+3] = vv.w;
      }
    }
    __syncthreads();
    float s[4];
    #pragma unroll
    for (int t4 = 0; t4 < 4; ++t4) {
      const int kloc = c + 16*t4;
      float sum = 0.0f;
      #pragma unroll
      for (int d = 0; d < 64; ++d) sum = fmaf(Qs[r][d], Ks[kloc][d], sum);
      const int kp = kt*64 + kloc;
      s[t4] = (kp <= qp) ? sum * 0.125f : -INFINITY;
    }
    float tm = fmaxf(fmaxf(s[0], s[1]), fmaxf(s[2], s[3]));
    #pragma unroll
    for (int o = 1; o < 16; o <<= 1) tm = fmaxf(tm, __shfl_xor(tm, o));
    const float mnew = fmaxf(m, tm);          // finite: first tile always has key 0
    const float corr = expf(m - mnew);        // m=-inf -> 0 on first tile
    float p[4], psum = 0.0f;
    #pragma unroll
    for (int t4 = 0; t4 < 4; ++t4) { p[t4] = expf(s[t4] - mnew); psum += p[t4]; }
    #pragma unroll
    for (int o = 1; o < 16; o <<= 1) psum += __shfl_xor(psum, o);
    l = l * corr + psum;
    #pragma unroll
    for (int q = 0; q < 4; ++q) acc[q] *= corr;
    Ps[r][c] = p[0]; Ps[r][c+16] = p[1]; Ps[r][c+32] = p[2]; Ps[r][c+48] = p[3];
    m = mnew;
    __syncthreads();  // Ps visible to all of row's threads; Vs stable
    #pragma unroll 8
    for (int kk = 0; kk < 64; ++kk) {
      const float pv = Ps[r][kk];
      #pragma unroll
      for (int q = 0; q < 4; ++q) acc[q] = fmaf(pv, Vs[kk][c + 16*q], acc[q]);
    }
  }
  const float invl = 1.0f / l;
  #pragma unroll
  for (int q = 0; q < 4; ++q)
    out[(bbase + qt*16 + r) * Dm + h*64 + c + 16*q] = acc[q] * invl;
}

// ---------------------------------------------------------------------------
// Local window-2 attention: one wave per (pair, head). No mask (full 2x2).
// ---------------------------------------------------------------------------
__global__ __launch_bounds__(256) void attn_local_kernel(
    const float* __restrict__ qkv, float* __restrict__ out) {
  const int unit = blockIdx.x * 4 + (threadIdx.x >> 6);  // (pair<<3)|h
  const int lane = threadIdx.x & 63;
  const int h = unit & 7;
  const size_t pair = (size_t)(unit >> 3);
  const float* r0 = qkv + pair * 2 * 1536;
  const float* r1 = r0 + 1536;
  const int off = h*64 + lane;
  const float q0 = r0[off], k0 = r0[512+off], v0 = r0[1024+off];
  const float q1 = r1[off], k1 = r1[512+off], v1 = r1[1024+off];
  float s00 = q0*k0, s01 = q0*k1, s10 = q1*k0, s11 = q1*k1;
  #pragma unroll
  for (int o = 1; o < 64; o <<= 1) {
    s00 += __shfl_xor(s00, o); s01 += __shfl_xor(s01, o);
    s10 += __shfl_xor(s10, o); s11 += __shfl_xor(s11, o);
  }
  s00 *= 0.125f; s01 *= 0.125f; s10 *= 0.125f; s11 *= 0.125f;
  const float m0 = fmaxf(s00, s01), m1 = fmaxf(s10, s11);
  const float e00 = expf(s00 - m0), e01 = expf(s01 - m0);
  const float e10 = expf(s10 - m1), e11 = expf(s11 - m1);
  const float w0 = 1.0f / (e00 + e01), w1 = 1.0f / (e10 + e11);
  out[pair*2*Dm + off]        = (e00*v0 + e01*v1) * w0;
  out[(pair*2 + 1)*Dm + off]  = (e10*v0 + e11*v1) * w1;
}

// ---------------------------------------------------------------------------
// x2 = x + gate*pg + (1-gate)*pl   (elementwise, float4)
// ---------------------------------------------------------------------------
__global__ __launch_bounds__(256) void combine_kernel(
    const float* __restrict__ x, const float* __restrict__ g,
    const float* __restrict__ pg, const float* __restrict__ pl,
    float* __restrict__ x2) {
  const int i = blockIdx.x * blockDim.x + threadIdx.x;  // float4 index
  float4 xv = reinterpret_cast<const float4*>(x)[i];
  float4 gv = reinterpret_cast<const float4*>(g)[i];
  float4 av = reinterpret_cast<const float4*>(pg)[i];
  float4 bv = reinterpret_cast<const float4*>(pl)[i];
  float4 o;
  o.x = xv.x + gv.x*av.x + (1.0f-gv.x)*bv.x;
  o.y = xv.y + gv.y*av.y + (1.0f-gv.y)*bv.y;
  o.z = xv.z + gv.z*av.z + (1.0f-gv.z)*bv.z;
  o.w = xv.w + gv.w*av.w + (1.0f-gv.w)*bv.w;
  reinterpret_cast<float4*>(x2)[i] = o;
}

// ---------------------------------------------------------------------------
extern "C" void kernel_launch(void* const* d_in, const int* in_sizes, int n_in,
                              void* d_out, int out_size, void* d_ws, size_t ws_size,
                              hipStream_t stream) {
  const float* x      = (const float*)d_in[0];
  const float* ln1_g  = (const float*)d_in[1];
  const float* ln1_b  = (const float*)d_in[2];
  const float* ln2_g  = (const float*)d_in[3];
  const float* ln2_b  = (const float*)d_in[4];
  const float* ln3_g  = (const float*)d_in[5];
  const float* ln3_b  = (const float*)d_in[6];
  const float* gw_in  = (const float*)d_in[7];
  const float* gb_in  = (const float*)d_in[8];
  const float* gw_out = (const float*)d_in[9];
  const float* gb_out = (const float*)d_in[10];
  const float* lw_in  = (const float*)d_in[11];
  const float* lb_in  = (const float*)d_in[12];
  const float* lw_out = (const float*)d_in[13];
  const float* lb_out = (const float*)d_in[14];
  const float* gate_w = (const float*)d_in[15];
  const float* gate_b = (const float*)d_in[16];
  const float* ff_w1  = (const float*)d_in[17];
  const float* ff_b1  = (const float*)d_in[18];
  const float* ff_w2  = (const float*)d_in[19];
  const float* ff_b2  = (const float*)d_in[20];
  float* out = (float*)d_out;
  float* ws  = (float*)d_ws;

  const size_t MD = (size_t)Mrows * Dm;  // 4,194,304 floats
  // workspace layout (8*MD floats = 134.2 MB total)
  float* xn   = ws;            // A: x_norm, later h_norm
  float* gate = ws + MD;       // B
  float* attg = ws + 2*MD;     // C: global attn out, later h2 (FFN out)
  float* attl = ws + 3*MD;     // D: local attn out, later x2
  float* big  = ws + 4*MD;     // E: 4*MD (qkv 3*MD; later pg|pl; later ff1 4*MD)
  float* qkv  = big;
  float* pg   = big;
  float* pl   = big + MD;
  float* ff1  = big;
  float* x2   = attl;
  float* h2   = attg;

  // 1. x_norm = LN1(x)
  ln_kernel<<<Mrows, 128, 0, stream>>>(x, nullptr, ln1_g, ln1_b, xn);
  // 2. local qkv = x_norm @ lw_in^T + lb_in
  gemm_kernel<0><<<dim3(1536/64, Mrows/64), 256, 0, stream>>>(xn, lw_in, lb_in, qkv, 1536, 512);
  // 3. local window-2 attention
  attn_local_kernel<<<(Mrows/2) * 8 / 4, 256, 0, stream>>>(qkv, attl);
  // 4. global qkv (overwrites local qkv)
  gemm_kernel<0><<<dim3(1536/64, Mrows/64), 256, 0, stream>>>(xn, gw_in, gb_in, qkv, 1536, 512);
  // 5. global causal attention
  attn_global_kernel<<<dim3(Sq/16, 8, Bc), 256, 0, stream>>>(qkv, attg);
  // 6. gate = sigmoid(x_norm @ gate_w^T + gate_b)
  gemm_kernel<1><<<dim3(512/64, Mrows/64), 256, 0, stream>>>(xn, gate_w, gate_b, gate, 512, 512);
  // 7. pg = attn_g @ gw_out^T + gb_out
  gemm_kernel<0><<<dim3(512/64, Mrows/64), 256, 0, stream>>>(attg, gw_out, gb_out, pg, 512, 512);
  // 8. pl = attn_l @ lw_out^T + lb_out
  gemm_kernel<0><<<dim3(512/64, Mrows/64), 256, 0, stream>>>(attl, lw_out, lb_out, pl, 512, 512);
  // 9. x2 = x + gate*pg + (1-gate)*pl   (writes over attl, which is now dead)
  combine_kernel<<<(Mrows*Dm/4) / 256, 256, 0, stream>>>(x, gate, pg, pl, x2);
  // 10. h_norm = LN2(x2)
  ln_kernel<<<Mrows, 128, 0, stream>>>(x2, nullptr, ln2_g, ln2_b, xn);
  // 11. ff1 = gelu(h_norm @ ff_w1^T + ff_b1)
  gemm_kernel<2><<<dim3(2048/64, Mrows/64), 256, 0, stream>>>(xn, ff_w1, ff_b1, ff1, 2048, 512);
  // 12. h2 = ff1 @ ff_w2^T + ff_b2   (writes over attg, now dead)
  gemm_kernel<0><<<dim3(512/64, Mrows/64), 256, 0, stream>>>(ff1, ff_w2, ff_b2, h2, 512, 2048);
  // 13. out = LN3(x2 + h2)
  ln_kernel<<<Mrows, 128, 0, stream>>>(x2, h2, ln3_g, ln3_b, out);
}

// Round 5
// 803.377 us; speedup vs baseline: 2.9762x; 2.9762x over previous
//
#include <hip/hip_runtime.h>
#include <math.h>
#include <stdint.h>

typedef unsigned short u16;
typedef __attribute__((ext_vector_type(4))) unsigned short u16x4;
typedef __attribute__((ext_vector_type(8))) unsigned short u16x8;
typedef __attribute__((ext_vector_type(8))) short s16x8;   // 8 bf16 = 4 VGPR (MFMA frag)
typedef __attribute__((ext_vector_type(4))) float f32x4;   // MFMA acc

// Problem constants
constexpr int Bc = 4;
constexpr int Sq = 2048;
constexpr int Dm = 512;
constexpr int Mrows = Bc * Sq;   // 8192

__device__ inline float b2f(u16 h) {
  union { uint32_t u; float f; } x; x.u = (uint32_t)h << 16; return x.f;
}
__device__ inline u16 f2bf(float f) {  // round-to-nearest-even
  union { float f; uint32_t u; } x; x.f = f;
  uint32_t r = (x.u + 0x7fffu + ((x.u >> 16) & 1u)) >> 16;
  return (u16)r;
}

// ---------------------------------------------------------------------------
// Weight fp32->bf16 conversion, all 7 weights in one kernel (compile-time map)
// ---------------------------------------------------------------------------
constexpr size_t W_GWIN  = 0;         // 1536x512
constexpr size_t W_LWIN  = 786432;    // 1536x512
constexpr size_t W_GWOUT = 1572864;   // 512x512
constexpr size_t W_LWOUT = 1835008;   // 512x512
constexpr size_t W_GATE  = 2097152;   // 512x512
constexpr size_t W_FF1   = 2359296;   // 2048x512
constexpr size_t W_FF2   = 3407872;   // 512x2048
constexpr size_t W_TOTAL = 4456448;

__global__ __launch_bounds__(256) void wconv_kernel(
    const float* __restrict__ gw_in, const float* __restrict__ lw_in,
    const float* __restrict__ gw_out, const float* __restrict__ lw_out,
    const float* __restrict__ gate_w, const float* __restrict__ ff_w1,
    const float* __restrict__ ff_w2, u16* __restrict__ dst) {
  size_t idx = ((size_t)blockIdx.x * 256 + threadIdx.x) * 4;
  if (idx >= W_TOTAL) return;
  const float* src; size_t base;
  if      (idx < W_LWIN)  { src = gw_in;  base = W_GWIN;  }
  else if (idx < W_GWOUT) { src = lw_in;  base = W_LWIN;  }
  else if (idx < W_LWOUT) { src = gw_out; base = W_GWOUT; }
  else if (idx < W_GATE)  { src = lw_out; base = W_LWOUT; }
  else if (idx < W_FF1)   { src = gate_w; base = W_GATE;  }
  else if (idx < W_FF2)   { src = ff_w1;  base = W_FF1;   }
  else                    { src = ff_w2;  base = W_FF2;   }
  float4 v = *reinterpret_cast<const float4*>(src + (idx - base));
  u16x4 o = { f2bf(v.x), f2bf(v.y), f2bf(v.z), f2bf(v.w) };
  *reinterpret_cast<u16x4*>(dst + idx) = o;
}

// ---------------------------------------------------------------------------
// LayerNorm (optional fused residual add). OB: write bf16 (else fp32).
// one block (128 threads) per row of 512 floats
// ---------------------------------------------------------------------------
template <bool OB>
__global__ __launch_bounds__(128) void ln_kernel(
    const float* __restrict__ in, const float* __restrict__ add,
    const float* __restrict__ g, const float* __restrict__ b,
    void* __restrict__ outp) {
  const int row = blockIdx.x;
  const int t = threadIdx.x;
  float4 v = reinterpret_cast<const float4*>(in + (size_t)row * Dm)[t];
  if (add != nullptr) {
    float4 a = reinterpret_cast<const float4*>(add + (size_t)row * Dm)[t];
    v.x += a.x; v.y += a.y; v.z += a.z; v.w += a.w;
  }
  float s  = v.x + v.y + v.z + v.w;
  float s2 = v.x*v.x + v.y*v.y + v.z*v.z + v.w*v.w;
  #pragma unroll
  for (int o = 32; o > 0; o >>= 1) {
    s  += __shfl_down(s, o);
    s2 += __shfl_down(s2, o);
  }
  __shared__ float rs[2], rs2[2];
  if ((t & 63) == 0) { rs[t >> 6] = s; rs2[t >> 6] = s2; }
  __syncthreads();
  const float mean = (rs[0] + rs[1]) * (1.0f / Dm);
  const float var  = (rs2[0] + rs2[1]) * (1.0f / Dm) - mean * mean;
  const float rstd = rsqrtf(var + 1e-5f);
  float4 gv = reinterpret_cast<const float4*>(g)[t];
  float4 bv = reinterpret_cast<const float4*>(b)[t];
  float ox = (v.x - mean) * rstd * gv.x + bv.x;
  float oy = (v.y - mean) * rstd * gv.y + bv.y;
  float oz = (v.z - mean) * rstd * gv.z + bv.z;
  float ow = (v.w - mean) * rstd * gv.w + bv.w;
  if (OB) {
    u16x4 o4 = { f2bf(ox), f2bf(oy), f2bf(oz), f2bf(ow) };
    *reinterpret_cast<u16x4*>((u16*)outp + (size_t)row * Dm + t * 4) = o4;
  } else {
    float4 o4; o4.x = ox; o4.y = oy; o4.z = oz; o4.w = ow;
    reinterpret_cast<float4*>((float*)outp + (size_t)row * Dm)[t] = o4;
  }
}

// ---------------------------------------------------------------------------
// MFMA GEMM: C[M,N] = act(A[M,K](bf16) @ W[N,K](bf16)^T + bias[N](f32))
// 128x128 block tile, 4 waves (2x2) of 64x64, BK=32, mfma_f32_16x16x32_bf16.
// Staging via global_load_lds width 16 (m97 structure, 2 barriers per K step).
// A/B frag: lane&15 = row(col), k = (lane>>4)*8 + e.
// D frag:   col = lane&15, row = (lane>>4)*4 + reg  [m89-verified]
// ACT: 0=none 1=sigmoid 2=exact-gelu.  OUT_BF16: store bf16 else fp32.
// Requires M%128==0, N%128==0, K%32==0 (true for all calls).
// ---------------------------------------------------------------------------
template <int ACT, bool OUT_BF16>
__global__ __launch_bounds__(256) void mfma_gemm(
    const u16* __restrict__ A, const u16* __restrict__ W,
    const float* __restrict__ bias, void* __restrict__ Cout, int N, int K) {
  __shared__ u16 sA[128 * 32];
  __shared__ u16 sW[128 * 32];
  const int tid  = threadIdx.x;
  const int wid  = tid >> 6, lane = tid & 63;
  const int lr   = lane & 15, kh = lane >> 4;
  const int wm   = wid >> 1, wn = wid & 1;
  const int m0   = blockIdx.y * 128, n0 = blockIdx.x * 128;
  // staging chunk mapping: chunk ci (16B) -> row ci>>2, k-offset (ci&3)*8
  const int row0 = tid >> 2,        ko0 = (tid & 3) * 8;
  const int row1 = (256 + tid) >> 2, ko1 = (tid & 3) * 8;  // rows 64..127

  f32x4 acc[4][4] = {};
  for (int k0 = 0; k0 < K; k0 += 32) {
    __syncthreads();  // previous tile's reads done before overwrite
    __builtin_amdgcn_global_load_lds(
        (const __attribute__((address_space(1))) void*)(A + (size_t)(m0 + row0) * K + k0 + ko0),
        (__attribute__((address_space(3))) void*)(sA + wid * 512), 16, 0, 0);
    __builtin_amdgcn_global_load_lds(
        (const __attribute__((address_space(1))) void*)(A + (size_t)(m0 + row1) * K + k0 + ko1),
        (__attribute__((address_space(3))) void*)(sA + 2048 + wid * 512), 16, 0, 0);
    __builtin_amdgcn_global_load_lds(
        (const __attribute__((address_space(1))) void*)(W + (size_t)(n0 + row0) * K + k0 + ko0),
        (__attribute__((address_space(3))) void*)(sW + wid * 512), 16, 0, 0);
    __builtin_amdgcn_global_load_lds(
        (const __attribute__((address_space(1))) void*)(W + (size_t)(n0 + row1) * K + k0 + ko1),
        (__attribute__((address_space(3))) void*)(sW + 2048 + wid * 512), 16, 0, 0);
    __syncthreads();  // drains vmcnt(0); staged data visible
    s16x8 af[4], bf[4];
    #pragma unroll
    for (int mf = 0; mf < 4; ++mf)
      af[mf] = *reinterpret_cast<const s16x8*>(&sA[(wm * 64 + mf * 16 + lr) * 32 + kh * 8]);
    #pragma unroll
    for (int nf = 0; nf < 4; ++nf)
      bf[nf] = *reinterpret_cast<const s16x8*>(&sW[(wn * 64 + nf * 16 + lr) * 32 + kh * 8]);
    #pragma unroll
    for (int mf = 0; mf < 4; ++mf)
      #pragma unroll
      for (int nf = 0; nf < 4; ++nf)
        acc[mf][nf] = __builtin_amdgcn_mfma_f32_16x16x32_bf16(af[mf], bf[nf], acc[mf][nf], 0, 0, 0);
  }
  // epilogue
  #pragma unroll
  for (int nf = 0; nf < 4; ++nf) {
    const int col = n0 + wn * 64 + nf * 16 + lr;
    const float bv = bias[col];
    #pragma unroll
    for (int mf = 0; mf < 4; ++mf) {
      #pragma unroll
      for (int j = 0; j < 4; ++j) {
        const int rowg = m0 + wm * 64 + mf * 16 + kh * 4 + j;
        float v = acc[mf][nf][j] + bv;
        if (ACT == 1) v = 1.0f / (1.0f + expf(-v));
        else if (ACT == 2) v = 0.5f * v * (1.0f + erff(v * 0.70710678118654752440f));
        if (OUT_BF16) ((u16*)Cout)[(size_t)rowg * N + col] = f2bf(v);
        else          ((float*)Cout)[(size_t)rowg * N + col] = v;
      }
    }
  }
}

// ---------------------------------------------------------------------------
// Global causal attention. qkv bf16 [Mrows][1536] (q|k|v, head h at cols h*64).
// One block per (b,h,16-row q-tile). fp32 flash softmax, LDS all b128.
// Thread (r=tid>>4, c=tid&15): q-row r, key lanes {c,c+16,c+32,c+48},
// output cols {4c..4c+3} (consecutive -> float4 V reads, ushort4 store).
// LDS rows padded to 68 floats (272B = 17*16B: b128-aligned, odd bank stride).
// ---------------------------------------------------------------------------
__global__ __launch_bounds__(256) void attn_global_kernel(
    const u16* __restrict__ qkv, u16* __restrict__ outb) {
  const int qt = blockIdx.x;
  const int h  = blockIdx.y;
  const int b  = blockIdx.z;
  const int tid = threadIdx.x;
  const int r = tid >> 4, c = tid & 15;
  __shared__ float Qs[16][68];
  __shared__ float Ks[64][68];
  __shared__ float Vs[64][68];
  __shared__ float Ps[16][68];

  const size_t bbase = (size_t)b * Sq;
  if (tid < 128) {  // load Q tile 16x64
    const int qr = tid >> 3, qc8 = (tid & 7) * 8;
    u16x8 qv = *reinterpret_cast<const u16x8*>(
        qkv + (bbase + qt * 16 + qr) * 1536 + h * 64 + qc8);
    #pragma unroll
    for (int j = 0; j < 8; ++j) Qs[qr][qc8 + j] = b2f(qv[j]);
  }
  float m = -INFINITY, l = 0.0f;
  float ax = 0.f, ay = 0.f, az = 0.f, aw = 0.f;
  const int qp = qt * 16 + r;
  const int ntiles = (qt * 16 + 15) / 64 + 1;
  const int krow = tid >> 2;        // 0..63
  const int kcb  = (tid & 3) * 16;  // 0,16,32,48
  for (int kt = 0; kt < ntiles; ++kt) {
    __syncthreads();  // prev tile's reads (and Qs store) done
    {  // stage K/V 64x64 (bf16 -> fp32)
      const u16* kb = qkv + (bbase + kt * 64 + krow) * 1536 + h * 64;
      #pragma unroll
      for (int ch = 0; ch < 2; ++ch) {
        const int c0 = kcb + ch * 8;
        u16x8 kv = *reinterpret_cast<const u16x8*>(kb + 512 + c0);
        u16x8 vv = *reinterpret_cast<const u16x8*>(kb + 1024 + c0);
        #pragma unroll
        for (int j = 0; j < 8; ++j) {
          Ks[krow][c0 + j] = b2f(kv[j]);
          Vs[krow][c0 + j] = b2f(vv[j]);
        }
      }
    }
    __syncthreads();
    // QK^T: 4 key lanes per thread, float4 along d
    float s0 = 0.f, s1 = 0.f, s2 = 0.f, s3 = 0.f;
    #pragma unroll
    for (int d4 = 0; d4 < 16; ++d4) {
      float4 q  = *reinterpret_cast<const float4*>(&Qs[r][d4 * 4]);
      float4 k0 = *reinterpret_cast<const float4*>(&Ks[c][d4 * 4]);
      float4 k1 = *reinterpret_cast<const float4*>(&Ks[c + 16][d4 * 4]);
      float4 k2 = *reinterpret_cast<const float4*>(&Ks[c + 32][d4 * 4]);
      float4 k3 = *reinterpret_cast<const float4*>(&Ks[c + 48][d4 * 4]);
      s0 = fmaf(q.x, k0.x, fmaf(q.y, k0.y, fmaf(q.z, k0.z, fmaf(q.w, k0.w, s0))));
      s1 = fmaf(q.x, k1.x, fmaf(q.y, k1.y, fmaf(q.z, k1.z, fmaf(q.w, k1.w, s1))));
      s2 = fmaf(q.x, k2.x, fmaf(q.y, k2.y, fmaf(q.z, k2.z, fmaf(q.w, k2.w, s2))));
      s3 = fmaf(q.x, k3.x, fmaf(q.y, k3.y, fmaf(q.z, k3.z, fmaf(q.w, k3.w, s3))));
    }
    float s[4] = { s0, s1, s2, s3 };
    #pragma unroll
    for (int t4 = 0; t4 < 4; ++t4) {
      const int kp = kt * 64 + c + 16 * t4;
      s[t4] = (kp <= qp) ? s[t4] * 0.125f : -INFINITY;
    }
    float tm = fmaxf(fmaxf(s[0], s[1]), fmaxf(s[2], s[3]));
    #pragma unroll
    for (int o = 1; o < 16; o <<= 1) tm = fmaxf(tm, __shfl_xor(tm, o));
    const float mnew = fmaxf(m, tm);     // finite after first tile (key 0 unmasked)
    const float corr = expf(m - mnew);   // m=-inf -> 0 on first tile
    float p[4], psum = 0.0f;
    #pragma unroll
    for (int t4 = 0; t4 < 4; ++t4) { p[t4] = expf(s[t4] - mnew); psum += p[t4]; }
    #pragma unroll
    for (int o = 1; o < 16; o <<= 1) psum += __shfl_xor(psum, o);
    l = l * corr + psum;
    ax *= corr; ay *= corr; az *= corr; aw *= corr;
    Ps[r][c] = p[0]; Ps[r][c + 16] = p[1]; Ps[r][c + 32] = p[2]; Ps[r][c + 48] = p[3];
    m = mnew;
    // no barrier: Ps row r is written & read by the same wave (lockstep wave64);
    // Vs is stable since the post-staging barrier.
    #pragma unroll 4
    for (int k4 = 0; k4 < 16; ++k4) {
      float4 p4 = *reinterpret_cast<const float4*>(&Ps[r][k4 * 4]);
      const float pj[4] = { p4.x, p4.y, p4.z, p4.w };
      #pragma unroll
      for (int j = 0; j < 4; ++j) {
        float4 vv = *reinterpret_cast<const float4*>(&Vs[k4 * 4 + j][c * 4]);
        ax = fmaf(pj[j], vv.x, ax);
        ay = fmaf(pj[j], vv.y, ay);
        az = fmaf(pj[j], vv.z, az);
        aw = fmaf(pj[j], vv.w, aw);
      }
    }
  }
  const float invl = 1.0f / l;
  u16x4 o4 = { f2bf(ax * invl), f2bf(ay * invl), f2bf(az * invl), f2bf(aw * invl) };
  *reinterpret_cast<u16x4*>(outb + (bbase + qt * 16 + r) * Dm + h * 64 + 4 * c) = o4;
}

// ---------------------------------------------------------------------------
// Local window-2 attention (bf16 in/out): one wave per (pair, head).
// ---------------------------------------------------------------------------
__global__ __launch_bounds__(256) void attn_local_kernel(
    const u16* __restrict__ qkv, u16* __restrict__ outb) {
  const int unit = blockIdx.x * 4 + (threadIdx.x >> 6);  // (pair<<3)|h
  const int lane = threadIdx.x & 63;
  const int h = unit & 7;
  const size_t pair = (size_t)(unit >> 3);
  const u16* r0 = qkv + pair * 2 * 1536;
  const u16* r1 = r0 + 1536;
  const int off = h * 64 + lane;
  const float q0 = b2f(r0[off]), k0 = b2f(r0[512 + off]), v0 = b2f(r0[1024 + off]);
  const float q1 = b2f(r1[off]), k1 = b2f(r1[512 + off]), v1 = b2f(r1[1024 + off]);
  float s00 = q0 * k0, s01 = q0 * k1, s10 = q1 * k0, s11 = q1 * k1;
  #pragma unroll
  for (int o = 1; o < 64; o <<= 1) {
    s00 += __shfl_xor(s00, o); s01 += __shfl_xor(s01, o);
    s10 += __shfl_xor(s10, o); s11 += __shfl_xor(s11, o);
  }
  s00 *= 0.125f; s01 *= 0.125f; s10 *= 0.125f; s11 *= 0.125f;
  const float m0 = fmaxf(s00, s01), m1 = fmaxf(s10, s11);
  const float e00 = expf(s00 - m0), e01 = expf(s01 - m0);
  const float e10 = expf(s10 - m1), e11 = expf(s11 - m1);
  const float w0 = 1.0f / (e00 + e01), w1 = 1.0f / (e10 + e11);
  outb[pair * 2 * Dm + off]       = f2bf((e00 * v0 + e01 * v1) * w0);
  outb[(pair * 2 + 1) * Dm + off] = f2bf((e10 * v0 + e11 * v1) * w1);
}

// ---------------------------------------------------------------------------
// x2 = x + gate*pg + (1-gate)*pl   (fp32 elementwise)
// ---------------------------------------------------------------------------
__global__ __launch_bounds__(256) void combine_kernel(
    const float* __restrict__ x, const float* __restrict__ g,
    const float* __restrict__ pg, const float* __restrict__ pl,
    float* __restrict__ x2) {
  const int i = blockIdx.x * blockDim.x + threadIdx.x;
  float4 xv = reinterpret_cast<const float4*>(x)[i];
  float4 gv = reinterpret_cast<const float4*>(g)[i];
  float4 av = reinterpret_cast<const float4*>(pg)[i];
  float4 bv = reinterpret_cast<const float4*>(pl)[i];
  float4 o;
  o.x = xv.x + gv.x * av.x + (1.0f - gv.x) * bv.x;
  o.y = xv.y + gv.y * av.y + (1.0f - gv.y) * bv.y;
  o.z = xv.z + gv.z * av.z + (1.0f - gv.z) * bv.z;
  o.w = xv.w + gv.w * av.w + (1.0f - gv.w) * bv.w;
  reinterpret_cast<float4*>(x2)[i] = o;
}

// ---------------------------------------------------------------------------
extern "C" void kernel_launch(void* const* d_in, const int* in_sizes, int n_in,
                              void* d_out, int out_size, void* d_ws, size_t ws_size,
                              hipStream_t stream) {
  const float* x      = (const float*)d_in[0];
  const float* ln1_g  = (const float*)d_in[1];
  const float* ln1_b  = (const float*)d_in[2];
  const float* ln2_g  = (const float*)d_in[3];
  const float* ln2_b  = (const float*)d_in[4];
  const float* ln3_g  = (const float*)d_in[5];
  const float* ln3_b  = (const float*)d_in[6];
  const float* gw_in  = (const float*)d_in[7];
  const float* gb_in  = (const float*)d_in[8];
  const float* gw_out = (const float*)d_in[9];
  const float* gb_out = (const float*)d_in[10];
  const float* lw_in  = (const float*)d_in[11];
  const float* lb_in  = (const float*)d_in[12];
  const float* lw_out = (const float*)d_in[13];
  const float* lb_out = (const float*)d_in[14];
  const float* gate_w = (const float*)d_in[15];
  const float* gate_b = (const float*)d_in[16];
  const float* ff_w1  = (const float*)d_in[17];
  const float* ff_b1  = (const float*)d_in[18];
  const float* ff_w2  = (const float*)d_in[19];
  const float* ff_b2  = (const float*)d_in[20];
  float* out = (float*)d_out;
  char* wsb  = (char*)d_ws;

  // workspace layout (bytes), total 126.4 MB <= ws_size (>=134.2 MB)
  float* x2    = (float*)(wsb + 0);           // 16.78 MB fp32
  float* gate  = (float*)(wsb + 16777216);    // 16.78 MB fp32
  float* pg    = (float*)(wsb + 33554432);    // 16.78 MB fp32 (h2 aliases)
  float* pl    = (float*)(wsb + 50331648);    // 16.78 MB fp32
  u16*   xnb   = (u16*)(wsb + 67108864);      //  8.39 MB bf16 [8192][512]
  u16*   qkvb  = (u16*)(wsb + 75497472);      // 25.17 MB bf16 [8192][1536]
  u16*   attgb = (u16*)(wsb + 100663296);     //  8.39 MB bf16
  u16*   attlb = (u16*)(wsb + 109051904);     //  8.39 MB bf16
  u16*   wb    = (u16*)(wsb + 117440512);     //  8.91 MB bf16 weights
  u16*   ff1b  = qkvb;                        // 33.55 MB = qkvb+attgb (both dead)
  float* h2    = pg;                          // pg dead after combine

  // 0. weights -> bf16
  wconv_kernel<<<(W_TOTAL / 4 + 255) / 256, 256, 0, stream>>>(
      gw_in, lw_in, gw_out, lw_out, gate_w, ff_w1, ff_w2, wb);
  // 1. x_norm = LN1(x)  (bf16)
  ln_kernel<true><<<Mrows, 128, 0, stream>>>(x, nullptr, ln1_g, ln1_b, xnb);
  // 2. local qkv
  mfma_gemm<0, true><<<dim3(1536 / 128, Mrows / 128), 256, 0, stream>>>(
      xnb, wb + W_LWIN, lb_in, qkvb, 1536, 512);
  // 3. local window-2 attention
  attn_local_kernel<<<(Mrows / 2) * 8 / 4, 256, 0, stream>>>(qkvb, attlb);
  // 4. global qkv (overwrites local qkv)
  mfma_gemm<0, true><<<dim3(1536 / 128, Mrows / 128), 256, 0, stream>>>(
      xnb, wb + W_GWIN, gb_in, qkvb, 1536, 512);
  // 5. global causal attention
  attn_global_kernel<<<dim3(Sq / 16, 8, Bc), 256, 0, stream>>>(qkvb, attgb);
  // 6. gate = sigmoid(xn @ gate_w^T)
  mfma_gemm<1, false><<<dim3(512 / 128, Mrows / 128), 256, 0, stream>>>(
      xnb, wb + W_GATE, gate_b, gate, 512, 512);
  // 7. pg = attn_g @ gw_out^T
  mfma_gemm<0, false><<<dim3(512 / 128, Mrows / 128), 256, 0, stream>>>(
      attgb, wb + W_GWOUT, gb_out, pg, 512, 512);
  // 8. pl = attn_l @ lw_out^T
  mfma_gemm<0, false><<<dim3(512 / 128, Mrows / 128), 256, 0, stream>>>(
      attlb, wb + W_LWOUT, lb_out, pl, 512, 512);
  // 9. x2 = x + gate*pg + (1-gate)*pl
  combine_kernel<<<(Mrows * Dm / 4) / 256, 256, 0, stream>>>(x, gate, pg, pl, x2);
  // 10. h_norm = LN2(x2) (bf16)
  ln_kernel<true><<<Mrows, 128, 0, stream>>>(x2, nullptr, ln2_g, ln2_b, xnb);
  // 11. ff1 = gelu(hn @ ff_w1^T) (bf16; region of dead qkvb+attgb)
  mfma_gemm<2, true><<<dim3(2048 / 128, Mrows / 128), 256, 0, stream>>>(
      xnb, wb + W_FF1, ff_b1, ff1b, 2048, 512);
  // 12. h2 = ff1 @ ff_w2^T (fp32, aliases pg)
  mfma_gemm<0, false><<<dim3(512 / 128, Mrows / 128), 256, 0, stream>>>(
      ff1b, wb + W_FF2, ff_b2, h2, 512, 2048);
  // 13. out = LN3(x2 + h2) (fp32)
  ln_kernel<false><<<Mrows, 128, 0, stream>>>(x2, h2, ln3_g, ln3_b, out);
}

// Round 6
// 394.489 us; speedup vs baseline: 6.0610x; 2.0365x over previous
//
#include <hip/hip_runtime.h>
#include <math.h>
#include <stdint.h>

typedef unsigned short u16;
typedef __attribute__((ext_vector_type(4))) unsigned short u16x4;
typedef __attribute__((ext_vector_type(8))) unsigned short u16x8;
typedef __attribute__((ext_vector_type(8))) short s16x8;   // 8 bf16 = 4 VGPR (MFMA frag)
typedef __attribute__((ext_vector_type(4))) float f32x4;   // MFMA acc

// Problem constants
constexpr int Bc = 4;
constexpr int Sq = 2048;
constexpr int Dm = 512;
constexpr int Mrows = Bc * Sq;   // 8192

__device__ inline float b2f(u16 h) {
  union { uint32_t u; float f; } x; x.u = (uint32_t)h << 16; return x.f;
}
__device__ inline u16 f2bf(float f) {  // round-to-nearest-even
  union { float f; uint32_t u; } x; x.f = f;
  uint32_t r = (x.u + 0x7fffu + ((x.u >> 16) & 1u)) >> 16;
  return (u16)r;
}

// ---------------------------------------------------------------------------
// Weight fp32->bf16 conversion, all 7 weights in one kernel (compile-time map)
// ---------------------------------------------------------------------------
constexpr size_t W_GWIN  = 0;         // 1536x512
constexpr size_t W_LWIN  = 786432;    // 1536x512
constexpr size_t W_GWOUT = 1572864;   // 512x512
constexpr size_t W_LWOUT = 1835008;   // 512x512
constexpr size_t W_GATE  = 2097152;   // 512x512
constexpr size_t W_FF1   = 2359296;   // 2048x512
constexpr size_t W_FF2   = 3407872;   // 512x2048
constexpr size_t W_TOTAL = 4456448;

__global__ __launch_bounds__(256) void wconv_kernel(
    const float* __restrict__ gw_in, const float* __restrict__ lw_in,
    const float* __restrict__ gw_out, const float* __restrict__ lw_out,
    const float* __restrict__ gate_w, const float* __restrict__ ff_w1,
    const float* __restrict__ ff_w2, u16* __restrict__ dst) {
  size_t idx = ((size_t)blockIdx.x * 256 + threadIdx.x) * 4;
  if (idx >= W_TOTAL) return;
  const float* src; size_t base;
  if      (idx < W_LWIN)  { src = gw_in;  base = W_GWIN;  }
  else if (idx < W_GWOUT) { src = lw_in;  base = W_LWIN;  }
  else if (idx < W_LWOUT) { src = gw_out; base = W_GWOUT; }
  else if (idx < W_GATE)  { src = lw_out; base = W_LWOUT; }
  else if (idx < W_FF1)   { src = gate_w; base = W_GATE;  }
  else if (idx < W_FF2)   { src = ff_w1;  base = W_FF1;   }
  else                    { src = ff_w2;  base = W_FF2;   }
  float4 v = *reinterpret_cast<const float4*>(src + (idx - base));
  u16x4 o = { f2bf(v.x), f2bf(v.y), f2bf(v.z), f2bf(v.w) };
  *reinterpret_cast<u16x4*>(dst + idx) = o;
}

// ---------------------------------------------------------------------------
// LayerNorm (optional fused residual add). OB: write bf16 (else fp32).
// ---------------------------------------------------------------------------
template <bool OB>
__global__ __launch_bounds__(128) void ln_kernel(
    const float* __restrict__ in, const float* __restrict__ add,
    const float* __restrict__ g, const float* __restrict__ b,
    void* __restrict__ outp) {
  const int row = blockIdx.x;
  const int t = threadIdx.x;
  float4 v = reinterpret_cast<const float4*>(in + (size_t)row * Dm)[t];
  if (add != nullptr) {
    float4 a = reinterpret_cast<const float4*>(add + (size_t)row * Dm)[t];
    v.x += a.x; v.y += a.y; v.z += a.z; v.w += a.w;
  }
  float s  = v.x + v.y + v.z + v.w;
  float s2 = v.x*v.x + v.y*v.y + v.z*v.z + v.w*v.w;
  #pragma unroll
  for (int o = 32; o > 0; o >>= 1) {
    s  += __shfl_down(s, o);
    s2 += __shfl_down(s2, o);
  }
  __shared__ float rs[2], rs2[2];
  if ((t & 63) == 0) { rs[t >> 6] = s; rs2[t >> 6] = s2; }
  __syncthreads();
  const float mean = (rs[0] + rs[1]) * (1.0f / Dm);
  const float var  = (rs2[0] + rs2[1]) * (1.0f / Dm) - mean * mean;
  const float rstd = rsqrtf(var + 1e-5f);
  float4 gv = reinterpret_cast<const float4*>(g)[t];
  float4 bv = reinterpret_cast<const float4*>(b)[t];
  float ox = (v.x - mean) * rstd * gv.x + bv.x;
  float oy = (v.y - mean) * rstd * gv.y + bv.y;
  float oz = (v.z - mean) * rstd * gv.z + bv.z;
  float ow = (v.w - mean) * rstd * gv.w + bv.w;
  if (OB) {
    u16x4 o4 = { f2bf(ox), f2bf(oy), f2bf(oz), f2bf(ow) };
    *reinterpret_cast<u16x4*>((u16*)outp + (size_t)row * Dm + t * 4) = o4;
  } else {
    float4 o4; o4.x = ox; o4.y = oy; o4.z = oz; o4.w = ow;
    reinterpret_cast<float4*>((float*)outp + (size_t)row * Dm)[t] = o4;
  }
}

// ---------------------------------------------------------------------------
// MFMA GEMM (HW-validated round 5): C = act(A @ W^T + bias)
// ---------------------------------------------------------------------------
template <int ACT, bool OUT_BF16>
__global__ __launch_bounds__(256) void mfma_gemm(
    const u16* __restrict__ A, const u16* __restrict__ W,
    const float* __restrict__ bias, void* __restrict__ Cout, int N, int K) {
  __shared__ u16 sA[128 * 32];
  __shared__ u16 sW[128 * 32];
  const int tid  = threadIdx.x;
  const int wid  = tid >> 6, lane = tid & 63;
  const int lr   = lane & 15, kh = lane >> 4;
  const int wm   = wid >> 1, wn = wid & 1;
  const int m0   = blockIdx.y * 128, n0 = blockIdx.x * 128;
  const int row0 = tid >> 2,        ko0 = (tid & 3) * 8;
  const int row1 = (256 + tid) >> 2, ko1 = (tid & 3) * 8;

  f32x4 acc[4][4] = {};
  for (int k0 = 0; k0 < K; k0 += 32) {
    __syncthreads();
    __builtin_amdgcn_global_load_lds(
        (const __attribute__((address_space(1))) void*)(A + (size_t)(m0 + row0) * K + k0 + ko0),
        (__attribute__((address_space(3))) void*)(sA + wid * 512), 16, 0, 0);
    __builtin_amdgcn_global_load_lds(
        (const __attribute__((address_space(1))) void*)(A + (size_t)(m0 + row1) * K + k0 + ko1),
        (__attribute__((address_space(3))) void*)(sA + 2048 + wid * 512), 16, 0, 0);
    __builtin_amdgcn_global_load_lds(
        (const __attribute__((address_space(1))) void*)(W + (size_t)(n0 + row0) * K + k0 + ko0),
        (__attribute__((address_space(3))) void*)(sW + wid * 512), 16, 0, 0);
    __builtin_amdgcn_global_load_lds(
        (const __attribute__((address_space(1))) void*)(W + (size_t)(n0 + row1) * K + k0 + ko1),
        (__attribute__((address_space(3))) void*)(sW + 2048 + wid * 512), 16, 0, 0);
    __syncthreads();
    s16x8 af[4], bf[4];
    #pragma unroll
    for (int mf = 0; mf < 4; ++mf)
      af[mf] = *reinterpret_cast<const s16x8*>(&sA[(wm * 64 + mf * 16 + lr) * 32 + kh * 8]);
    #pragma unroll
    for (int nf = 0; nf < 4; ++nf)
      bf[nf] = *reinterpret_cast<const s16x8*>(&sW[(wn * 64 + nf * 16 + lr) * 32 + kh * 8]);
    #pragma unroll
    for (int mf = 0; mf < 4; ++mf)
      #pragma unroll
      for (int nf = 0; nf < 4; ++nf)
        acc[mf][nf] = __builtin_amdgcn_mfma_f32_16x16x32_bf16(af[mf], bf[nf], acc[mf][nf], 0, 0, 0);
  }
  #pragma unroll
  for (int nf = 0; nf < 4; ++nf) {
    const int col = n0 + wn * 64 + nf * 16 + lr;
    const float bv = bias[col];
    #pragma unroll
    for (int mf = 0; mf < 4; ++mf) {
      #pragma unroll
      for (int j = 0; j < 4; ++j) {
        const int rowg = m0 + wm * 64 + mf * 16 + kh * 4 + j;
        float v = acc[mf][nf][j] + bv;
        if (ACT == 1) v = 1.0f / (1.0f + expf(-v));
        else if (ACT == 2) v = 0.5f * v * (1.0f + erff(v * 0.70710678118654752440f));
        if (OUT_BF16) ((u16*)Cout)[(size_t)rowg * N + col] = f2bf(v);
        else          ((float*)Cout)[(size_t)rowg * N + col] = v;
      }
    }
  }
}

// ---------------------------------------------------------------------------
// MFMA flash attention (global causal). qkv bf16 [Mrows][1536].
// Block: 4 waves, 64 q-rows (16/wave). Grid (Sq/64, H=8, B=4). K-tiles of 64.
// Per wave & k-tile:
//   QK^T: A=Q frag (regs, from global), B=K frag (LDS row-major) -> 8 MFMAs
//   softmax fp32 on D-layout (col=lane&15=kpos, row=(lane>>4)*4+j=q-row)
//   P -> bf16 via per-wave LDS buffer (D-layout write, A-layout read)
//   PV: A=P frag, B=Vt frag (LDS [dh][kpos], XOR-swizzled) -> 8 MFMAs
// Vt swizzle: element V[kpos][dh] stored at Vt[dh][kpos ^ 8*((dh>>3)&7)]
//   (keeps u16x8 reads contiguous; scatter writes conflict-free)
// ---------------------------------------------------------------------------
__global__ __launch_bounds__(256) void attn_global_kernel(
    const u16* __restrict__ qkv, u16* __restrict__ outb) {
  const int qt = blockIdx.x;   // 64-row q tile: 0..31
  const int h  = blockIdx.y;
  const int b  = blockIdx.z;
  const int tid = threadIdx.x;
  const int w = tid >> 6, lane = tid & 63;
  const int c = lane & 15, kh = lane >> 4;

  __shared__ u16 Kb[64][72];       // K row-major [kpos][dh]
  __shared__ u16 Vt[64][72];       // V transposed [dh][kpos-swizzled]
  __shared__ u16 Pw[4][16][72];    // per-wave P [q-row][kpos]

  const size_t bbase = (size_t)b * Sq;

  // Q fragments in registers: A[m=c][k = kk*32 + kh*8 + e]
  s16x8 aq[2];
  {
    const u16* qg = qkv + (bbase + qt * 64 + w * 16 + c) * 1536 + h * 64 + kh * 8;
    aq[0] = *reinterpret_cast<const s16x8*>(qg);
    aq[1] = *reinterpret_cast<const s16x8*>(qg + 32);
  }

  f32x4 o_acc[4] = {};     // [nb2 dh-block]; elem j = q-row kh*4+j
  float mrow[4] = { -INFINITY, -INFINITY, -INFINITY, -INFINITY };
  float lrow[4] = { 0.f, 0.f, 0.f, 0.f };
  int qp[4];
  #pragma unroll
  for (int j = 0; j < 4; ++j) qp[j] = qt * 64 + w * 16 + kh * 4 + j;

  // staging mapping: row = tid>>2 (kpos 0..63), cc2 = (tid&3)*2 (8-elem chunks)
  const int srow = tid >> 2, cc2 = (tid & 3) * 2;

  const int ntiles = qt + 1;
  for (int kt = 0; kt < ntiles; ++kt) {
    __syncthreads();  // prior tile's LDS reads complete
    {
      const u16* kg = qkv + (bbase + kt * 64 + srow) * 1536 + 512 + h * 64;
      u16x8 k0 = *reinterpret_cast<const u16x8*>(kg + cc2 * 8);
      u16x8 k1 = *reinterpret_cast<const u16x8*>(kg + cc2 * 8 + 8);
      u16x8 v0 = *reinterpret_cast<const u16x8*>(kg + 512 + cc2 * 8);
      u16x8 v1 = *reinterpret_cast<const u16x8*>(kg + 512 + cc2 * 8 + 8);
      *reinterpret_cast<u16x8*>(&Kb[srow][cc2 * 8]) = k0;
      *reinterpret_cast<u16x8*>(&Kb[srow][cc2 * 8 + 8]) = k1;
      const int sw0 = srow ^ ((cc2 & 7) * 8);        // swizzled kpos for dh block cc2
      const int sw1 = srow ^ (((cc2 + 1) & 7) * 8);  // ... for dh block cc2+1
      #pragma unroll
      for (int i = 0; i < 8; ++i) {
        Vt[cc2 * 8 + i][sw0] = v0[i];
        Vt[cc2 * 8 + 8 + i][sw1] = v1[i];
      }
    }
    __syncthreads();  // staged tile visible

    // ---- QK^T ----
    f32x4 s_acc[4] = {};
    #pragma unroll
    for (int nb = 0; nb < 4; ++nb) {
      #pragma unroll
      for (int kk = 0; kk < 2; ++kk) {
        s16x8 bk = *reinterpret_cast<const s16x8*>(&Kb[nb * 16 + c][kk * 32 + kh * 8]);
        s_acc[nb] = __builtin_amdgcn_mfma_f32_16x16x32_bf16(aq[kk], bk, s_acc[nb], 0, 0, 0);
      }
    }

    // ---- softmax (fp32, per q-row j) ----
    const bool diag = (kt == qt);
    float p[4][4];     // [nb][j]
    float tm[4] = { -INFINITY, -INFINITY, -INFINITY, -INFINITY };
    #pragma unroll
    for (int nb = 0; nb < 4; ++nb) {
      #pragma unroll
      for (int j = 0; j < 4; ++j) {
        float sv = s_acc[nb][j] * 0.125f;
        if (diag && (kt * 64 + nb * 16 + c) > qp[j]) sv = -INFINITY;
        p[nb][j] = sv;
        tm[j] = fmaxf(tm[j], sv);
      }
    }
    #pragma unroll
    for (int o = 1; o < 16; o <<= 1) {
      #pragma unroll
      for (int j = 0; j < 4; ++j) tm[j] = fmaxf(tm[j], __shfl_xor(tm[j], o));
    }
    float corr[4], psum[4];
    #pragma unroll
    for (int j = 0; j < 4; ++j) {
      const float mnew = fmaxf(mrow[j], tm[j]);
      corr[j] = __expf(mrow[j] - mnew);
      mrow[j] = mnew;
      psum[j] = 0.f;
      #pragma unroll
      for (int nb = 0; nb < 4; ++nb) {
        p[nb][j] = __expf(p[nb][j] - mnew);
        psum[j] += p[nb][j];
      }
    }
    #pragma unroll
    for (int o = 1; o < 16; o <<= 1) {
      #pragma unroll
      for (int j = 0; j < 4; ++j) psum[j] += __shfl_xor(psum[j], o);
    }
    #pragma unroll
    for (int j = 0; j < 4; ++j) lrow[j] = lrow[j] * corr[j] + psum[j];
    #pragma unroll
    for (int nb2 = 0; nb2 < 4; ++nb2)
      #pragma unroll
      for (int j = 0; j < 4; ++j) o_acc[nb2][j] *= corr[j];

    // P -> bf16 into per-wave LDS (D-layout: row kh*4+j, col nb*16+c)
    #pragma unroll
    for (int nb = 0; nb < 4; ++nb)
      #pragma unroll
      for (int j = 0; j < 4; ++j)
        Pw[w][kh * 4 + j][nb * 16 + c] = f2bf(p[nb][j]);

    // ---- PV ----  A = P (row=c, k=kpos), B = Vt (col=dh, k=kpos)
    #pragma unroll
    for (int kk = 0; kk < 2; ++kk) {
      s16x8 ap = *reinterpret_cast<const s16x8*>(&Pw[w][c][kk * 32 + kh * 8]);
      #pragma unroll
      for (int nb2 = 0; nb2 < 4; ++nb2) {
        const int dh = nb2 * 16 + c;
        const int f8 = ((dh >> 3) & 7) * 8;
        s16x8 bv = *reinterpret_cast<const s16x8*>(&Vt[dh][(kk * 32 + kh * 8) ^ f8]);
        o_acc[nb2] = __builtin_amdgcn_mfma_f32_16x16x32_bf16(ap, bv, o_acc[nb2], 0, 0, 0);
      }
    }
  }

  // ---- store O ----
  float invl[4];
  #pragma unroll
  for (int j = 0; j < 4; ++j) invl[j] = 1.0f / lrow[j];
  #pragma unroll
  for (int nb2 = 0; nb2 < 4; ++nb2) {
    #pragma unroll
    for (int j = 0; j < 4; ++j) {
      const int qrow = qt * 64 + w * 16 + kh * 4 + j;
      outb[(bbase + qrow) * Dm + h * 64 + nb2 * 16 + c] = f2bf(o_acc[nb2][j] * invl[j]);
    }
  }
}

// ---------------------------------------------------------------------------
// Local window-2 attention (bf16 in/out): one wave per (pair, head).
// ---------------------------------------------------------------------------
__global__ __launch_bounds__(256) void attn_local_kernel(
    const u16* __restrict__ qkv, u16* __restrict__ outb) {
  const int unit = blockIdx.x * 4 + (threadIdx.x >> 6);  // (pair<<3)|h
  const int lane = threadIdx.x & 63;
  const int h = unit & 7;
  const size_t pair = (size_t)(unit >> 3);
  const u16* r0 = qkv + pair * 2 * 1536;
  const u16* r1 = r0 + 1536;
  const int off = h * 64 + lane;
  const float q0 = b2f(r0[off]), k0 = b2f(r0[512 + off]), v0 = b2f(r0[1024 + off]);
  const float q1 = b2f(r1[off]), k1 = b2f(r1[512 + off]), v1 = b2f(r1[1024 + off]);
  float s00 = q0 * k0, s01 = q0 * k1, s10 = q1 * k0, s11 = q1 * k1;
  #pragma unroll
  for (int o = 1; o < 64; o <<= 1) {
    s00 += __shfl_xor(s00, o); s01 += __shfl_xor(s01, o);
    s10 += __shfl_xor(s10, o); s11 += __shfl_xor(s11, o);
  }
  s00 *= 0.125f; s01 *= 0.125f; s10 *= 0.125f; s11 *= 0.125f;
  const float m0 = fmaxf(s00, s01), m1 = fmaxf(s10, s11);
  const float e00 = expf(s00 - m0), e01 = expf(s01 - m0);
  const float e10 = expf(s10 - m1), e11 = expf(s11 - m1);
  const float w0 = 1.0f / (e00 + e01), w1 = 1.0f / (e10 + e11);
  outb[pair * 2 * Dm + off]       = f2bf((e00 * v0 + e01 * v1) * w0);
  outb[(pair * 2 + 1) * Dm + off] = f2bf((e10 * v0 + e11 * v1) * w1);
}

// ---------------------------------------------------------------------------
// x2 = x + gate*pg + (1-gate)*pl   (fp32 elementwise)
// ---------------------------------------------------------------------------
__global__ __launch_bounds__(256) void combine_kernel(
    const float* __restrict__ x, const float* __restrict__ g,
    const float* __restrict__ pg, const float* __restrict__ pl,
    float* __restrict__ x2) {
  const int i = blockIdx.x * blockDim.x + threadIdx.x;
  float4 xv = reinterpret_cast<const float4*>(x)[i];
  float4 gv = reinterpret_cast<const float4*>(g)[i];
  float4 av = reinterpret_cast<const float4*>(pg)[i];
  float4 bv = reinterpret_cast<const float4*>(pl)[i];
  float4 o;
  o.x = xv.x + gv.x * av.x + (1.0f - gv.x) * bv.x;
  o.y = xv.y + gv.y * av.y + (1.0f - gv.y) * bv.y;
  o.z = xv.z + gv.z * av.z + (1.0f - gv.z) * bv.z;
  o.w = xv.w + gv.w * av.w + (1.0f - gv.w) * bv.w;
  reinterpret_cast<float4*>(x2)[i] = o;
}

// ---------------------------------------------------------------------------
extern "C" void kernel_launch(void* const* d_in, const int* in_sizes, int n_in,
                              void* d_out, int out_size, void* d_ws, size_t ws_size,
                              hipStream_t stream) {
  const float* x      = (const float*)d_in[0];
  const float* ln1_g  = (const float*)d_in[1];
  const float* ln1_b  = (const float*)d_in[2];
  const float* ln2_g  = (const float*)d_in[3];
  const float* ln2_b  = (const float*)d_in[4];
  const float* ln3_g  = (const float*)d_in[5];
  const float* ln3_b  = (const float*)d_in[6];
  const float* gw_in  = (const float*)d_in[7];
  const float* gb_in  = (const float*)d_in[8];
  const float* gw_out = (const float*)d_in[9];
  const float* gb_out = (const float*)d_in[10];
  const float* lw_in  = (const float*)d_in[11];
  const float* lb_in  = (const float*)d_in[12];
  const float* lw_out = (const float*)d_in[13];
  const float* lb_out = (const float*)d_in[14];
  const float* gate_w = (const float*)d_in[15];
  const float* gate_b = (const float*)d_in[16];
  const float* ff_w1  = (const float*)d_in[17];
  const float* ff_b1  = (const float*)d_in[18];
  const float* ff_w2  = (const float*)d_in[19];
  const float* ff_b2  = (const float*)d_in[20];
  float* out = (float*)d_out;
  char* wsb  = (char*)d_ws;

  // workspace layout (bytes), total 126.4 MB <= ws_size
  float* x2    = (float*)(wsb + 0);
  float* gate  = (float*)(wsb + 16777216);
  float* pg    = (float*)(wsb + 33554432);
  float* pl    = (float*)(wsb + 50331648);
  u16*   xnb   = (u16*)(wsb + 67108864);
  u16*   qkvb  = (u16*)(wsb + 75497472);
  u16*   attgb = (u16*)(wsb + 100663296);
  u16*   attlb = (u16*)(wsb + 109051904);
  u16*   wb    = (u16*)(wsb + 117440512);
  u16*   ff1b  = qkvb;
  float* h2    = pg;

  // 0. weights -> bf16
  wconv_kernel<<<(W_TOTAL / 4 + 255) / 256, 256, 0, stream>>>(
      gw_in, lw_in, gw_out, lw_out, gate_w, ff_w1, ff_w2, wb);
  // 1. x_norm = LN1(x)  (bf16)
  ln_kernel<true><<<Mrows, 128, 0, stream>>>(x, nullptr, ln1_g, ln1_b, xnb);
  // 2. local qkv
  mfma_gemm<0, true><<<dim3(1536 / 128, Mrows / 128), 256, 0, stream>>>(
      xnb, wb + W_LWIN, lb_in, qkvb, 1536, 512);
  // 3. local window-2 attention
  attn_local_kernel<<<(Mrows / 2) * 8 / 4, 256, 0, stream>>>(qkvb, attlb);
  // 4. global qkv (overwrites local qkv)
  mfma_gemm<0, true><<<dim3(1536 / 128, Mrows / 128), 256, 0, stream>>>(
      xnb, wb + W_GWIN, gb_in, qkvb, 1536, 512);
  // 5. global causal attention (MFMA flash)
  attn_global_kernel<<<dim3(Sq / 64, 8, Bc), 256, 0, stream>>>(qkvb, attgb);
  // 6. gate = sigmoid(xn @ gate_w^T)
  mfma_gemm<1, false><<<dim3(512 / 128, Mrows / 128), 256, 0, stream>>>(
      xnb, wb + W_GATE, gate_b, gate, 512, 512);
  // 7. pg = attn_g @ gw_out^T
  mfma_gemm<0, false><<<dim3(512 / 128, Mrows / 128), 256, 0, stream>>>(
      attgb, wb + W_GWOUT, gb_out, pg, 512, 512);
  // 8. pl = attn_l @ lw_out^T
  mfma_gemm<0, false><<<dim3(512 / 128, Mrows / 128), 256, 0, stream>>>(
      attlb, wb + W_LWOUT, lb_out, pl, 512, 512);
  // 9. x2 = x + gate*pg + (1-gate)*pl
  combine_kernel<<<(Mrows * Dm / 4) / 256, 256, 0, stream>>>(x, gate, pg, pl, x2);
  // 10. h_norm = LN2(x2) (bf16)
  ln_kernel<true><<<Mrows, 128, 0, stream>>>(x2, nullptr, ln2_g, ln2_b, xnb);
  // 11. ff1 = gelu(hn @ ff_w1^T)
  mfma_gemm<2, true><<<dim3(2048 / 128, Mrows / 128), 256, 0, stream>>>(
      xnb, wb + W_FF1, ff_b1, ff1b, 2048, 512);
  // 12. h2 = ff1 @ ff_w2^T (fp32)
  mfma_gemm<0, false><<<dim3(512 / 128, Mrows / 128), 256, 0, stream>>>(
      ff1b, wb + W_FF2, ff_b2, h2, 512, 2048);
  // 13. out = LN3(x2 + h2) (fp32)
  ln_kernel<false><<<Mrows, 128, 0, stream>>>(x2, h2, ln3_g, ln3_b, out);
}

// Round 7
// 356.116 us; speedup vs baseline: 6.7141x; 1.1078x over previous
//
#include <hip/hip_runtime.h>
#include <math.h>
#include <stdint.h>

typedef unsigned short u16;
typedef __attribute__((ext_vector_type(4))) unsigned short u16x4;
typedef __attribute__((ext_vector_type(8))) unsigned short u16x8;
typedef __attribute__((ext_vector_type(8))) short s16x8;   // 8 bf16 = 4 VGPR (MFMA frag)
typedef __attribute__((ext_vector_type(4))) float f32x4;   // MFMA acc

// Problem constants
constexpr int Bc = 4;
constexpr int Sq = 2048;
constexpr int Dm = 512;
constexpr int Mrows = Bc * Sq;   // 8192

__device__ inline float b2f(u16 h) {
  union { uint32_t u; float f; } x; x.u = (uint32_t)h << 16; return x.f;
}
__device__ inline u16 f2bf(float f) {  // round-to-nearest-even
  union { float f; uint32_t u; } x; x.f = f;
  uint32_t r = (x.u + 0x7fffu + ((x.u >> 16) & 1u)) >> 16;
  return (u16)r;
}

// ---------------------------------------------------------------------------
// Weight fp32->bf16 conversion, all 7 weights in one kernel (compile-time map)
// ---------------------------------------------------------------------------
constexpr size_t W_GWIN  = 0;         // 1536x512
constexpr size_t W_LWIN  = 786432;    // 1536x512
constexpr size_t W_GWOUT = 1572864;   // 512x512
constexpr size_t W_LWOUT = 1835008;   // 512x512
constexpr size_t W_GATE  = 2097152;   // 512x512
constexpr size_t W_FF1   = 2359296;   // 2048x512
constexpr size_t W_FF2   = 3407872;   // 512x2048
constexpr size_t W_TOTAL = 4456448;

__global__ __launch_bounds__(256) void wconv_kernel(
    const float* __restrict__ gw_in, const float* __restrict__ lw_in,
    const float* __restrict__ gw_out, const float* __restrict__ lw_out,
    const float* __restrict__ gate_w, const float* __restrict__ ff_w1,
    const float* __restrict__ ff_w2, u16* __restrict__ dst) {
  size_t idx = ((size_t)blockIdx.x * 256 + threadIdx.x) * 4;
  if (idx >= W_TOTAL) return;
  const float* src; size_t base;
  if      (idx < W_LWIN)  { src = gw_in;  base = W_GWIN;  }
  else if (idx < W_GWOUT) { src = lw_in;  base = W_LWIN;  }
  else if (idx < W_LWOUT) { src = gw_out; base = W_GWOUT; }
  else if (idx < W_GATE)  { src = lw_out; base = W_LWOUT; }
  else if (idx < W_FF1)   { src = gate_w; base = W_GATE;  }
  else if (idx < W_FF2)   { src = ff_w1;  base = W_FF1;   }
  else                    { src = ff_w2;  base = W_FF2;   }
  float4 v = *reinterpret_cast<const float4*>(src + (idx - base));
  u16x4 o = { f2bf(v.x), f2bf(v.y), f2bf(v.z), f2bf(v.w) };
  *reinterpret_cast<u16x4*>(dst + idx) = o;
}

// ---------------------------------------------------------------------------
// LayerNorm (optional fused residual add). OB: write bf16 (else fp32).
// ---------------------------------------------------------------------------
template <bool OB>
__global__ __launch_bounds__(128) void ln_kernel(
    const float* __restrict__ in, const float* __restrict__ add,
    const float* __restrict__ g, const float* __restrict__ b,
    void* __restrict__ outp) {
  const int row = blockIdx.x;
  const int t = threadIdx.x;
  float4 v = reinterpret_cast<const float4*>(in + (size_t)row * Dm)[t];
  if (add != nullptr) {
    float4 a = reinterpret_cast<const float4*>(add + (size_t)row * Dm)[t];
    v.x += a.x; v.y += a.y; v.z += a.z; v.w += a.w;
  }
  float s  = v.x + v.y + v.z + v.w;
  float s2 = v.x*v.x + v.y*v.y + v.z*v.z + v.w*v.w;
  #pragma unroll
  for (int o = 32; o > 0; o >>= 1) {
    s  += __shfl_down(s, o);
    s2 += __shfl_down(s2, o);
  }
  __shared__ float rs[2], rs2[2];
  if ((t & 63) == 0) { rs[t >> 6] = s; rs2[t >> 6] = s2; }
  __syncthreads();
  const float mean = (rs[0] + rs[1]) * (1.0f / Dm);
  const float var  = (rs2[0] + rs2[1]) * (1.0f / Dm) - mean * mean;
  const float rstd = rsqrtf(var + 1e-5f);
  float4 gv = reinterpret_cast<const float4*>(g)[t];
  float4 bv = reinterpret_cast<const float4*>(b)[t];
  float ox = (v.x - mean) * rstd * gv.x + bv.x;
  float oy = (v.y - mean) * rstd * gv.y + bv.y;
  float oz = (v.z - mean) * rstd * gv.z + bv.z;
  float ow = (v.w - mean) * rstd * gv.w + bv.w;
  if (OB) {
    u16x4 o4 = { f2bf(ox), f2bf(oy), f2bf(oz), f2bf(ow) };
    *reinterpret_cast<u16x4*>((u16*)outp + (size_t)row * Dm + t * 4) = o4;
  } else {
    float4 o4; o4.x = ox; o4.y = oy; o4.z = oz; o4.w = ow;
    reinterpret_cast<float4*>((float*)outp + (size_t)row * Dm)[t] = o4;
  }
}

// ---------------------------------------------------------------------------
// MFMA GEMM (HW-validated round 5): C = act(A @ W^T + bias)
// ---------------------------------------------------------------------------
template <int ACT, bool OUT_BF16>
__global__ __launch_bounds__(256) void mfma_gemm(
    const u16* __restrict__ A, const u16* __restrict__ W,
    const float* __restrict__ bias, void* __restrict__ Cout, int N, int K) {
  __shared__ u16 sA[128 * 32];
  __shared__ u16 sW[128 * 32];
  const int tid  = threadIdx.x;
  const int wid  = tid >> 6, lane = tid & 63;
  const int lr   = lane & 15, kh = lane >> 4;
  const int wm   = wid >> 1, wn = wid & 1;
  const int m0   = blockIdx.y * 128, n0 = blockIdx.x * 128;
  const int row0 = tid >> 2,        ko0 = (tid & 3) * 8;
  const int row1 = (256 + tid) >> 2, ko1 = (tid & 3) * 8;

  f32x4 acc[4][4] = {};
  for (int k0 = 0; k0 < K; k0 += 32) {
    __syncthreads();
    __builtin_amdgcn_global_load_lds(
        (const __attribute__((address_space(1))) void*)(A + (size_t)(m0 + row0) * K + k0 + ko0),
        (__attribute__((address_space(3))) void*)(sA + wid * 512), 16, 0, 0);
    __builtin_amdgcn_global_load_lds(
        (const __attribute__((address_space(1))) void*)(A + (size_t)(m0 + row1) * K + k0 + ko1),
        (__attribute__((address_space(3))) void*)(sA + 2048 + wid * 512), 16, 0, 0);
    __builtin_amdgcn_global_load_lds(
        (const __attribute__((address_space(1))) void*)(W + (size_t)(n0 + row0) * K + k0 + ko0),
        (__attribute__((address_space(3))) void*)(sW + wid * 512), 16, 0, 0);
    __builtin_amdgcn_global_load_lds(
        (const __attribute__((address_space(1))) void*)(W + (size_t)(n0 + row1) * K + k0 + ko1),
        (__attribute__((address_space(3))) void*)(sW + 2048 + wid * 512), 16, 0, 0);
    __syncthreads();
    s16x8 af[4], bf[4];
    #pragma unroll
    for (int mf = 0; mf < 4; ++mf)
      af[mf] = *reinterpret_cast<const s16x8*>(&sA[(wm * 64 + mf * 16 + lr) * 32 + kh * 8]);
    #pragma unroll
    for (int nf = 0; nf < 4; ++nf)
      bf[nf] = *reinterpret_cast<const s16x8*>(&sW[(wn * 64 + nf * 16 + lr) * 32 + kh * 8]);
    #pragma unroll
    for (int mf = 0; mf < 4; ++mf)
      #pragma unroll
      for (int nf = 0; nf < 4; ++nf)
        acc[mf][nf] = __builtin_amdgcn_mfma_f32_16x16x32_bf16(af[mf], bf[nf], acc[mf][nf], 0, 0, 0);
  }
  #pragma unroll
  for (int nf = 0; nf < 4; ++nf) {
    const int col = n0 + wn * 64 + nf * 16 + lr;
    const float bv = bias[col];
    #pragma unroll
    for (int mf = 0; mf < 4; ++mf) {
      #pragma unroll
      for (int j = 0; j < 4; ++j) {
        const int rowg = m0 + wm * 64 + mf * 16 + kh * 4 + j;
        float v = acc[mf][nf][j] + bv;
        if (ACT == 1) v = 1.0f / (1.0f + expf(-v));
        else if (ACT == 2) v = 0.5f * v * (1.0f + erff(v * 0.70710678118654752440f));
        if (OUT_BF16) ((u16*)Cout)[(size_t)rowg * N + col] = f2bf(v);
        else          ((float*)Cout)[(size_t)rowg * N + col] = v;
      }
    }
  }
}

// ---------------------------------------------------------------------------
// MFMA flash attention (global causal). qkv bf16 [Mrows][1536].
// Round 7: heavy-first qt ordering (LPT), reg-staged K/V prefetch (T14),
// packed b32 Vt staging (2 kpos per thread). Compute phase = round 6 (HW-ok).
// Block: 4 waves, 64 q-rows (16/wave). Grid (Sq/64, 8, 4). K-tiles of 64.
// Vt swizzle: V[kpos][dh] at Vt[dh][kpos ^ 8*((dh>>3)&7)].
// ---------------------------------------------------------------------------
__global__ __launch_bounds__(256) void attn_global_kernel(
    const u16* __restrict__ qkv, u16* __restrict__ outb) {
  const int qt = (int)gridDim.x - 1 - (int)blockIdx.x;   // heavy-first
  const int h  = blockIdx.y;
  const int b  = blockIdx.z;
  const int tid = threadIdx.x;
  const int w = tid >> 6, lane = tid & 63;
  const int c = lane & 15, kh = lane >> 4;

  __shared__ u16 Kb[64][72];       // K row-major [kpos][dh]
  __shared__ u16 Vt[64][72];       // V transposed [dh][kpos-swizzled]
  __shared__ u16 Pw[4][16][72];    // per-wave P [q-row][kpos]

  const size_t bbase = (size_t)b * Sq;

  // Q fragments in registers: A[m=c][k = kk*32 + kh*8 + e]
  s16x8 aq[2];
  {
    const u16* qg = qkv + (bbase + qt * 64 + w * 16 + c) * 1536 + h * 64 + kh * 8;
    aq[0] = *reinterpret_cast<const s16x8*>(qg);
    aq[1] = *reinterpret_cast<const s16x8*>(qg + 32);
  }

  f32x4 o_acc[4] = {};     // [nb2 dh-block]; elem j = q-row kh*4+j
  float mrow[4] = { -INFINITY, -INFINITY, -INFINITY, -INFINITY };
  float lrow[4] = { 0.f, 0.f, 0.f, 0.f };
  int qp[4];
  #pragma unroll
  for (int j = 0; j < 4; ++j) qp[j] = qt * 64 + w * 16 + kh * 4 + j;

  // staging mapping: thread owns kpos rows {srow2, srow2+1}, dh chunk cc*8..+7
  const int g2 = tid >> 3, cc = tid & 7;
  const int srow2 = g2 * 2;
  const u16* kg0 = qkv + (bbase + srow2) * 1536 + 512 + h * 64 + cc * 8;
  const size_t tilestep = (size_t)64 * 1536;

  // prefetch tile 0 into regs
  u16x8 ka, kb2, va, vb;
  {
    const u16* p = kg0;
    ka  = *reinterpret_cast<const u16x8*>(p);
    kb2 = *reinterpret_cast<const u16x8*>(p + 1536);
    va  = *reinterpret_cast<const u16x8*>(p + 512);
    vb  = *reinterpret_cast<const u16x8*>(p + 1536 + 512);
  }

  const int ntiles = qt + 1;
  for (int kt = 0; kt < ntiles; ++kt) {
    __syncthreads();  // prior tile's LDS reads complete
    {  // write staged regs -> LDS
      *reinterpret_cast<u16x8*>(&Kb[srow2][cc * 8])     = ka;
      *reinterpret_cast<u16x8*>(&Kb[srow2 + 1][cc * 8]) = kb2;
      const int sw = srow2 ^ (cc * 8);   // even; (srow2+1)^f8 = sw+1
      #pragma unroll
      for (int i = 0; i < 8; ++i) {
        uint32_t pk = (uint32_t)va[i] | ((uint32_t)vb[i] << 16);
        *reinterpret_cast<uint32_t*>(&Vt[cc * 8 + i][sw]) = pk;
      }
    }
    __syncthreads();  // staged tile visible
    if (kt + 1 < ntiles) {  // issue next tile's loads; latency hides under compute
      const u16* p = kg0 + (size_t)(kt + 1) * tilestep;
      ka  = *reinterpret_cast<const u16x8*>(p);
      kb2 = *reinterpret_cast<const u16x8*>(p + 1536);
      va  = *reinterpret_cast<const u16x8*>(p + 512);
      vb  = *reinterpret_cast<const u16x8*>(p + 1536 + 512);
    }

    // ---- QK^T ----
    f32x4 s_acc[4] = {};
    #pragma unroll
    for (int nb = 0; nb < 4; ++nb) {
      #pragma unroll
      for (int kk = 0; kk < 2; ++kk) {
        s16x8 bk = *reinterpret_cast<const s16x8*>(&Kb[nb * 16 + c][kk * 32 + kh * 8]);
        s_acc[nb] = __builtin_amdgcn_mfma_f32_16x16x32_bf16(aq[kk], bk, s_acc[nb], 0, 0, 0);
      }
    }

    // ---- softmax (fp32, per q-row j) ----
    const bool diag = (kt == qt);
    float p[4][4];     // [nb][j]
    float tm[4] = { -INFINITY, -INFINITY, -INFINITY, -INFINITY };
    #pragma unroll
    for (int nb = 0; nb < 4; ++nb) {
      #pragma unroll
      for (int j = 0; j < 4; ++j) {
        float sv = s_acc[nb][j] * 0.125f;
        if (diag && (kt * 64 + nb * 16 + c) > qp[j]) sv = -INFINITY;
        p[nb][j] = sv;
        tm[j] = fmaxf(tm[j], sv);
      }
    }
    #pragma unroll
    for (int o = 1; o < 16; o <<= 1) {
      #pragma unroll
      for (int j = 0; j < 4; ++j) tm[j] = fmaxf(tm[j], __shfl_xor(tm[j], o));
    }
    float corr[4], psum[4];
    #pragma unroll
    for (int j = 0; j < 4; ++j) {
      const float mnew = fmaxf(mrow[j], tm[j]);
      corr[j] = __expf(mrow[j] - mnew);
      mrow[j] = mnew;
      psum[j] = 0.f;
      #pragma unroll
      for (int nb = 0; nb < 4; ++nb) {
        p[nb][j] = __expf(p[nb][j] - mnew);
        psum[j] += p[nb][j];
      }
    }
    #pragma unroll
    for (int o = 1; o < 16; o <<= 1) {
      #pragma unroll
      for (int j = 0; j < 4; ++j) psum[j] += __shfl_xor(psum[j], o);
    }
    #pragma unroll
    for (int j = 0; j < 4; ++j) lrow[j] = lrow[j] * corr[j] + psum[j];
    #pragma unroll
    for (int nb2 = 0; nb2 < 4; ++nb2)
      #pragma unroll
      for (int j = 0; j < 4; ++j) o_acc[nb2][j] *= corr[j];

    // P -> bf16 into per-wave LDS (D-layout: row kh*4+j, col nb*16+c)
    #pragma unroll
    for (int nb = 0; nb < 4; ++nb)
      #pragma unroll
      for (int j = 0; j < 4; ++j)
        Pw[w][kh * 4 + j][nb * 16 + c] = f2bf(p[nb][j]);

    // ---- PV ----  A = P (row=c, k=kpos), B = Vt (col=dh, k=kpos)
    #pragma unroll
    for (int kk = 0; kk < 2; ++kk) {
      s16x8 ap = *reinterpret_cast<const s16x8*>(&Pw[w][c][kk * 32 + kh * 8]);
      #pragma unroll
      for (int nb2 = 0; nb2 < 4; ++nb2) {
        const int dh = nb2 * 16 + c;
        const int f8 = ((dh >> 3) & 7) * 8;
        s16x8 bv = *reinterpret_cast<const s16x8*>(&Vt[dh][(kk * 32 + kh * 8) ^ f8]);
        o_acc[nb2] = __builtin_amdgcn_mfma_f32_16x16x32_bf16(ap, bv, o_acc[nb2], 0, 0, 0);
      }
    }
  }

  // ---- store O ----
  float invl[4];
  #pragma unroll
  for (int j = 0; j < 4; ++j) invl[j] = 1.0f / lrow[j];
  #pragma unroll
  for (int nb2 = 0; nb2 < 4; ++nb2) {
    #pragma unroll
    for (int j = 0; j < 4; ++j) {
      const int qrow = qt * 64 + w * 16 + kh * 4 + j;
      outb[(bbase + qrow) * Dm + h * 64 + nb2 * 16 + c] = f2bf(o_acc[nb2][j] * invl[j]);
    }
  }
}

// ---------------------------------------------------------------------------
// Local window-2 attention (bf16 in/out): one wave per (pair, head).
// ---------------------------------------------------------------------------
__global__ __launch_bounds__(256) void attn_local_kernel(
    const u16* __restrict__ qkv, u16* __restrict__ outb) {
  const int unit = blockIdx.x * 4 + (threadIdx.x >> 6);  // (pair<<3)|h
  const int lane = threadIdx.x & 63;
  const int h = unit & 7;
  const size_t pair = (size_t)(unit >> 3);
  const u16* r0 = qkv + pair * 2 * 1536;
  const u16* r1 = r0 + 1536;
  const int off = h * 64 + lane;
  const float q0 = b2f(r0[off]), k0 = b2f(r0[512 + off]), v0 = b2f(r0[1024 + off]);
  const float q1 = b2f(r1[off]), k1 = b2f(r1[512 + off]), v1 = b2f(r1[1024 + off]);
  float s00 = q0 * k0, s01 = q0 * k1, s10 = q1 * k0, s11 = q1 * k1;
  #pragma unroll
  for (int o = 1; o < 64; o <<= 1) {
    s00 += __shfl_xor(s00, o); s01 += __shfl_xor(s01, o);
    s10 += __shfl_xor(s10, o); s11 += __shfl_xor(s11, o);
  }
  s00 *= 0.125f; s01 *= 0.125f; s10 *= 0.125f; s11 *= 0.125f;
  const float m0 = fmaxf(s00, s01), m1 = fmaxf(s10, s11);
  const float e00 = expf(s00 - m0), e01 = expf(s01 - m0);
  const float e10 = expf(s10 - m1), e11 = expf(s11 - m1);
  const float w0 = 1.0f / (e00 + e01), w1 = 1.0f / (e10 + e11);
  outb[pair * 2 * Dm + off]       = f2bf((e00 * v0 + e01 * v1) * w0);
  outb[(pair * 2 + 1) * Dm + off] = f2bf((e10 * v0 + e11 * v1) * w1);
}

// ---------------------------------------------------------------------------
// x2 = x + gate*pg + (1-gate)*pl   (fp32 elementwise)
// ---------------------------------------------------------------------------
__global__ __launch_bounds__(256) void combine_kernel(
    const float* __restrict__ x, const float* __restrict__ g,
    const float* __restrict__ pg, const float* __restrict__ pl,
    float* __restrict__ x2) {
  const int i = blockIdx.x * blockDim.x + threadIdx.x;
  float4 xv = reinterpret_cast<const float4*>(x)[i];
  float4 gv = reinterpret_cast<const float4*>(g)[i];
  float4 av = reinterpret_cast<const float4*>(pg)[i];
  float4 bv = reinterpret_cast<const float4*>(pl)[i];
  float4 o;
  o.x = xv.x + gv.x * av.x + (1.0f - gv.x) * bv.x;
  o.y = xv.y + gv.y * av.y + (1.0f - gv.y) * bv.y;
  o.z = xv.z + gv.z * av.z + (1.0f - gv.z) * bv.z;
  o.w = xv.w + gv.w * av.w + (1.0f - gv.w) * bv.w;
  reinterpret_cast<float4*>(x2)[i] = o;
}

// ---------------------------------------------------------------------------
extern "C" void kernel_launch(void* const* d_in, const int* in_sizes, int n_in,
                              void* d_out, int out_size, void* d_ws, size_t ws_size,
                              hipStream_t stream) {
  const float* x      = (const float*)d_in[0];
  const float* ln1_g  = (const float*)d_in[1];
  const float* ln1_b  = (const float*)d_in[2];
  const float* ln2_g  = (const float*)d_in[3];
  const float* ln2_b  = (const float*)d_in[4];
  const float* ln3_g  = (const float*)d_in[5];
  const float* ln3_b  = (const float*)d_in[6];
  const float* gw_in  = (const float*)d_in[7];
  const float* gb_in  = (const float*)d_in[8];
  const float* gw_out = (const float*)d_in[9];
  const float* gb_out = (const float*)d_in[10];
  const float* lw_in  = (const float*)d_in[11];
  const float* lb_in  = (const float*)d_in[12];
  const float* lw_out = (const float*)d_in[13];
  const float* lb_out = (const float*)d_in[14];
  const float* gate_w = (const float*)d_in[15];
  const float* gate_b = (const float*)d_in[16];
  const float* ff_w1  = (const float*)d_in[17];
  const float* ff_b1  = (const float*)d_in[18];
  const float* ff_w2  = (const float*)d_in[19];
  const float* ff_b2  = (const float*)d_in[20];
  float* out = (float*)d_out;
  char* wsb  = (char*)d_ws;

  // workspace layout (bytes), total 126.4 MB <= ws_size
  float* x2    = (float*)(wsb + 0);
  float* gate  = (float*)(wsb + 16777216);
  float* pg    = (float*)(wsb + 33554432);
  float* pl    = (float*)(wsb + 50331648);
  u16*   xnb   = (u16*)(wsb + 67108864);
  u16*   qkvb  = (u16*)(wsb + 75497472);
  u16*   attgb = (u16*)(wsb + 100663296);
  u16*   attlb = (u16*)(wsb + 109051904);
  u16*   wb    = (u16*)(wsb + 117440512);
  u16*   ff1b  = qkvb;
  float* h2    = pg;

  // 0. weights -> bf16
  wconv_kernel<<<(W_TOTAL / 4 + 255) / 256, 256, 0, stream>>>(
      gw_in, lw_in, gw_out, lw_out, gate_w, ff_w1, ff_w2, wb);
  // 1. x_norm = LN1(x)  (bf16)
  ln_kernel<true><<<Mrows, 128, 0, stream>>>(x, nullptr, ln1_g, ln1_b, xnb);
  // 2. local qkv
  mfma_gemm<0, true><<<dim3(1536 / 128, Mrows / 128), 256, 0, stream>>>(
      xnb, wb + W_LWIN, lb_in, qkvb, 1536, 512);
  // 3. local window-2 attention
  attn_local_kernel<<<(Mrows / 2) * 8 / 4, 256, 0, stream>>>(qkvb, attlb);
  // 4. global qkv (overwrites local qkv)
  mfma_gemm<0, true><<<dim3(1536 / 128, Mrows / 128), 256, 0, stream>>>(
      xnb, wb + W_GWIN, gb_in, qkvb, 1536, 512);
  // 5. global causal attention (MFMA flash)
  attn_global_kernel<<<dim3(Sq / 64, 8, Bc), 256, 0, stream>>>(qkvb, attgb);
  // 6. gate = sigmoid(xn @ gate_w^T)
  mfma_gemm<1, false><<<dim3(512 / 128, Mrows / 128), 256, 0, stream>>>(
      xnb, wb + W_GATE, gate_b, gate, 512, 512);
  // 7. pg = attn_g @ gw_out^T
  mfma_gemm<0, false><<<dim3(512 / 128, Mrows / 128), 256, 0, stream>>>(
      attgb, wb + W_GWOUT, gb_out, pg, 512, 512);
  // 8. pl = attn_l @ lw_out^T
  mfma_gemm<0, false><<<dim3(512 / 128, Mrows / 128), 256, 0, stream>>>(
      attlb, wb + W_LWOUT, lb_out, pl, 512, 512);
  // 9. x2 = x + gate*pg + (1-gate)*pl
  combine_kernel<<<(Mrows * Dm / 4) / 256, 256, 0, stream>>>(x, gate, pg, pl, x2);
  // 10. h_norm = LN2(x2) (bf16)
  ln_kernel<true><<<Mrows, 128, 0, stream>>>(x2, nullptr, ln2_g, ln2_b, xnb);
  // 11. ff1 = gelu(hn @ ff_w1^T)
  mfma_gemm<2, true><<<dim3(2048 / 128, Mrows / 128), 256, 0, stream>>>(
      xnb, wb + W_FF1, ff_b1, ff1b, 2048, 512);
  // 12. h2 = ff1 @ ff_w2^T (fp32)
  mfma_gemm<0, false><<<dim3(512 / 128, Mrows / 128), 256, 0, stream>>>(
      ff1b, wb + W_FF2, ff_b2, h2, 512, 2048);
  // 13. out = LN3(x2 + h2) (fp32)
  ln_kernel<false><<<Mrows, 128, 0, stream>>>(x2, h2, ln3_g, ln3_b, out);
}

// Round 8
// 298.401 us; speedup vs baseline: 8.0127x; 1.1934x over previous
//
#include <hip/hip_runtime.h>
#include <math.h>
#include <stdint.h>

typedef unsigned short u16;
typedef __attribute__((ext_vector_type(4))) unsigned short u16x4;
typedef __attribute__((ext_vector_type(8))) unsigned short u16x8;
typedef __attribute__((ext_vector_type(8))) short s16x8;   // 8 bf16 = 4 VGPR (MFMA frag)
typedef __attribute__((ext_vector_type(4))) float f32x4;   // MFMA acc

// Problem constants
constexpr int Bc = 4;
constexpr int Sq = 2048;
constexpr int Dm = 512;
constexpr int Mrows = Bc * Sq;   // 8192

__device__ inline float b2f(u16 h) {
  union { uint32_t u; float f; } x; x.u = (uint32_t)h << 16; return x.f;
}
__device__ inline u16 f2bf(float f) {  // round-to-nearest-even
  union { float f; uint32_t u; } x; x.f = f;
  uint32_t r = (x.u + 0x7fffu + ((x.u >> 16) & 1u)) >> 16;
  return (u16)r;
}

// ---------------------------------------------------------------------------
// Weight fp32->bf16 conversion
// ---------------------------------------------------------------------------
constexpr size_t W_GWIN  = 0;         // 1536x512
constexpr size_t W_LWIN  = 786432;    // 1536x512
constexpr size_t W_GWOUT = 1572864;   // 512x512
constexpr size_t W_LWOUT = 1835008;   // 512x512
constexpr size_t W_GATE  = 2097152;   // 512x512
constexpr size_t W_FF1   = 2359296;   // 2048x512
constexpr size_t W_FF2   = 3407872;   // 512x2048
constexpr size_t W_TOTAL = 4456448;

__global__ __launch_bounds__(256) void wconv_kernel(
    const float* __restrict__ gw_in, const float* __restrict__ lw_in,
    const float* __restrict__ gw_out, const float* __restrict__ lw_out,
    const float* __restrict__ gate_w, const float* __restrict__ ff_w1,
    const float* __restrict__ ff_w2, u16* __restrict__ dst) {
  size_t idx = ((size_t)blockIdx.x * 256 + threadIdx.x) * 4;
  if (idx >= W_TOTAL) return;
  const float* src; size_t base;
  if      (idx < W_LWIN)  { src = gw_in;  base = W_GWIN;  }
  else if (idx < W_GWOUT) { src = lw_in;  base = W_LWIN;  }
  else if (idx < W_LWOUT) { src = gw_out; base = W_GWOUT; }
  else if (idx < W_GATE)  { src = lw_out; base = W_LWOUT; }
  else if (idx < W_FF1)   { src = gate_w; base = W_GATE;  }
  else if (idx < W_FF2)   { src = ff_w1;  base = W_FF1;   }
  else                    { src = ff_w2;  base = W_FF2;   }
  float4 v = *reinterpret_cast<const float4*>(src + (idx - base));
  u16x4 o = { f2bf(v.x), f2bf(v.y), f2bf(v.z), f2bf(v.w) };
  *reinterpret_cast<u16x4*>(dst + idx) = o;
}

// ---------------------------------------------------------------------------
// LayerNorm (optional fused residual add). OB: write bf16 (else fp32).
// ---------------------------------------------------------------------------
template <bool OB>
__global__ __launch_bounds__(128) void ln_kernel(
    const float* __restrict__ in, const float* __restrict__ add,
    const float* __restrict__ g, const float* __restrict__ b,
    void* __restrict__ outp) {
  const int row = blockIdx.x;
  const int t = threadIdx.x;
  float4 v = reinterpret_cast<const float4*>(in + (size_t)row * Dm)[t];
  if (add != nullptr) {
    float4 a = reinterpret_cast<const float4*>(add + (size_t)row * Dm)[t];
    v.x += a.x; v.y += a.y; v.z += a.z; v.w += a.w;
  }
  float s  = v.x + v.y + v.z + v.w;
  float s2 = v.x*v.x + v.y*v.y + v.z*v.z + v.w*v.w;
  #pragma unroll
  for (int o = 32; o > 0; o >>= 1) {
    s  += __shfl_down(s, o);
    s2 += __shfl_down(s2, o);
  }
  __shared__ float rs[2], rs2[2];
  if ((t & 63) == 0) { rs[t >> 6] = s; rs2[t >> 6] = s2; }
  __syncthreads();
  const float mean = (rs[0] + rs[1]) * (1.0f / Dm);
  const float var  = (rs2[0] + rs2[1]) * (1.0f / Dm) - mean * mean;
  const float rstd = rsqrtf(var + 1e-5f);
  float4 gv = reinterpret_cast<const float4*>(g)[t];
  float4 bv = reinterpret_cast<const float4*>(b)[t];
  float ox = (v.x - mean) * rstd * gv.x + bv.x;
  float oy = (v.y - mean) * rstd * gv.y + bv.y;
  float oz = (v.z - mean) * rstd * gv.z + bv.z;
  float ow = (v.w - mean) * rstd * gv.w + bv.w;
  if (OB) {
    u16x4 o4 = { f2bf(ox), f2bf(oy), f2bf(oz), f2bf(ow) };
    *reinterpret_cast<u16x4*>((u16*)outp + (size_t)row * Dm + t * 4) = o4;
  } else {
    float4 o4; o4.x = ox; o4.y = oy; o4.z = oz; o4.w = ow;
    reinterpret_cast<float4*>((float*)outp + (size_t)row * Dm)[t] = o4;
  }
}

// ---------------------------------------------------------------------------
// MFMA GEMM (HW-validated): C = act(A @ W^T + bias)
// ---------------------------------------------------------------------------
template <int ACT, bool OUT_BF16>
__global__ __launch_bounds__(256) void mfma_gemm(
    const u16* __restrict__ A, const u16* __restrict__ W,
    const float* __restrict__ bias, void* __restrict__ Cout, int N, int K) {
  __shared__ u16 sA[128 * 32];
  __shared__ u16 sW[128 * 32];
  const int tid  = threadIdx.x;
  const int wid  = tid >> 6, lane = tid & 63;
  const int lr   = lane & 15, kh = lane >> 4;
  const int wm   = wid >> 1, wn = wid & 1;
  const int m0   = blockIdx.y * 128, n0 = blockIdx.x * 128;
  const int row0 = tid >> 2,        ko0 = (tid & 3) * 8;
  const int row1 = (256 + tid) >> 2, ko1 = (tid & 3) * 8;

  f32x4 acc[4][4] = {};
  for (int k0 = 0; k0 < K; k0 += 32) {
    __syncthreads();
    __builtin_amdgcn_global_load_lds(
        (const __attribute__((address_space(1))) void*)(A + (size_t)(m0 + row0) * K + k0 + ko0),
        (__attribute__((address_space(3))) void*)(sA + wid * 512), 16, 0, 0);
    __builtin_amdgcn_global_load_lds(
        (const __attribute__((address_space(1))) void*)(A + (size_t)(m0 + row1) * K + k0 + ko1),
        (__attribute__((address_space(3))) void*)(sA + 2048 + wid * 512), 16, 0, 0);
    __builtin_amdgcn_global_load_lds(
        (const __attribute__((address_space(1))) void*)(W + (size_t)(n0 + row0) * K + k0 + ko0),
        (__attribute__((address_space(3))) void*)(sW + wid * 512), 16, 0, 0);
    __builtin_amdgcn_global_load_lds(
        (const __attribute__((address_space(1))) void*)(W + (size_t)(n0 + row1) * K + k0 + ko1),
        (__attribute__((address_space(3))) void*)(sW + 2048 + wid * 512), 16, 0, 0);
    __syncthreads();
    s16x8 af[4], bf[4];
    #pragma unroll
    for (int mf = 0; mf < 4; ++mf)
      af[mf] = *reinterpret_cast<const s16x8*>(&sA[(wm * 64 + mf * 16 + lr) * 32 + kh * 8]);
    #pragma unroll
    for (int nf = 0; nf < 4; ++nf)
      bf[nf] = *reinterpret_cast<const s16x8*>(&sW[(wn * 64 + nf * 16 + lr) * 32 + kh * 8]);
    #pragma unroll
    for (int mf = 0; mf < 4; ++mf)
      #pragma unroll
      for (int nf = 0; nf < 4; ++nf)
        acc[mf][nf] = __builtin_amdgcn_mfma_f32_16x16x32_bf16(af[mf], bf[nf], acc[mf][nf], 0, 0, 0);
  }
  #pragma unroll
  for (int nf = 0; nf < 4; ++nf) {
    const int col = n0 + wn * 64 + nf * 16 + lr;
    const float bv = bias[col];
    #pragma unroll
    for (int mf = 0; mf < 4; ++mf) {
      #pragma unroll
      for (int j = 0; j < 4; ++j) {
        const int rowg = m0 + wm * 64 + mf * 16 + kh * 4 + j;
        float v = acc[mf][nf][j] + bv;
        if (ACT == 1) v = 1.0f / (1.0f + expf(-v));
        else if (ACT == 2) v = 0.5f * v * (1.0f + erff(v * 0.70710678118654752440f));
        if (OUT_BF16) ((u16*)Cout)[(size_t)rowg * N + col] = f2bf(v);
        else          ((float*)Cout)[(size_t)rowg * N + col] = v;
      }
    }
  }
}

// ---------------------------------------------------------------------------
// Fused gate/pg/pl + combine: x2 = x + sigmoid(xn@Wg^T+bg) * (attg@Wgo^T+bgo)
//                                  + (1-gate) * (attl@Wlo^T+blo)
// Three K=512 MFMA passes sharing one LDS stage; 128x128 tile per block.
// ---------------------------------------------------------------------------
__global__ __launch_bounds__(256) void fuse3_kernel(
    const u16* __restrict__ A0, const u16* __restrict__ A1, const u16* __restrict__ A2,
    const u16* __restrict__ Wg, const u16* __restrict__ Wgo, const u16* __restrict__ Wlo,
    const float* __restrict__ bg, const float* __restrict__ bgo, const float* __restrict__ blo,
    const float* __restrict__ x, float* __restrict__ x2) {
  constexpr int N = 512, K = 512;
  __shared__ u16 sA[128 * 32];
  __shared__ u16 sW[128 * 32];
  const int tid  = threadIdx.x;
  const int wid  = tid >> 6, lane = tid & 63;
  const int lr   = lane & 15, kh = lane >> 4;
  const int wm   = wid >> 1, wn = wid & 1;
  const int m0   = blockIdx.y * 128, n0 = blockIdx.x * 128;
  const int row0 = tid >> 2,        ko0 = (tid & 3) * 8;
  const int row1 = (256 + tid) >> 2, ko1 = (tid & 3) * 8;

  f32x4 gv[4][4], pgv[4][4], acc[4][4];
  for (int pass = 0; pass < 3; ++pass) {
    const u16* A = (pass == 0) ? A0 : (pass == 1) ? A1 : A2;
    const u16* W = (pass == 0) ? Wg : (pass == 1) ? Wgo : Wlo;
    #pragma unroll
    for (int mf = 0; mf < 4; ++mf)
      #pragma unroll
      for (int nf = 0; nf < 4; ++nf)
        acc[mf][nf] = f32x4{0.f, 0.f, 0.f, 0.f};
    for (int k0 = 0; k0 < K; k0 += 32) {
      __syncthreads();
      __builtin_amdgcn_global_load_lds(
          (const __attribute__((address_space(1))) void*)(A + (size_t)(m0 + row0) * K + k0 + ko0),
          (__attribute__((address_space(3))) void*)(sA + wid * 512), 16, 0, 0);
      __builtin_amdgcn_global_load_lds(
          (const __attribute__((address_space(1))) void*)(A + (size_t)(m0 + row1) * K + k0 + ko1),
          (__attribute__((address_space(3))) void*)(sA + 2048 + wid * 512), 16, 0, 0);
      __builtin_amdgcn_global_load_lds(
          (const __attribute__((address_space(1))) void*)(W + (size_t)(n0 + row0) * K + k0 + ko0),
          (__attribute__((address_space(3))) void*)(sW + wid * 512), 16, 0, 0);
      __builtin_amdgcn_global_load_lds(
          (const __attribute__((address_space(1))) void*)(W + (size_t)(n0 + row1) * K + k0 + ko1),
          (__attribute__((address_space(3))) void*)(sW + 2048 + wid * 512), 16, 0, 0);
      __syncthreads();
      s16x8 af[4], bf[4];
      #pragma unroll
      for (int mf = 0; mf < 4; ++mf)
        af[mf] = *reinterpret_cast<const s16x8*>(&sA[(wm * 64 + mf * 16 + lr) * 32 + kh * 8]);
      #pragma unroll
      for (int nf = 0; nf < 4; ++nf)
        bf[nf] = *reinterpret_cast<const s16x8*>(&sW[(wn * 64 + nf * 16 + lr) * 32 + kh * 8]);
      #pragma unroll
      for (int mf = 0; mf < 4; ++mf)
        #pragma unroll
        for (int nf = 0; nf < 4; ++nf)
          acc[mf][nf] = __builtin_amdgcn_mfma_f32_16x16x32_bf16(af[mf], bf[nf], acc[mf][nf], 0, 0, 0);
    }
    if (pass == 0) {
      #pragma unroll
      for (int nf = 0; nf < 4; ++nf) {
        const float bv = bg[n0 + wn * 64 + nf * 16 + lr];
        #pragma unroll
        for (int mf = 0; mf < 4; ++mf)
          #pragma unroll
          for (int j = 0; j < 4; ++j)
            gv[mf][nf][j] = 1.0f / (1.0f + __expf(-(acc[mf][nf][j] + bv)));
      }
    } else if (pass == 1) {
      #pragma unroll
      for (int nf = 0; nf < 4; ++nf) {
        const float bv = bgo[n0 + wn * 64 + nf * 16 + lr];
        #pragma unroll
        for (int mf = 0; mf < 4; ++mf)
          #pragma unroll
          for (int j = 0; j < 4; ++j)
            pgv[mf][nf][j] = acc[mf][nf][j] + bv;
      }
    }
  }
  // epilogue: acc holds pl pre-bias
  #pragma unroll
  for (int nf = 0; nf < 4; ++nf) {
    const int col = n0 + wn * 64 + nf * 16 + lr;
    const float bv = blo[col];
    #pragma unroll
    for (int mf = 0; mf < 4; ++mf) {
      #pragma unroll
      for (int j = 0; j < 4; ++j) {
        const int rowg = m0 + wm * 64 + mf * 16 + kh * 4 + j;
        const float pl = acc[mf][nf][j] + bv;
        const float g  = gv[mf][nf][j];
        const float pg = pgv[mf][nf][j];
        x2[(size_t)rowg * N + col] = x[(size_t)rowg * N + col] + g * pg + (1.0f - g) * pl;
      }
    }
  }
}

// ---------------------------------------------------------------------------
// MFMA flash attention, SPLIT-K (round 8). qkv bf16 [Mrows][1536].
// Block = one (qt, split) pair: <=8 K-tiles of 64 keys. Grid (80, 8, 4).
// id decode (heavy-first via 79-blockIdx.x):
//   id<8:  qt=id,          s=0,      ns=1
//   id<24: qt=8+(id-8)/2,  s=(id-8)%2,  ns=2
//   id<48: qt=16+(id-24)/3, s=(id-24)%3, ns=3
//   else:  qt=24+(id-48)/4, s=(id-48)%4, ns=4
// ns==1: final bf16 out.  ns>1: unnormalized fp32 O + (m,l) partials.
// ---------------------------------------------------------------------------
__global__ __launch_bounds__(256) void attn_global_kernel(
    const u16* __restrict__ qkv, u16* __restrict__ outb,
    float* __restrict__ opart, float* __restrict__ ml) {
  const int id = 79 - (int)blockIdx.x;   // heavy splits first
  int qt, s, ns;
  if (id < 8)       { qt = id;                s = 0;            ns = 1; }
  else if (id < 24) { int t = id - 8;  qt = 8 + (t >> 1);  s = t & 1;  ns = 2; }
  else if (id < 48) { int t = id - 24; int q3 = t / 3; qt = 16 + q3; s = t - q3 * 3; ns = 3; }
  else              { int t = id - 48; qt = 24 + (t >> 2); s = t & 3;  ns = 4; }
  const int kt0 = s * 8;
  const int kt1 = min(kt0 + 8, qt + 1);

  const int h  = blockIdx.y;
  const int b  = blockIdx.z;
  const int tid = threadIdx.x;
  const int w = tid >> 6, lane = tid & 63;
  const int c = lane & 15, kh = lane >> 4;

  __shared__ u16 Kb[64][72];       // K row-major [kpos][dh]
  __shared__ u16 Vt[64][72];       // V transposed [dh][kpos-swizzled]
  __shared__ u16 Pw[4][16][72];    // per-wave P [q-row][kpos]

  const size_t bbase = (size_t)b * Sq;

  s16x8 aq[2];
  {
    const u16* qg = qkv + (bbase + qt * 64 + w * 16 + c) * 1536 + h * 64 + kh * 8;
    aq[0] = *reinterpret_cast<const s16x8*>(qg);
    aq[1] = *reinterpret_cast<const s16x8*>(qg + 32);
  }

  f32x4 o_acc[4] = {};
  float mrow[4] = { -INFINITY, -INFINITY, -INFINITY, -INFINITY };
  float lrow[4] = { 0.f, 0.f, 0.f, 0.f };
  int qp[4];
  #pragma unroll
  for (int j = 0; j < 4; ++j) qp[j] = qt * 64 + w * 16 + kh * 4 + j;

  const int g2 = tid >> 3, cc = tid & 7;
  const int srow2 = g2 * 2;
  const u16* kg0 = qkv + (bbase + srow2) * 1536 + 512 + h * 64 + cc * 8;
  const size_t tilestep = (size_t)64 * 1536;

  u16x8 ka, kb2, va, vb;
  {
    const u16* p = kg0 + (size_t)kt0 * tilestep;
    ka  = *reinterpret_cast<const u16x8*>(p);
    kb2 = *reinterpret_cast<const u16x8*>(p + 1536);
    va  = *reinterpret_cast<const u16x8*>(p + 512);
    vb  = *reinterpret_cast<const u16x8*>(p + 1536 + 512);
  }

  for (int kt = kt0; kt < kt1; ++kt) {
    __syncthreads();
    {  // staged regs -> LDS
      *reinterpret_cast<u16x8*>(&Kb[srow2][cc * 8])     = ka;
      *reinterpret_cast<u16x8*>(&Kb[srow2 + 1][cc * 8]) = kb2;
      const int sw = srow2 ^ (cc * 8);
      #pragma unroll
      for (int i = 0; i < 8; ++i) {
        uint32_t pk = (uint32_t)va[i] | ((uint32_t)vb[i] << 16);
        *reinterpret_cast<uint32_t*>(&Vt[cc * 8 + i][sw]) = pk;
      }
    }
    __syncthreads();
    if (kt + 1 < kt1) {
      const u16* p = kg0 + (size_t)(kt + 1) * tilestep;
      ka  = *reinterpret_cast<const u16x8*>(p);
      kb2 = *reinterpret_cast<const u16x8*>(p + 1536);
      va  = *reinterpret_cast<const u16x8*>(p + 512);
      vb  = *reinterpret_cast<const u16x8*>(p + 1536 + 512);
    }

    // ---- QK^T ----
    f32x4 s_acc[4] = {};
    #pragma unroll
    for (int nb = 0; nb < 4; ++nb) {
      #pragma unroll
      for (int kk = 0; kk < 2; ++kk) {
        s16x8 bk = *reinterpret_cast<const s16x8*>(&Kb[nb * 16 + c][kk * 32 + kh * 8]);
        s_acc[nb] = __builtin_amdgcn_mfma_f32_16x16x32_bf16(aq[kk], bk, s_acc[nb], 0, 0, 0);
      }
    }

    // ---- softmax ----
    const bool diag = (kt == qt);
    float p[4][4];
    float tm[4] = { -INFINITY, -INFINITY, -INFINITY, -INFINITY };
    #pragma unroll
    for (int nb = 0; nb < 4; ++nb) {
      #pragma unroll
      for (int j = 0; j < 4; ++j) {
        float sv = s_acc[nb][j] * 0.125f;
        if (diag && (kt * 64 + nb * 16 + c) > qp[j]) sv = -INFINITY;
        p[nb][j] = sv;
        tm[j] = fmaxf(tm[j], sv);
      }
    }
    #pragma unroll
    for (int o = 1; o < 16; o <<= 1) {
      #pragma unroll
      for (int j = 0; j < 4; ++j) tm[j] = fmaxf(tm[j], __shfl_xor(tm[j], o));
    }
    float corr[4], psum[4];
    #pragma unroll
    for (int j = 0; j < 4; ++j) {
      const float mnew = fmaxf(mrow[j], tm[j]);
      corr[j] = __expf(mrow[j] - mnew);
      mrow[j] = mnew;
      psum[j] = 0.f;
      #pragma unroll
      for (int nb = 0; nb < 4; ++nb) {
        p[nb][j] = __expf(p[nb][j] - mnew);
        psum[j] += p[nb][j];
      }
    }
    #pragma unroll
    for (int o = 1; o < 16; o <<= 1) {
      #pragma unroll
      for (int j = 0; j < 4; ++j) psum[j] += __shfl_xor(psum[j], o);
    }
    #pragma unroll
    for (int j = 0; j < 4; ++j) lrow[j] = lrow[j] * corr[j] + psum[j];
    #pragma unroll
    for (int nb2 = 0; nb2 < 4; ++nb2)
      #pragma unroll
      for (int j = 0; j < 4; ++j) o_acc[nb2][j] *= corr[j];

    #pragma unroll
    for (int nb = 0; nb < 4; ++nb)
      #pragma unroll
      for (int j = 0; j < 4; ++j)
        Pw[w][kh * 4 + j][nb * 16 + c] = f2bf(p[nb][j]);

    // ---- PV ----
    #pragma unroll
    for (int kk = 0; kk < 2; ++kk) {
      s16x8 ap = *reinterpret_cast<const s16x8*>(&Pw[w][c][kk * 32 + kh * 8]);
      #pragma unroll
      for (int nb2 = 0; nb2 < 4; ++nb2) {
        const int dh = nb2 * 16 + c;
        const int f8 = ((dh >> 3) & 7) * 8;
        s16x8 bv = *reinterpret_cast<const s16x8*>(&Vt[dh][(kk * 32 + kh * 8) ^ f8]);
        o_acc[nb2] = __builtin_amdgcn_mfma_f32_16x16x32_bf16(ap, bv, o_acc[nb2], 0, 0, 0);
      }
    }
  }

  if (ns == 1) {
    float invl[4];
    #pragma unroll
    for (int j = 0; j < 4; ++j) invl[j] = 1.0f / lrow[j];
    #pragma unroll
    for (int nb2 = 0; nb2 < 4; ++nb2)
      #pragma unroll
      for (int j = 0; j < 4; ++j) {
        const int qrow = qt * 64 + w * 16 + kh * 4 + j;
        outb[(bbase + qrow) * Dm + h * 64 + nb2 * 16 + c] = f2bf(o_acc[nb2][j] * invl[j]);
      }
  } else {
    const size_t pid = (size_t)(b * 8 + h) * 80 + id;
    float* op = opart + pid * 4096;
    #pragma unroll
    for (int nb2 = 0; nb2 < 4; ++nb2)
      #pragma unroll
      for (int j = 0; j < 4; ++j)
        op[(w * 16 + kh * 4 + j) * 64 + nb2 * 16 + c] = o_acc[nb2][j];
    if (c == 0) {
      #pragma unroll
      for (int j = 0; j < 4; ++j) {
        ml[pid * 128 + w * 16 + kh * 4 + j]      = mrow[j];
        ml[pid * 128 + 64 + w * 16 + kh * 4 + j] = lrow[j];
      }
    }
  }
}

// ---------------------------------------------------------------------------
// Flash split merge: O = sum_s e^{m_s-M} O_s / sum_s e^{m_s-M} l_s
// Grid (24, 8, 4): qt = 8 + blockIdx.x. 256 thr: row=tid>>2, 16 dims each.
// ---------------------------------------------------------------------------
__global__ __launch_bounds__(256) void attn_combine_kernel(
    const float* __restrict__ opart, const float* __restrict__ ml,
    u16* __restrict__ outb) {
  const int qt = 8 + (int)blockIdx.x;
  const int h = blockIdx.y, b = blockIdx.z;
  int ns, idb;
  if (qt < 16)      { ns = 2; idb = 8 + (qt - 8) * 2; }
  else if (qt < 24) { ns = 3; idb = 24 + (qt - 16) * 3; }
  else              { ns = 4; idb = 48 + (qt - 24) * 4; }
  const int r  = threadIdx.x >> 2;
  const int d0 = (threadIdx.x & 3) * 16;
  const size_t pidb = (size_t)(b * 8 + h) * 80 + idb;

  float M = -INFINITY;
  for (int s2 = 0; s2 < ns; ++s2)
    M = fmaxf(M, ml[(pidb + s2) * 128 + r]);
  float L = 0.f;
  f32x4 o0 = {}, o1 = {}, o2 = {}, o3 = {};
  for (int s2 = 0; s2 < ns; ++s2) {
    const size_t pp = pidb + s2;
    const float wgt = __expf(ml[pp * 128 + r] - M);
    L += wgt * ml[pp * 128 + 64 + r];
    const float* op = opart + pp * 4096 + (size_t)r * 64 + d0;
    f32x4 a0 = *reinterpret_cast<const f32x4*>(op);
    f32x4 a1 = *reinterpret_cast<const f32x4*>(op + 4);
    f32x4 a2 = *reinterpret_cast<const f32x4*>(op + 8);
    f32x4 a3 = *reinterpret_cast<const f32x4*>(op + 12);
    #pragma unroll
    for (int i = 0; i < 4; ++i) {
      o0[i] += wgt * a0[i]; o1[i] += wgt * a1[i];
      o2[i] += wgt * a2[i]; o3[i] += wgt * a3[i];
    }
  }
  const float invL = 1.0f / L;
  u16* dst = outb + ((size_t)b * Sq + qt * 64 + r) * Dm + h * 64 + d0;
  u16x4 w0 = { f2bf(o0[0]*invL), f2bf(o0[1]*invL), f2bf(o0[2]*invL), f2bf(o0[3]*invL) };
  u16x4 w1 = { f2bf(o1[0]*invL), f2bf(o1[1]*invL), f2bf(o1[2]*invL), f2bf(o1[3]*invL) };
  u16x4 w2 = { f2bf(o2[0]*invL), f2bf(o2[1]*invL), f2bf(o2[2]*invL), f2bf(o2[3]*invL) };
  u16x4 w3 = { f2bf(o3[0]*invL), f2bf(o3[1]*invL), f2bf(o3[2]*invL), f2bf(o3[3]*invL) };
  *reinterpret_cast<u16x4*>(dst)      = w0;
  *reinterpret_cast<u16x4*>(dst + 4)  = w1;
  *reinterpret_cast<u16x4*>(dst + 8)  = w2;
  *reinterpret_cast<u16x4*>(dst + 12) = w3;
}

// ---------------------------------------------------------------------------
// Local window-2 attention (bf16 in/out): one wave per (pair, head).
// ---------------------------------------------------------------------------
__global__ __launch_bounds__(256) void attn_local_kernel(
    const u16* __restrict__ qkv, u16* __restrict__ outb) {
  const int unit = blockIdx.x * 4 + (threadIdx.x >> 6);  // (pair<<3)|h
  const int lane = threadIdx.x & 63;
  const int h = unit & 7;
  const size_t pair = (size_t)(unit >> 3);
  const u16* r0 = qkv + pair * 2 * 1536;
  const u16* r1 = r0 + 1536;
  const int off = h * 64 + lane;
  const float q0 = b2f(r0[off]), k0 = b2f(r0[512 + off]), v0 = b2f(r0[1024 + off]);
  const float q1 = b2f(r1[off]), k1 = b2f(r1[512 + off]), v1 = b2f(r1[1024 + off]);
  float s00 = q0 * k0, s01 = q0 * k1, s10 = q1 * k0, s11 = q1 * k1;
  #pragma unroll
  for (int o = 1; o < 64; o <<= 1) {
    s00 += __shfl_xor(s00, o); s01 += __shfl_xor(s01, o);
    s10 += __shfl_xor(s10, o); s11 += __shfl_xor(s11, o);
  }
  s00 *= 0.125f; s01 *= 0.125f; s10 *= 0.125f; s11 *= 0.125f;
  const float m0 = fmaxf(s00, s01), m1 = fmaxf(s10, s11);
  const float e00 = expf(s00 - m0), e01 = expf(s01 - m0);
  const float e10 = expf(s10 - m1), e11 = expf(s11 - m1);
  const float w0 = 1.0f / (e00 + e01), w1 = 1.0f / (e10 + e11);
  outb[pair * 2 * Dm + off]       = f2bf((e00 * v0 + e01 * v1) * w0);
  outb[(pair * 2 + 1) * Dm + off] = f2bf((e10 * v0 + e11 * v1) * w1);
}

// ---------------------------------------------------------------------------
extern "C" void kernel_launch(void* const* d_in, const int* in_sizes, int n_in,
                              void* d_out, int out_size, void* d_ws, size_t ws_size,
                              hipStream_t stream) {
  const float* x      = (const float*)d_in[0];
  const float* ln1_g  = (const float*)d_in[1];
  const float* ln1_b  = (const float*)d_in[2];
  const float* ln2_g  = (const float*)d_in[3];
  const float* ln2_b  = (const float*)d_in[4];
  const float* ln3_g  = (const float*)d_in[5];
  const float* ln3_b  = (const float*)d_in[6];
  const float* gw_in  = (const float*)d_in[7];
  const float* gb_in  = (const float*)d_in[8];
  const float* gw_out = (const float*)d_in[9];
  const float* gb_out = (const float*)d_in[10];
  const float* lw_in  = (const float*)d_in[11];
  const float* lb_in  = (const float*)d_in[12];
  const float* lw_out = (const float*)d_in[13];
  const float* lb_out = (const float*)d_in[14];
  const float* gate_w = (const float*)d_in[15];
  const float* gate_b = (const float*)d_in[16];
  const float* ff_w1  = (const float*)d_in[17];
  const float* ff_b1  = (const float*)d_in[18];
  const float* ff_w2  = (const float*)d_in[19];
  const float* ff_b2  = (const float*)d_in[20];
  float* out = (float*)d_out;
  char* wsb  = (char*)d_ws;

  // workspace (liveness-disjoint overlays):
  //   [0 .. 41.94MB)  opart (attn partials, dead after combine)
  //   [41.94 .. 43.25MB) ml
  //   [0 .. 16.78MB)  x2   (written by fuse3, after combine)
  //   [16.78 .. 33.55MB) h2 (written step 12)
  float* opart = (float*)(wsb + 0);
  float* ml    = (float*)(wsb + 41943040);
  float* x2    = (float*)(wsb + 0);
  float* h2    = (float*)(wsb + 16777216);
  u16*   xnb   = (u16*)(wsb + 67108864);
  u16*   qkvb  = (u16*)(wsb + 75497472);
  u16*   attgb = (u16*)(wsb + 100663296);
  u16*   attlb = (u16*)(wsb + 109051904);
  u16*   wb    = (u16*)(wsb + 117440512);
  u16*   ff1b  = qkvb;

  // 0. weights -> bf16
  wconv_kernel<<<(W_TOTAL / 4 + 255) / 256, 256, 0, stream>>>(
      gw_in, lw_in, gw_out, lw_out, gate_w, ff_w1, ff_w2, wb);
  // 1. x_norm = LN1(x)
  ln_kernel<true><<<Mrows, 128, 0, stream>>>(x, nullptr, ln1_g, ln1_b, xnb);
  // 2. local qkv
  mfma_gemm<0, true><<<dim3(1536 / 128, Mrows / 128), 256, 0, stream>>>(
      xnb, wb + W_LWIN, lb_in, qkvb, 1536, 512);
  // 3. local window-2 attention
  attn_local_kernel<<<(Mrows / 2) * 8 / 4, 256, 0, stream>>>(qkvb, attlb);
  // 4. global qkv
  mfma_gemm<0, true><<<dim3(1536 / 128, Mrows / 128), 256, 0, stream>>>(
      xnb, wb + W_GWIN, gb_in, qkvb, 1536, 512);
  // 5. global causal attention (split-K flash) + merge
  attn_global_kernel<<<dim3(80, 8, Bc), 256, 0, stream>>>(qkvb, attgb, opart, ml);
  attn_combine_kernel<<<dim3(24, 8, Bc), 256, 0, stream>>>(opart, ml, attgb);
  // 6-9 fused: x2 = x + gate*pg + (1-gate)*pl
  fuse3_kernel<<<dim3(512 / 128, Mrows / 128), 256, 0, stream>>>(
      xnb, attgb, attlb, wb + W_GATE, wb + W_GWOUT, wb + W_LWOUT,
      gate_b, gb_out, lb_out, x, x2);
  // 10. h_norm = LN2(x2)
  ln_kernel<true><<<Mrows, 128, 0, stream>>>(x2, nullptr, ln2_g, ln2_b, xnb);
  // 11. ff1 = gelu(hn @ ff_w1^T)
  mfma_gemm<2, true><<<dim3(2048 / 128, Mrows / 128), 256, 0, stream>>>(
      xnb, wb + W_FF1, ff_b1, ff1b, 2048, 512);
  // 12. h2 = ff1 @ ff_w2^T
  mfma_gemm<0, false><<<dim3(512 / 128, Mrows / 128), 256, 0, stream>>>(
      ff1b, wb + W_FF2, ff_b2, h2, 512, 2048);
  // 13. out = LN3(x2 + h2)
  ln_kernel<false><<<Mrows, 128, 0, stream>>>(x2, h2, ln3_g, ln3_b, out);
}

// Round 9
// 280.186 us; speedup vs baseline: 8.5336x; 1.0650x over previous
//
#include <hip/hip_runtime.h>
#include <math.h>
#include <stdint.h>

typedef unsigned short u16;
typedef __attribute__((ext_vector_type(4))) unsigned short u16x4;
typedef __attribute__((ext_vector_type(8))) unsigned short u16x8;
typedef __attribute__((ext_vector_type(8))) short s16x8;   // 8 bf16 = 4 VGPR (MFMA frag)
typedef __attribute__((ext_vector_type(4))) float f32x4;   // MFMA acc

// Problem constants
constexpr int Bc = 4;
constexpr int Sq = 2048;
constexpr int Dm = 512;
constexpr int Mrows = Bc * Sq;   // 8192
constexpr int QW = 3072;         // merged qkv row width (global 0..1535 | local 1536..3071)

__device__ inline float b2f(u16 h) {
  union { uint32_t u; float f; } x; x.u = (uint32_t)h << 16; return x.f;
}
__device__ inline u16 f2bf(float f) {  // round-to-nearest-even
  union { float f; uint32_t u; } x; x.f = f;
  uint32_t r = (x.u + 0x7fffu + ((x.u >> 16) & 1u)) >> 16;
  return (u16)r;
}

// ---------------------------------------------------------------------------
// Weight fp32->bf16 conversion
// ---------------------------------------------------------------------------
constexpr size_t W_GWIN  = 0;         // 1536x512   (merged QKV rows 0..1535)
constexpr size_t W_LWIN  = 786432;    // 1536x512   (merged QKV rows 1536..3071)
constexpr size_t W_GWOUT = 1572864;   // 512x512
constexpr size_t W_LWOUT = 1835008;   // 512x512
constexpr size_t W_GATE  = 2097152;   // 512x512
constexpr size_t W_FF1   = 2359296;   // 2048x512
constexpr size_t W_FF2   = 3407872;   // 512x2048
constexpr size_t W_TOTAL = 4456448;

__global__ __launch_bounds__(256) void wconv_kernel(
    const float* __restrict__ gw_in, const float* __restrict__ lw_in,
    const float* __restrict__ gw_out, const float* __restrict__ lw_out,
    const float* __restrict__ gate_w, const float* __restrict__ ff_w1,
    const float* __restrict__ ff_w2, u16* __restrict__ dst) {
  size_t idx = ((size_t)blockIdx.x * 256 + threadIdx.x) * 4;
  if (idx >= W_TOTAL) return;
  const float* src; size_t base;
  if      (idx < W_LWIN)  { src = gw_in;  base = W_GWIN;  }
  else if (idx < W_GWOUT) { src = lw_in;  base = W_LWIN;  }
  else if (idx < W_LWOUT) { src = gw_out; base = W_GWOUT; }
  else if (idx < W_GATE)  { src = lw_out; base = W_LWOUT; }
  else if (idx < W_FF1)   { src = gate_w; base = W_GATE;  }
  else if (idx < W_FF2)   { src = ff_w1;  base = W_FF1;   }
  else                    { src = ff_w2;  base = W_FF2;   }
  float4 v = *reinterpret_cast<const float4*>(src + (idx - base));
  u16x4 o = { f2bf(v.x), f2bf(v.y), f2bf(v.z), f2bf(v.w) };
  *reinterpret_cast<u16x4*>(dst + idx) = o;
}

// ---------------------------------------------------------------------------
// LayerNorm (optional fused residual adds). OB: write bf16 (else fp32).
// ---------------------------------------------------------------------------
template <bool OB>
__global__ __launch_bounds__(128) void ln_kernel(
    const float* __restrict__ in, const float* __restrict__ add,
    const float* __restrict__ add2,
    const float* __restrict__ g, const float* __restrict__ b,
    void* __restrict__ outp) {
  const int row = blockIdx.x;
  const int t = threadIdx.x;
  float4 v = reinterpret_cast<const float4*>(in + (size_t)row * Dm)[t];
  if (add != nullptr) {
    float4 a = reinterpret_cast<const float4*>(add + (size_t)row * Dm)[t];
    v.x += a.x; v.y += a.y; v.z += a.z; v.w += a.w;
  }
  if (add2 != nullptr) {
    float4 a = reinterpret_cast<const float4*>(add2 + (size_t)row * Dm)[t];
    v.x += a.x; v.y += a.y; v.z += a.z; v.w += a.w;
  }
  float s  = v.x + v.y + v.z + v.w;
  float s2 = v.x*v.x + v.y*v.y + v.z*v.z + v.w*v.w;
  #pragma unroll
  for (int o = 32; o > 0; o >>= 1) {
    s  += __shfl_down(s, o);
    s2 += __shfl_down(s2, o);
  }
  __shared__ float rs[2], rs2[2];
  if ((t & 63) == 0) { rs[t >> 6] = s; rs2[t >> 6] = s2; }
  __syncthreads();
  const float mean = (rs[0] + rs[1]) * (1.0f / Dm);
  const float var  = (rs2[0] + rs2[1]) * (1.0f / Dm) - mean * mean;
  const float rstd = rsqrtf(var + 1e-5f);
  float4 gv = reinterpret_cast<const float4*>(g)[t];
  float4 bv = reinterpret_cast<const float4*>(b)[t];
  float ox = (v.x - mean) * rstd * gv.x + bv.x;
  float oy = (v.y - mean) * rstd * gv.y + bv.y;
  float oz = (v.z - mean) * rstd * gv.z + bv.z;
  float ow = (v.w - mean) * rstd * gv.w + bv.w;
  if (OB) {
    u16x4 o4 = { f2bf(ox), f2bf(oy), f2bf(oz), f2bf(ow) };
    *reinterpret_cast<u16x4*>((u16*)outp + (size_t)row * Dm + t * 4) = o4;
  } else {
    float4 o4; o4.x = ox; o4.y = oy; o4.z = oz; o4.w = ow;
    reinterpret_cast<float4*>((float*)outp + (size_t)row * Dm)[t] = o4;
  }
}

// ---------------------------------------------------------------------------
// MFMA GEMM (HW-validated): C = act(A @ W^T + bias)
// Dual-bias: bias2 != nullptr -> col >= bsplit uses bias2[col-bsplit].
// ---------------------------------------------------------------------------
template <int ACT, bool OUT_BF16>
__global__ __launch_bounds__(256) void mfma_gemm(
    const u16* __restrict__ A, const u16* __restrict__ W,
    const float* __restrict__ bias, const float* __restrict__ bias2, int bsplit,
    void* __restrict__ Cout, int N, int K) {
  __shared__ u16 sA[128 * 32];
  __shared__ u16 sW[128 * 32];
  const int tid  = threadIdx.x;
  const int wid  = tid >> 6, lane = tid & 63;
  const int lr   = lane & 15, kh = lane >> 4;
  const int wm   = wid >> 1, wn = wid & 1;
  const int m0   = blockIdx.y * 128, n0 = blockIdx.x * 128;
  const int row0 = tid >> 2,        ko0 = (tid & 3) * 8;
  const int row1 = (256 + tid) >> 2, ko1 = (tid & 3) * 8;

  f32x4 acc[4][4] = {};
  for (int k0 = 0; k0 < K; k0 += 32) {
    __syncthreads();
    __builtin_amdgcn_global_load_lds(
        (const __attribute__((address_space(1))) void*)(A + (size_t)(m0 + row0) * K + k0 + ko0),
        (__attribute__((address_space(3))) void*)(sA + wid * 512), 16, 0, 0);
    __builtin_amdgcn_global_load_lds(
        (const __attribute__((address_space(1))) void*)(A + (size_t)(m0 + row1) * K + k0 + ko1),
        (__attribute__((address_space(3))) void*)(sA + 2048 + wid * 512), 16, 0, 0);
    __builtin_amdgcn_global_load_lds(
        (const __attribute__((address_space(1))) void*)(W + (size_t)(n0 + row0) * K + k0 + ko0),
        (__attribute__((address_space(3))) void*)(sW + wid * 512), 16, 0, 0);
    __builtin_amdgcn_global_load_lds(
        (const __attribute__((address_space(1))) void*)(W + (size_t)(n0 + row1) * K + k0 + ko1),
        (__attribute__((address_space(3))) void*)(sW + 2048 + wid * 512), 16, 0, 0);
    __syncthreads();
    s16x8 af[4], bf[4];
    #pragma unroll
    for (int mf = 0; mf < 4; ++mf)
      af[mf] = *reinterpret_cast<const s16x8*>(&sA[(wm * 64 + mf * 16 + lr) * 32 + kh * 8]);
    #pragma unroll
    for (int nf = 0; nf < 4; ++nf)
      bf[nf] = *reinterpret_cast<const s16x8*>(&sW[(wn * 64 + nf * 16 + lr) * 32 + kh * 8]);
    #pragma unroll
    for (int mf = 0; mf < 4; ++mf)
      #pragma unroll
      for (int nf = 0; nf < 4; ++nf)
        acc[mf][nf] = __builtin_amdgcn_mfma_f32_16x16x32_bf16(af[mf], bf[nf], acc[mf][nf], 0, 0, 0);
  }
  #pragma unroll
  for (int nf = 0; nf < 4; ++nf) {
    const int col = n0 + wn * 64 + nf * 16 + lr;
    const float bv = (bias2 != nullptr && col >= bsplit) ? bias2[col - bsplit] : bias[col];
    #pragma unroll
    for (int mf = 0; mf < 4; ++mf) {
      #pragma unroll
      for (int j = 0; j < 4; ++j) {
        const int rowg = m0 + wm * 64 + mf * 16 + kh * 4 + j;
        float v = acc[mf][nf][j] + bv;
        if (ACT == 1) v = 1.0f / (1.0f + expf(-v));
        else if (ACT == 2) v = 0.5f * v * (1.0f + erff(v * 0.70710678118654752440f));
        if (OUT_BF16) ((u16*)Cout)[(size_t)rowg * N + col] = f2bf(v);
        else          ((float*)Cout)[(size_t)rowg * N + col] = v;
      }
    }
  }
}

// ---------------------------------------------------------------------------
// Split-K MFMA GEMM for FFN2: z = blockIdx.z selects K-half and output buffer.
// C_z = A[:, zK/2:(z+1)K/2] @ W[:, same]^T  (+bias only in z==0). fp32 out.
// ---------------------------------------------------------------------------
__global__ __launch_bounds__(256) void mfma_gemm_sk(
    const u16* __restrict__ A, const u16* __restrict__ W,
    const float* __restrict__ bias, float* __restrict__ C0, float* __restrict__ C1,
    int N, int Kt) {
  __shared__ u16 sA[128 * 32];
  __shared__ u16 sW[128 * 32];
  const int tid  = threadIdx.x;
  const int wid  = tid >> 6, lane = tid & 63;
  const int lr   = lane & 15, kh = lane >> 4;
  const int wm   = wid >> 1, wn = wid & 1;
  const int m0   = blockIdx.y * 128, n0 = blockIdx.x * 128;
  const int z    = blockIdx.z;
  const int kbeg = z * (Kt / 2), kend = kbeg + (Kt / 2);
  const int row0 = tid >> 2,        ko0 = (tid & 3) * 8;
  const int row1 = (256 + tid) >> 2, ko1 = (tid & 3) * 8;

  f32x4 acc[4][4] = {};
  for (int k0 = kbeg; k0 < kend; k0 += 32) {
    __syncthreads();
    __builtin_amdgcn_global_load_lds(
        (const __attribute__((address_space(1))) void*)(A + (size_t)(m0 + row0) * Kt + k0 + ko0),
        (__attribute__((address_space(3))) void*)(sA + wid * 512), 16, 0, 0);
    __builtin_amdgcn_global_load_lds(
        (const __attribute__((address_space(1))) void*)(A + (size_t)(m0 + row1) * Kt + k0 + ko1),
        (__attribute__((address_space(3))) void*)(sA + 2048 + wid * 512), 16, 0, 0);
    __builtin_amdgcn_global_load_lds(
        (const __attribute__((address_space(1))) void*)(W + (size_t)(n0 + row0) * Kt + k0 + ko0),
        (__attribute__((address_space(3))) void*)(sW + wid * 512), 16, 0, 0);
    __builtin_amdgcn_global_load_lds(
        (const __attribute__((address_space(1))) void*)(W + (size_t)(n0 + row1) * Kt + k0 + ko1),
        (__attribute__((address_space(3))) void*)(sW + 2048 + wid * 512), 16, 0, 0);
    __syncthreads();
    s16x8 af[4], bf[4];
    #pragma unroll
    for (int mf = 0; mf < 4; ++mf)
      af[mf] = *reinterpret_cast<const s16x8*>(&sA[(wm * 64 + mf * 16 + lr) * 32 + kh * 8]);
    #pragma unroll
    for (int nf = 0; nf < 4; ++nf)
      bf[nf] = *reinterpret_cast<const s16x8*>(&sW[(wn * 64 + nf * 16 + lr) * 32 + kh * 8]);
    #pragma unroll
    for (int mf = 0; mf < 4; ++mf)
      #pragma unroll
      for (int nf = 0; nf < 4; ++nf)
        acc[mf][nf] = __builtin_amdgcn_mfma_f32_16x16x32_bf16(af[mf], bf[nf], acc[mf][nf], 0, 0, 0);
  }
  float* C = z ? C1 : C0;
  #pragma unroll
  for (int nf = 0; nf < 4; ++nf) {
    const int col = n0 + wn * 64 + nf * 16 + lr;
    const float bv = z ? 0.0f : bias[col];
    #pragma unroll
    for (int mf = 0; mf < 4; ++mf) {
      #pragma unroll
      for (int j = 0; j < 4; ++j) {
        const int rowg = m0 + wm * 64 + mf * 16 + kh * 4 + j;
        C[(size_t)rowg * N + col] = acc[mf][nf][j] + bv;
      }
    }
  }
}

// ---------------------------------------------------------------------------
// Fused gate/pg/pl + combine: x2 = x + sigmoid(xn@Wg^T+bg)*(attg@Wgo^T+bgo)
//                                  + (1-gate)*(attl@Wlo^T+blo)
// ---------------------------------------------------------------------------
__global__ __launch_bounds__(256) void fuse3_kernel(
    const u16* __restrict__ A0, const u16* __restrict__ A1, const u16* __restrict__ A2,
    const u16* __restrict__ Wg, const u16* __restrict__ Wgo, const u16* __restrict__ Wlo,
    const float* __restrict__ bg, const float* __restrict__ bgo, const float* __restrict__ blo,
    const float* __restrict__ x, float* __restrict__ x2) {
  constexpr int N = 512, K = 512;
  __shared__ u16 sA[128 * 32];
  __shared__ u16 sW[128 * 32];
  const int tid  = threadIdx.x;
  const int wid  = tid >> 6, lane = tid & 63;
  const int lr   = lane & 15, kh = lane >> 4;
  const int wm   = wid >> 1, wn = wid & 1;
  const int m0   = blockIdx.y * 128, n0 = blockIdx.x * 128;
  const int row0 = tid >> 2,        ko0 = (tid & 3) * 8;
  const int row1 = (256 + tid) >> 2, ko1 = (tid & 3) * 8;

  f32x4 gv[4][4], pgv[4][4], acc[4][4];
  for (int pass = 0; pass < 3; ++pass) {
    const u16* A = (pass == 0) ? A0 : (pass == 1) ? A1 : A2;
    const u16* W = (pass == 0) ? Wg : (pass == 1) ? Wgo : Wlo;
    #pragma unroll
    for (int mf = 0; mf < 4; ++mf)
      #pragma unroll
      for (int nf = 0; nf < 4; ++nf)
        acc[mf][nf] = f32x4{0.f, 0.f, 0.f, 0.f};
    for (int k0 = 0; k0 < K; k0 += 32) {
      __syncthreads();
      __builtin_amdgcn_global_load_lds(
          (const __attribute__((address_space(1))) void*)(A + (size_t)(m0 + row0) * K + k0 + ko0),
          (__attribute__((address_space(3))) void*)(sA + wid * 512), 16, 0, 0);
      __builtin_amdgcn_global_load_lds(
          (const __attribute__((address_space(1))) void*)(A + (size_t)(m0 + row1) * K + k0 + ko1),
          (__attribute__((address_space(3))) void*)(sA + 2048 + wid * 512), 16, 0, 0);
      __builtin_amdgcn_global_load_lds(
          (const __attribute__((address_space(1))) void*)(W + (size_t)(n0 + row0) * K + k0 + ko0),
          (__attribute__((address_space(3))) void*)(sW + wid * 512), 16, 0, 0);
      __builtin_amdgcn_global_load_lds(
          (const __attribute__((address_space(1))) void*)(W + (size_t)(n0 + row1) * K + k0 + ko1),
          (__attribute__((address_space(3))) void*)(sW + 2048 + wid * 512), 16, 0, 0);
      __syncthreads();
      s16x8 af[4], bf[4];
      #pragma unroll
      for (int mf = 0; mf < 4; ++mf)
        af[mf] = *reinterpret_cast<const s16x8*>(&sA[(wm * 64 + mf * 16 + lr) * 32 + kh * 8]);
      #pragma unroll
      for (int nf = 0; nf < 4; ++nf)
        bf[nf] = *reinterpret_cast<const s16x8*>(&sW[(wn * 64 + nf * 16 + lr) * 32 + kh * 8]);
      #pragma unroll
      for (int mf = 0; mf < 4; ++mf)
        #pragma unroll
        for (int nf = 0; nf < 4; ++nf)
          acc[mf][nf] = __builtin_amdgcn_mfma_f32_16x16x32_bf16(af[mf], bf[nf], acc[mf][nf], 0, 0, 0);
    }
    if (pass == 0) {
      #pragma unroll
      for (int nf = 0; nf < 4; ++nf) {
        const float bv = bg[n0 + wn * 64 + nf * 16 + lr];
        #pragma unroll
        for (int mf = 0; mf < 4; ++mf)
          #pragma unroll
          for (int j = 0; j < 4; ++j)
            gv[mf][nf][j] = 1.0f / (1.0f + __expf(-(acc[mf][nf][j] + bv)));
      }
    } else if (pass == 1) {
      #pragma unroll
      for (int nf = 0; nf < 4; ++nf) {
        const float bv = bgo[n0 + wn * 64 + nf * 16 + lr];
        #pragma unroll
        for (int mf = 0; mf < 4; ++mf)
          #pragma unroll
          for (int j = 0; j < 4; ++j)
            pgv[mf][nf][j] = acc[mf][nf][j] + bv;
      }
    }
  }
  #pragma unroll
  for (int nf = 0; nf < 4; ++nf) {
    const int col = n0 + wn * 64 + nf * 16 + lr;
    const float bv = blo[col];
    #pragma unroll
    for (int mf = 0; mf < 4; ++mf) {
      #pragma unroll
      for (int j = 0; j < 4; ++j) {
        const int rowg = m0 + wm * 64 + mf * 16 + kh * 4 + j;
        const float pl = acc[mf][nf][j] + bv;
        const float g  = gv[mf][nf][j];
        const float pg = pgv[mf][nf][j];
        x2[(size_t)rowg * N + col] = x[(size_t)rowg * N + col] + g * pg + (1.0f - g) * pl;
      }
    }
  }
}

// ---------------------------------------------------------------------------
// MFMA flash attention, SPLIT-K. qkv bf16 [Mrows][3072] (global at cols 0..1535).
// Round 9: deferred l-reduce (once per block), base-2 exp with absorbed scale.
// Grid (80, 8, 4); id decode heavy-first. ns==1 -> bf16 out; else fp32 partials.
// ---------------------------------------------------------------------------
__global__ __launch_bounds__(256) void attn_global_kernel(
    const u16* __restrict__ qkv, u16* __restrict__ outb,
    float* __restrict__ opart, float* __restrict__ ml) {
  const int id = 79 - (int)blockIdx.x;   // heavy splits first
  int qt, s, ns;
  if (id < 8)       { qt = id;                s = 0;            ns = 1; }
  else if (id < 24) { int t = id - 8;  qt = 8 + (t >> 1);  s = t & 1;  ns = 2; }
  else if (id < 48) { int t = id - 24; int q3 = t / 3; qt = 16 + q3; s = t - q3 * 3; ns = 3; }
  else              { int t = id - 48; qt = 24 + (t >> 2); s = t & 3;  ns = 4; }
  const int kt0 = s * 8;
  const int kt1 = min(kt0 + 8, qt + 1);

  const int h  = blockIdx.y;
  const int b  = blockIdx.z;
  const int tid = threadIdx.x;
  const int w = tid >> 6, lane = tid & 63;
  const int c = lane & 15, kh = lane >> 4;
  constexpr float TS = 0.125f * 1.44269504088896f;   // scale * log2(e)

  __shared__ u16 Kb[64][72];
  __shared__ u16 Vt[64][72];
  __shared__ u16 Pw[4][16][72];

  const size_t bbase = (size_t)b * Sq;

  s16x8 aq[2];
  {
    const u16* qg = qkv + (bbase + qt * 64 + w * 16 + c) * QW + h * 64 + kh * 8;
    aq[0] = *reinterpret_cast<const s16x8*>(qg);
    aq[1] = *reinterpret_cast<const s16x8*>(qg + 32);
  }

  f32x4 o_acc[4] = {};
  float mrow[4] = { -INFINITY, -INFINITY, -INFINITY, -INFINITY };
  float lrow[4] = { 0.f, 0.f, 0.f, 0.f };   // lane-partial; reduced once at end
  int qp[4];
  #pragma unroll
  for (int j = 0; j < 4; ++j) qp[j] = qt * 64 + w * 16 + kh * 4 + j;

  const int g2 = tid >> 3, cc = tid & 7;
  const int srow2 = g2 * 2;
  const u16* kg0 = qkv + (bbase + srow2) * QW + 512 + h * 64 + cc * 8;
  const size_t tilestep = (size_t)64 * QW;

  u16x8 ka, kb2, va, vb;
  {
    const u16* p = kg0 + (size_t)kt0 * tilestep;
    ka  = *reinterpret_cast<const u16x8*>(p);
    kb2 = *reinterpret_cast<const u16x8*>(p + QW);
    va  = *reinterpret_cast<const u16x8*>(p + 512);
    vb  = *reinterpret_cast<const u16x8*>(p + QW + 512);
  }

  for (int kt = kt0; kt < kt1; ++kt) {
    __syncthreads();
    {
      *reinterpret_cast<u16x8*>(&Kb[srow2][cc * 8])     = ka;
      *reinterpret_cast<u16x8*>(&Kb[srow2 + 1][cc * 8]) = kb2;
      const int sw = srow2 ^ (cc * 8);
      #pragma unroll
      for (int i = 0; i < 8; ++i) {
        uint32_t pk = (uint32_t)va[i] | ((uint32_t)vb[i] << 16);
        *reinterpret_cast<uint32_t*>(&Vt[cc * 8 + i][sw]) = pk;
      }
    }
    __syncthreads();
    if (kt + 1 < kt1) {
      const u16* p = kg0 + (size_t)(kt + 1) * tilestep;
      ka  = *reinterpret_cast<const u16x8*>(p);
      kb2 = *reinterpret_cast<const u16x8*>(p + QW);
      va  = *reinterpret_cast<const u16x8*>(p + 512);
      vb  = *reinterpret_cast<const u16x8*>(p + QW + 512);
    }

    // ---- QK^T ----
    f32x4 s_acc[4] = {};
    #pragma unroll
    for (int nb = 0; nb < 4; ++nb) {
      #pragma unroll
      for (int kk = 0; kk < 2; ++kk) {
        s16x8 bk = *reinterpret_cast<const s16x8*>(&Kb[nb * 16 + c][kk * 32 + kh * 8]);
        s_acc[nb] = __builtin_amdgcn_mfma_f32_16x16x32_bf16(aq[kk], bk, s_acc[nb], 0, 0, 0);
      }
    }

    // ---- softmax (base-2 domain, deferred l-reduce) ----
    const bool diag = (kt == qt);
    float p[4][4];
    float tm[4] = { -INFINITY, -INFINITY, -INFINITY, -INFINITY };
    #pragma unroll
    for (int nb = 0; nb < 4; ++nb) {
      #pragma unroll
      for (int j = 0; j < 4; ++j) {
        float sv = s_acc[nb][j] * TS;
        if (diag && (kt * 64 + nb * 16 + c) > qp[j]) sv = -INFINITY;
        p[nb][j] = sv;
        tm[j] = fmaxf(tm[j], sv);
      }
    }
    #pragma unroll
    for (int o = 1; o < 16; o <<= 1) {
      #pragma unroll
      for (int j = 0; j < 4; ++j) tm[j] = fmaxf(tm[j], __shfl_xor(tm[j], o));
    }
    #pragma unroll
    for (int j = 0; j < 4; ++j) {
      const float mnew = fmaxf(mrow[j], tm[j]);
      const float corr = exp2f(mrow[j] - mnew);
      mrow[j] = mnew;
      float ps = 0.f;
      #pragma unroll
      for (int nb = 0; nb < 4; ++nb) {
        p[nb][j] = exp2f(p[nb][j] - mnew);
        ps += p[nb][j];
      }
      lrow[j] = lrow[j] * corr + ps;
      #pragma unroll
      for (int nb2 = 0; nb2 < 4; ++nb2) o_acc[nb2][j] *= corr;
    }

    #pragma unroll
    for (int nb = 0; nb < 4; ++nb)
      #pragma unroll
      for (int j = 0; j < 4; ++j)
        Pw[w][kh * 4 + j][nb * 16 + c] = f2bf(p[nb][j]);

    // ---- PV ----
    #pragma unroll
    for (int kk = 0; kk < 2; ++kk) {
      s16x8 ap = *reinterpret_cast<const s16x8*>(&Pw[w][c][kk * 32 + kh * 8]);
      #pragma unroll
      for (int nb2 = 0; nb2 < 4; ++nb2) {
        const int dh = nb2 * 16 + c;
        const int f8 = ((dh >> 3) & 7) * 8;
        s16x8 bv = *reinterpret_cast<const s16x8*>(&Vt[dh][(kk * 32 + kh * 8) ^ f8]);
        o_acc[nb2] = __builtin_amdgcn_mfma_f32_16x16x32_bf16(ap, bv, o_acc[nb2], 0, 0, 0);
      }
    }
  }

  // final l reduce across the 16 lanes of each row group
  #pragma unroll
  for (int o = 1; o < 16; o <<= 1) {
    #pragma unroll
    for (int j = 0; j < 4; ++j) lrow[j] += __shfl_xor(lrow[j], o);
  }

  if (ns == 1) {
    float invl[4];
    #pragma unroll
    for (int j = 0; j < 4; ++j) invl[j] = 1.0f / lrow[j];
    #pragma unroll
    for (int nb2 = 0; nb2 < 4; ++nb2)
      #pragma unroll
      for (int j = 0; j < 4; ++j) {
        const int qrow = qt * 64 + w * 16 + kh * 4 + j;
        outb[(bbase + qrow) * Dm + h * 64 + nb2 * 16 + c] = f2bf(o_acc[nb2][j] * invl[j]);
      }
  } else {
    const size_t pid = (size_t)(b * 8 + h) * 72 + (id - 8);
    float* op = opart + pid * 4096;
    #pragma unroll
    for (int nb2 = 0; nb2 < 4; ++nb2)
      #pragma unroll
      for (int j = 0; j < 4; ++j)
        op[(w * 16 + kh * 4 + j) * 64 + nb2 * 16 + c] = o_acc[nb2][j];
    if (c == 0) {
      #pragma unroll
      for (int j = 0; j < 4; ++j) {
        ml[pid * 128 + w * 16 + kh * 4 + j]      = mrow[j];
        ml[pid * 128 + 64 + w * 16 + kh * 4 + j] = lrow[j];
      }
    }
  }
}

// ---------------------------------------------------------------------------
// Flash split merge (base-2 m's): O = sum_s 2^{m_s-M} O_s / sum_s 2^{m_s-M} l_s
// ---------------------------------------------------------------------------
__global__ __launch_bounds__(256) void attn_combine_kernel(
    const float* __restrict__ opart, const float* __restrict__ ml,
    u16* __restrict__ outb) {
  const int qt = 8 + (int)blockIdx.x;
  const int h = blockIdx.y, b = blockIdx.z;
  int ns, idb;
  if (qt < 16)      { ns = 2; idb = (qt - 8) * 2; }
  else if (qt < 24) { ns = 3; idb = 16 + (qt - 16) * 3; }
  else              { ns = 4; idb = 40 + (qt - 24) * 4; }
  const int r  = threadIdx.x >> 2;
  const int d0 = (threadIdx.x & 3) * 16;
  const size_t pidb = (size_t)(b * 8 + h) * 72 + idb;

  float M = -INFINITY;
  for (int s2 = 0; s2 < ns; ++s2)
    M = fmaxf(M, ml[(pidb + s2) * 128 + r]);
  float L = 0.f;
  f32x4 o0 = {}, o1 = {}, o2 = {}, o3 = {};
  for (int s2 = 0; s2 < ns; ++s2) {
    const size_t pp = pidb + s2;
    const float wgt = exp2f(ml[pp * 128 + r] - M);
    L += wgt * ml[pp * 128 + 64 + r];
    const float* op = opart + pp * 4096 + (size_t)r * 64 + d0;
    f32x4 a0 = *reinterpret_cast<const f32x4*>(op);
    f32x4 a1 = *reinterpret_cast<const f32x4*>(op + 4);
    f32x4 a2 = *reinterpret_cast<const f32x4*>(op + 8);
    f32x4 a3 = *reinterpret_cast<const f32x4*>(op + 12);
    #pragma unroll
    for (int i = 0; i < 4; ++i) {
      o0[i] += wgt * a0[i]; o1[i] += wgt * a1[i];
      o2[i] += wgt * a2[i]; o3[i] += wgt * a3[i];
    }
  }
  const float invL = 1.0f / L;
  u16* dst = outb + ((size_t)b * Sq + qt * 64 + r) * Dm + h * 64 + d0;
  u16x4 w0 = { f2bf(o0[0]*invL), f2bf(o0[1]*invL), f2bf(o0[2]*invL), f2bf(o0[3]*invL) };
  u16x4 w1 = { f2bf(o1[0]*invL), f2bf(o1[1]*invL), f2bf(o1[2]*invL), f2bf(o1[3]*invL) };
  u16x4 w2 = { f2bf(o2[0]*invL), f2bf(o2[1]*invL), f2bf(o2[2]*invL), f2bf(o2[3]*invL) };
  u16x4 w3 = { f2bf(o3[0]*invL), f2bf(o3[1]*invL), f2bf(o3[2]*invL), f2bf(o3[3]*invL) };
  *reinterpret_cast<u16x4*>(dst)      = w0;
  *reinterpret_cast<u16x4*>(dst + 4)  = w1;
  *reinterpret_cast<u16x4*>(dst + 8)  = w2;
  *reinterpret_cast<u16x4*>(dst + 12) = w3;
}

// ---------------------------------------------------------------------------
// Local window-2 attention, reads local section (cols 1536..3071) of merged qkv.
// ---------------------------------------------------------------------------
__global__ __launch_bounds__(256) void attn_local_kernel(
    const u16* __restrict__ qkv, u16* __restrict__ outb) {
  const int unit = blockIdx.x * 4 + (threadIdx.x >> 6);  // (pair<<3)|h
  const int lane = threadIdx.x & 63;
  const int h = unit & 7;
  const size_t pair = (size_t)(unit >> 3);
  const u16* r0 = qkv + pair * 2 * QW + 1536;
  const u16* r1 = r0 + QW;
  const int off = h * 64 + lane;
  const float q0 = b2f(r0[off]), k0 = b2f(r0[512 + off]), v0 = b2f(r0[1024 + off]);
  const float q1 = b2f(r1[off]), k1 = b2f(r1[512 + off]), v1 = b2f(r1[1024 + off]);
  float s00 = q0 * k0, s01 = q0 * k1, s10 = q1 * k0, s11 = q1 * k1;
  #pragma unroll
  for (int o = 1; o < 64; o <<= 1) {
    s00 += __shfl_xor(s00, o); s01 += __shfl_xor(s01, o);
    s10 += __shfl_xor(s10, o); s11 += __shfl_xor(s11, o);
  }
  s00 *= 0.125f; s01 *= 0.125f; s10 *= 0.125f; s11 *= 0.125f;
  const float m0 = fmaxf(s00, s01), m1 = fmaxf(s10, s11);
  const float e00 = expf(s00 - m0), e01 = expf(s01 - m0);
  const float e10 = expf(s10 - m1), e11 = expf(s11 - m1);
  const float w0 = 1.0f / (e00 + e01), w1 = 1.0f / (e10 + e11);
  outb[pair * 2 * Dm + off]       = f2bf((e00 * v0 + e01 * v1) * w0);
  outb[(pair * 2 + 1) * Dm + off] = f2bf((e10 * v0 + e11 * v1) * w1);
}

// ---------------------------------------------------------------------------
extern "C" void kernel_launch(void* const* d_in, const int* in_sizes, int n_in,
                              void* d_out, int out_size, void* d_ws, size_t ws_size,
                              hipStream_t stream) {
  const float* x      = (const float*)d_in[0];
  const float* ln1_g  = (const float*)d_in[1];
  const float* ln1_b  = (const float*)d_in[2];
  const float* ln2_g  = (const float*)d_in[3];
  const float* ln2_b  = (const float*)d_in[4];
  const float* ln3_g  = (const float*)d_in[5];
  const float* ln3_b  = (const float*)d_in[6];
  const float* gw_in  = (const float*)d_in[7];
  const float* gb_in  = (const float*)d_in[8];
  const float* gw_out = (const float*)d_in[9];
  const float* gb_out = (const float*)d_in[10];
  const float* lw_in  = (const float*)d_in[11];
  const float* lb_in  = (const float*)d_in[12];
  const float* lw_out = (const float*)d_in[13];
  const float* lb_out = (const float*)d_in[14];
  const float* gate_w = (const float*)d_in[15];
  const float* gate_b = (const float*)d_in[16];
  const float* ff_w1  = (const float*)d_in[17];
  const float* ff_b1  = (const float*)d_in[18];
  const float* ff_w2  = (const float*)d_in[19];
  const float* ff_b2  = (const float*)d_in[20];
  float* out = (float*)d_out;
  char* wsb  = (char*)d_ws;

  // workspace layout (bytes), peak 126.35 MB; overlays are liveness-disjoint:
  u16*   xnb   = (u16*)(wsb + 0);             //  8.39 MB
  u16*   qkvb  = (u16*)(wsb + 8388608);       // 50.33 MB merged [8192][3072]
  u16*   ff1b  = qkvb;                        // 33.55 MB (qkv dead after attn)
  float* h2b   = (float*)(wsb + 41943040);    // 16.78 MB (tail of qkv region)
  u16*   attgb = (u16*)(wsb + 58720256);      //  8.39 MB
  u16*   attlb = (u16*)(wsb + 67108864);      //  8.39 MB
  u16*   wb    = (u16*)(wsb + 75497472);      //  8.91 MB weights
  float* opart = (float*)(wsb + 84410368);    // 37.75 MB (dead after combine)
  float* ml    = (float*)(wsb + 122159104);   //  1.18 MB
  float* x2    = (float*)(wsb + 84410368);    // 16.78 MB (overlays opart)
  float* h2a   = (float*)(wsb + 101187584);   // 16.78 MB (overlays opart tail)

  // 0. weights -> bf16
  wconv_kernel<<<(W_TOTAL / 4 + 255) / 256, 256, 0, stream>>>(
      gw_in, lw_in, gw_out, lw_out, gate_w, ff_w1, ff_w2, wb);
  // 1. x_norm = LN1(x)
  ln_kernel<true><<<Mrows, 128, 0, stream>>>(x, nullptr, nullptr, ln1_g, ln1_b, xnb);
  // 2. merged qkv (global | local), N=3072, dual bias
  mfma_gemm<0, true><<<dim3(QW / 128, Mrows / 128), 256, 0, stream>>>(
      xnb, wb, gb_in, lb_in, 1536, qkvb, QW, 512);
  // 3. local window-2 attention
  attn_local_kernel<<<(Mrows / 2) * 8 / 4, 256, 0, stream>>>(qkvb, attlb);
  // 4. global causal attention (split-K flash) + merge
  attn_global_kernel<<<dim3(80, 8, Bc), 256, 0, stream>>>(qkvb, attgb, opart, ml);
  attn_combine_kernel<<<dim3(24, 8, Bc), 256, 0, stream>>>(opart, ml, attgb);
  // 5. fused gate/pg/pl/combine: x2 = x + g*pg + (1-g)*pl
  fuse3_kernel<<<dim3(512 / 128, Mrows / 128), 256, 0, stream>>>(
      xnb, attgb, attlb, wb + W_GATE, wb + W_GWOUT, wb + W_LWOUT,
      gate_b, gb_out, lb_out, x, x2);
  // 6. h_norm = LN2(x2)
  ln_kernel<true><<<Mrows, 128, 0, stream>>>(x2, nullptr, nullptr, ln2_g, ln2_b, xnb);
  // 7. ff1 = gelu(hn @ ff_w1^T)
  mfma_gemm<2, true><<<dim3(2048 / 128, Mrows / 128), 256, 0, stream>>>(
      xnb, wb + W_FF1, ff_b1, nullptr, 0, ff1b, 2048, 512);
  // 8. h2a/h2b = split-K halves of ff1 @ ff_w2^T
  mfma_gemm_sk<<<dim3(512 / 128, Mrows / 128, 2), 256, 0, stream>>>(
      ff1b, wb + W_FF2, ff_b2, h2a, h2b, 512, 2048);
  // 9. out = LN3(x2 + h2a + h2b)
  ln_kernel<false><<<Mrows, 128, 0, stream>>>(x2, h2a, h2b, ln3_g, ln3_b, out);
}

// Round 10
// 278.570 us; speedup vs baseline: 8.5831x; 1.0058x over previous
//
#include <hip/hip_runtime.h>
#include <math.h>
#include <stdint.h>

typedef unsigned short u16;
typedef __attribute__((ext_vector_type(4))) unsigned short u16x4;
typedef __attribute__((ext_vector_type(8))) unsigned short u16x8;
typedef __attribute__((ext_vector_type(8))) short s16x8;   // 8 bf16 = 4 VGPR (MFMA frag)
typedef __attribute__((ext_vector_type(4))) float f32x4;   // MFMA acc

// Problem constants
constexpr int Bc = 4;
constexpr int Sq = 2048;
constexpr int Dm = 512;
constexpr int Mrows = Bc * Sq;   // 8192

__device__ inline float b2f(u16 h) {
  union { uint32_t u; float f; } x; x.u = (uint32_t)h << 16; return x.f;
}
__device__ inline u16 f2bf(float f) {  // round-to-nearest-even
  union { float f; uint32_t u; } x; x.f = f;
  uint32_t r = (x.u + 0x7fffu + ((x.u >> 16) & 1u)) >> 16;
  return (u16)r;
}

// ---------------------------------------------------------------------------
// Weight fp32->bf16 conversion
// ---------------------------------------------------------------------------
constexpr size_t W_GWIN  = 0;         // 1536x512   (merged QKV rows 0..1535)
constexpr size_t W_LWIN  = 786432;    // 1536x512   (merged QKV rows 1536..3071)
constexpr size_t W_GWOUT = 1572864;   // 512x512
constexpr size_t W_LWOUT = 1835008;   // 512x512
constexpr size_t W_GATE  = 2097152;   // 512x512
constexpr size_t W_FF1   = 2359296;   // 2048x512
constexpr size_t W_FF2   = 3407872;   // 512x2048
constexpr size_t W_TOTAL = 4456448;

__global__ __launch_bounds__(256) void wconv_kernel(
    const float* __restrict__ gw_in, const float* __restrict__ lw_in,
    const float* __restrict__ gw_out, const float* __restrict__ lw_out,
    const float* __restrict__ gate_w, const float* __restrict__ ff_w1,
    const float* __restrict__ ff_w2, u16* __restrict__ dst) {
  size_t idx = ((size_t)blockIdx.x * 256 + threadIdx.x) * 4;
  if (idx >= W_TOTAL) return;
  const float* src; size_t base;
  if      (idx < W_LWIN)  { src = gw_in;  base = W_GWIN;  }
  else if (idx < W_GWOUT) { src = lw_in;  base = W_LWIN;  }
  else if (idx < W_LWOUT) { src = gw_out; base = W_GWOUT; }
  else if (idx < W_GATE)  { src = lw_out; base = W_LWOUT; }
  else if (idx < W_FF1)   { src = gate_w; base = W_GATE;  }
  else if (idx < W_FF2)   { src = ff_w1;  base = W_FF1;   }
  else                    { src = ff_w2;  base = W_FF2;   }
  float4 v = *reinterpret_cast<const float4*>(src + (idx - base));
  u16x4 o = { f2bf(v.x), f2bf(v.y), f2bf(v.z), f2bf(v.w) };
  *reinterpret_cast<u16x4*>(dst + idx) = o;
}

// ---------------------------------------------------------------------------
// LayerNorm (optional fused residual adds). OB: write bf16 (else fp32).
// ---------------------------------------------------------------------------
template <bool OB>
__global__ __launch_bounds__(128) void ln_kernel(
    const float* __restrict__ in, const float* __restrict__ add,
    const float* __restrict__ add2,
    const float* __restrict__ g, const float* __restrict__ b,
    void* __restrict__ outp) {
  const int row = blockIdx.x;
  const int t = threadIdx.x;
  float4 v = reinterpret_cast<const float4*>(in + (size_t)row * Dm)[t];
  if (add != nullptr) {
    float4 a = reinterpret_cast<const float4*>(add + (size_t)row * Dm)[t];
    v.x += a.x; v.y += a.y; v.z += a.z; v.w += a.w;
  }
  if (add2 != nullptr) {
    float4 a = reinterpret_cast<const float4*>(add2 + (size_t)row * Dm)[t];
    v.x += a.x; v.y += a.y; v.z += a.z; v.w += a.w;
  }
  float s  = v.x + v.y + v.z + v.w;
  float s2 = v.x*v.x + v.y*v.y + v.z*v.z + v.w*v.w;
  #pragma unroll
  for (int o = 32; o > 0; o >>= 1) {
    s  += __shfl_down(s, o);
    s2 += __shfl_down(s2, o);
  }
  __shared__ float rs[2], rs2[2];
  if ((t & 63) == 0) { rs[t >> 6] = s; rs2[t >> 6] = s2; }
  __syncthreads();
  const float mean = (rs[0] + rs[1]) * (1.0f / Dm);
  const float var  = (rs2[0] + rs2[1]) * (1.0f / Dm) - mean * mean;
  const float rstd = rsqrtf(var + 1e-5f);
  float4 gv = reinterpret_cast<const float4*>(g)[t];
  float4 bv = reinterpret_cast<const float4*>(b)[t];
  float ox = (v.x - mean) * rstd * gv.x + bv.x;
  float oy = (v.y - mean) * rstd * gv.y + bv.y;
  float oz = (v.z - mean) * rstd * gv.z + bv.z;
  float ow = (v.w - mean) * rstd * gv.w + bv.w;
  if (OB) {
    u16x4 o4 = { f2bf(ox), f2bf(oy), f2bf(oz), f2bf(ow) };
    *reinterpret_cast<u16x4*>((u16*)outp + (size_t)row * Dm + t * 4) = o4;
  } else {
    float4 o4; o4.x = ox; o4.y = oy; o4.z = oz; o4.w = ow;
    reinterpret_cast<float4*>((float*)outp + (size_t)row * Dm)[t] = o4;
  }
}

// ---------------------------------------------------------------------------
// MFMA GEMM (HW-validated): C = act(A @ W^T + bias)
// Dual-bias: bias2 != nullptr -> col >= bsplit uses bias2[col-bsplit].
// SPLITQ: write halves to Cout/Cout2, each row width bsplit.
// ---------------------------------------------------------------------------
template <int ACT, bool OUT_BF16, bool SPLITQ>
__global__ __launch_bounds__(256) void mfma_gemm(
    const u16* __restrict__ A, const u16* __restrict__ W,
    const float* __restrict__ bias, const float* __restrict__ bias2, int bsplit,
    void* __restrict__ Cout, void* __restrict__ Cout2, int N, int K) {
  __shared__ u16 sA[128 * 32];
  __shared__ u16 sW[128 * 32];
  const int tid  = threadIdx.x;
  const int wid  = tid >> 6, lane = tid & 63;
  const int lr   = lane & 15, kh = lane >> 4;
  const int wm   = wid >> 1, wn = wid & 1;
  const int m0   = blockIdx.y * 128, n0 = blockIdx.x * 128;
  const int row0 = tid >> 2,        ko0 = (tid & 3) * 8;
  const int row1 = (256 + tid) >> 2, ko1 = (tid & 3) * 8;

  f32x4 acc[4][4] = {};
  for (int k0 = 0; k0 < K; k0 += 32) {
    __syncthreads();
    __builtin_amdgcn_global_load_lds(
        (const __attribute__((address_space(1))) void*)(A + (size_t)(m0 + row0) * K + k0 + ko0),
        (__attribute__((address_space(3))) void*)(sA + wid * 512), 16, 0, 0);
    __builtin_amdgcn_global_load_lds(
        (const __attribute__((address_space(1))) void*)(A + (size_t)(m0 + row1) * K + k0 + ko1),
        (__attribute__((address_space(3))) void*)(sA + 2048 + wid * 512), 16, 0, 0);
    __builtin_amdgcn_global_load_lds(
        (const __attribute__((address_space(1))) void*)(W + (size_t)(n0 + row0) * K + k0 + ko0),
        (__attribute__((address_space(3))) void*)(sW + wid * 512), 16, 0, 0);
    __builtin_amdgcn_global_load_lds(
        (const __attribute__((address_space(1))) void*)(W + (size_t)(n0 + row1) * K + k0 + ko1),
        (__attribute__((address_space(3))) void*)(sW + 2048 + wid * 512), 16, 0, 0);
    __syncthreads();
    s16x8 af[4], bf[4];
    #pragma unroll
    for (int mf = 0; mf < 4; ++mf)
      af[mf] = *reinterpret_cast<const s16x8*>(&sA[(wm * 64 + mf * 16 + lr) * 32 + kh * 8]);
    #pragma unroll
    for (int nf = 0; nf < 4; ++nf)
      bf[nf] = *reinterpret_cast<const s16x8*>(&sW[(wn * 64 + nf * 16 + lr) * 32 + kh * 8]);
    #pragma unroll
    for (int mf = 0; mf < 4; ++mf)
      #pragma unroll
      for (int nf = 0; nf < 4; ++nf)
        acc[mf][nf] = __builtin_amdgcn_mfma_f32_16x16x32_bf16(af[mf], bf[nf], acc[mf][nf], 0, 0, 0);
  }
  #pragma unroll
  for (int nf = 0; nf < 4; ++nf) {
    const int col = n0 + wn * 64 + nf * 16 + lr;
    const float bv = (bias2 != nullptr && col >= bsplit) ? bias2[col - bsplit] : bias[col];
    #pragma unroll
    for (int mf = 0; mf < 4; ++mf) {
      #pragma unroll
      for (int j = 0; j < 4; ++j) {
        const int rowg = m0 + wm * 64 + mf * 16 + kh * 4 + j;
        float v = acc[mf][nf][j] + bv;
        if (ACT == 1) v = 1.0f / (1.0f + expf(-v));
        else if (ACT == 2) v = 0.5f * v * (1.0f + erff(v * 0.70710678118654752440f));
        if (SPLITQ) {
          u16* dst = (col < bsplit) ? (u16*)Cout : (u16*)Cout2;
          const int cc = (col < bsplit) ? col : col - bsplit;
          dst[(size_t)rowg * bsplit + cc] = f2bf(v);
        } else if (OUT_BF16) {
          ((u16*)Cout)[(size_t)rowg * N + col] = f2bf(v);
        } else {
          ((float*)Cout)[(size_t)rowg * N + col] = v;
        }
      }
    }
  }
}

// ---------------------------------------------------------------------------
// Split-K MFMA GEMM for FFN2: z = blockIdx.z selects K-half and output buffer.
// ---------------------------------------------------------------------------
__global__ __launch_bounds__(256) void mfma_gemm_sk(
    const u16* __restrict__ A, const u16* __restrict__ W,
    const float* __restrict__ bias, float* __restrict__ C0, float* __restrict__ C1,
    int N, int Kt) {
  __shared__ u16 sA[128 * 32];
  __shared__ u16 sW[128 * 32];
  const int tid  = threadIdx.x;
  const int wid  = tid >> 6, lane = tid & 63;
  const int lr   = lane & 15, kh = lane >> 4;
  const int wm   = wid >> 1, wn = wid & 1;
  const int m0   = blockIdx.y * 128, n0 = blockIdx.x * 128;
  const int z    = blockIdx.z;
  const int kbeg = z * (Kt / 2), kend = kbeg + (Kt / 2);
  const int row0 = tid >> 2,        ko0 = (tid & 3) * 8;
  const int row1 = (256 + tid) >> 2, ko1 = (tid & 3) * 8;

  f32x4 acc[4][4] = {};
  for (int k0 = kbeg; k0 < kend; k0 += 32) {
    __syncthreads();
    __builtin_amdgcn_global_load_lds(
        (const __attribute__((address_space(1))) void*)(A + (size_t)(m0 + row0) * Kt + k0 + ko0),
        (__attribute__((address_space(3))) void*)(sA + wid * 512), 16, 0, 0);
    __builtin_amdgcn_global_load_lds(
        (const __attribute__((address_space(1))) void*)(A + (size_t)(m0 + row1) * Kt + k0 + ko1),
        (__attribute__((address_space(3))) void*)(sA + 2048 + wid * 512), 16, 0, 0);
    __builtin_amdgcn_global_load_lds(
        (const __attribute__((address_space(1))) void*)(W + (size_t)(n0 + row0) * Kt + k0 + ko0),
        (__attribute__((address_space(3))) void*)(sW + wid * 512), 16, 0, 0);
    __builtin_amdgcn_global_load_lds(
        (const __attribute__((address_space(1))) void*)(W + (size_t)(n0 + row1) * Kt + k0 + ko1),
        (__attribute__((address_space(3))) void*)(sW + 2048 + wid * 512), 16, 0, 0);
    __syncthreads();
    s16x8 af[4], bf[4];
    #pragma unroll
    for (int mf = 0; mf < 4; ++mf)
      af[mf] = *reinterpret_cast<const s16x8*>(&sA[(wm * 64 + mf * 16 + lr) * 32 + kh * 8]);
    #pragma unroll
    for (int nf = 0; nf < 4; ++nf)
      bf[nf] = *reinterpret_cast<const s16x8*>(&sW[(wn * 64 + nf * 16 + lr) * 32 + kh * 8]);
    #pragma unroll
    for (int mf = 0; mf < 4; ++mf)
      #pragma unroll
      for (int nf = 0; nf < 4; ++nf)
        acc[mf][nf] = __builtin_amdgcn_mfma_f32_16x16x32_bf16(af[mf], bf[nf], acc[mf][nf], 0, 0, 0);
  }
  float* C = z ? C1 : C0;
  #pragma unroll
  for (int nf = 0; nf < 4; ++nf) {
    const int col = n0 + wn * 64 + nf * 16 + lr;
    const float bv = z ? 0.0f : bias[col];
    #pragma unroll
    for (int mf = 0; mf < 4; ++mf) {
      #pragma unroll
      for (int j = 0; j < 4; ++j) {
        const int rowg = m0 + wm * 64 + mf * 16 + kh * 4 + j;
        C[(size_t)rowg * N + col] = acc[mf][nf][j] + bv;
      }
    }
  }
}

// ---------------------------------------------------------------------------
// fuse1: pg GEMM + combine epilogue.
// x2 = x + g*(attg@Wgo^T+bgo) + (1-g)*pl, with g/pl read as bf16.
// ---------------------------------------------------------------------------
__global__ __launch_bounds__(256) void fuse1_kernel(
    const u16* __restrict__ A, const u16* __restrict__ W,
    const float* __restrict__ bgo,
    const u16* __restrict__ gateb, const u16* __restrict__ plb,
    const float* __restrict__ x, float* __restrict__ x2) {
  constexpr int N = 512, K = 512;
  __shared__ u16 sA[128 * 32];
  __shared__ u16 sW[128 * 32];
  const int tid  = threadIdx.x;
  const int wid  = tid >> 6, lane = tid & 63;
  const int lr   = lane & 15, kh = lane >> 4;
  const int wm   = wid >> 1, wn = wid & 1;
  const int m0   = blockIdx.y * 128, n0 = blockIdx.x * 128;
  const int row0 = tid >> 2,        ko0 = (tid & 3) * 8;
  const int row1 = (256 + tid) >> 2, ko1 = (tid & 3) * 8;

  f32x4 acc[4][4] = {};
  for (int k0 = 0; k0 < K; k0 += 32) {
    __syncthreads();
    __builtin_amdgcn_global_load_lds(
        (const __attribute__((address_space(1))) void*)(A + (size_t)(m0 + row0) * K + k0 + ko0),
        (__attribute__((address_space(3))) void*)(sA + wid * 512), 16, 0, 0);
    __builtin_amdgcn_global_load_lds(
        (const __attribute__((address_space(1))) void*)(A + (size_t)(m0 + row1) * K + k0 + ko1),
        (__attribute__((address_space(3))) void*)(sA + 2048 + wid * 512), 16, 0, 0);
    __builtin_amdgcn_global_load_lds(
        (const __attribute__((address_space(1))) void*)(W + (size_t)(n0 + row0) * K + k0 + ko0),
        (__attribute__((address_space(3))) void*)(sW + wid * 512), 16, 0, 0);
    __builtin_amdgcn_global_load_lds(
        (const __attribute__((address_space(1))) void*)(W + (size_t)(n0 + row1) * K + k0 + ko1),
        (__attribute__((address_space(3))) void*)(sW + 2048 + wid * 512), 16, 0, 0);
    __syncthreads();
    s16x8 af[4], bf[4];
    #pragma unroll
    for (int mf = 0; mf < 4; ++mf)
      af[mf] = *reinterpret_cast<const s16x8*>(&sA[(wm * 64 + mf * 16 + lr) * 32 + kh * 8]);
    #pragma unroll
    for (int nf = 0; nf < 4; ++nf)
      bf[nf] = *reinterpret_cast<const s16x8*>(&sW[(wn * 64 + nf * 16 + lr) * 32 + kh * 8]);
    #pragma unroll
    for (int mf = 0; mf < 4; ++mf)
      #pragma unroll
      for (int nf = 0; nf < 4; ++nf)
        acc[mf][nf] = __builtin_amdgcn_mfma_f32_16x16x32_bf16(af[mf], bf[nf], acc[mf][nf], 0, 0, 0);
  }
  #pragma unroll
  for (int nf = 0; nf < 4; ++nf) {
    const int col = n0 + wn * 64 + nf * 16 + lr;
    const float bv = bgo[col];
    #pragma unroll
    for (int mf = 0; mf < 4; ++mf) {
      #pragma unroll
      for (int j = 0; j < 4; ++j) {
        const int rowg = m0 + wm * 64 + mf * 16 + kh * 4 + j;
        const size_t off = (size_t)rowg * N + col;
        const float pg = acc[mf][nf][j] + bv;
        const float g  = b2f(gateb[off]);
        const float pl = b2f(plb[off]);
        x2[off] = x[off] + g * pg + (1.0f - g) * pl;
      }
    }
  }
}

// ---------------------------------------------------------------------------
// FAT attn dispatch: ids 0..79 = split-K flash attention (heavy-first);
// ids 80..87 = gate GEMM blocks; ids 88..95 = pl GEMM blocks (tail-fill).
// qkvg bf16 [Mrows][1536] (q|k|v per 512). launch_bounds(256,5) pins VGPR<=102
// so attn occupancy (5 blocks/CU, LDS-capped) is preserved.
// ---------------------------------------------------------------------------
__global__ __launch_bounds__(256, 5) void attn_fat_kernel(
    const u16* __restrict__ qkv, u16* __restrict__ outb,
    float* __restrict__ opart, float* __restrict__ ml,
    const u16* __restrict__ xnb, const u16* __restrict__ attlb,
    const u16* __restrict__ Wg, const u16* __restrict__ Wlo,
    const float* __restrict__ bg, const float* __restrict__ blo,
    u16* __restrict__ gateb, u16* __restrict__ plb) {
  __shared__ u16 Kb[64][72];
  __shared__ u16 Vt[64][72];
  __shared__ u16 Pw[4][16][72];

  const int bx = blockIdx.x;
  const int h  = blockIdx.y;
  const int b  = blockIdx.z;
  const int tid = threadIdx.x;

  if (bx >= 80) {
    // ---------------- embedded 128x128 GEMM (gate or pl), N=512, K=512 ----
    const bool isGate = bx < 88;
    const int lin = (bx - (isGate ? 80 : 88)) * 32 + h * 4 + b;   // 0..255
    const int n0 = (lin >> 6) * 128;
    const int m0 = (lin & 63) * 128;
    const u16* A = isGate ? xnb : attlb;
    const u16* W = isGate ? Wg : Wlo;
    const float* bias = isGate ? bg : blo;
    u16* Cout = isGate ? gateb : plb;
    u16* sA = &Kb[0][0];   // 9216 B >= 8192 needed
    u16* sW = &Vt[0][0];
    constexpr int K = 512;
    const int wid = tid >> 6, lane = tid & 63;
    const int lr = lane & 15, kh = lane >> 4;
    const int wm = wid >> 1, wn = wid & 1;
    const int row0 = tid >> 2,        ko0 = (tid & 3) * 8;
    const int row1 = (256 + tid) >> 2, ko1 = (tid & 3) * 8;
    f32x4 acc[4][4] = {};
    for (int k0 = 0; k0 < K; k0 += 32) {
      __syncthreads();
      __builtin_amdgcn_global_load_lds(
          (const __attribute__((address_space(1))) void*)(A + (size_t)(m0 + row0) * K + k0 + ko0),
          (__attribute__((address_space(3))) void*)(sA + wid * 512), 16, 0, 0);
      __builtin_amdgcn_global_load_lds(
          (const __attribute__((address_space(1))) void*)(A + (size_t)(m0 + row1) * K + k0 + ko1),
          (__attribute__((address_space(3))) void*)(sA + 2048 + wid * 512), 16, 0, 0);
      __builtin_amdgcn_global_load_lds(
          (const __attribute__((address_space(1))) void*)(W + (size_t)(n0 + row0) * K + k0 + ko0),
          (__attribute__((address_space(3))) void*)(sW + wid * 512), 16, 0, 0);
      __builtin_amdgcn_global_load_lds(
          (const __attribute__((address_space(1))) void*)(W + (size_t)(n0 + row1) * K + k0 + ko1),
          (__attribute__((address_space(3))) void*)(sW + 2048 + wid * 512), 16, 0, 0);
      __syncthreads();
      s16x8 af[4], bf[4];
      #pragma unroll
      for (int mf = 0; mf < 4; ++mf)
        af[mf] = *reinterpret_cast<const s16x8*>(&sA[(wm * 64 + mf * 16 + lr) * 32 + kh * 8]);
      #pragma unroll
      for (int nf = 0; nf < 4; ++nf)
        bf[nf] = *reinterpret_cast<const s16x8*>(&sW[(wn * 64 + nf * 16 + lr) * 32 + kh * 8]);
      #pragma unroll
      for (int mf = 0; mf < 4; ++mf)
        #pragma unroll
        for (int nf = 0; nf < 4; ++nf)
          acc[mf][nf] = __builtin_amdgcn_mfma_f32_16x16x32_bf16(af[mf], bf[nf], acc[mf][nf], 0, 0, 0);
    }
    #pragma unroll
    for (int nf = 0; nf < 4; ++nf) {
      const int col = n0 + wn * 64 + nf * 16 + lr;
      const float bv = bias[col];
      #pragma unroll
      for (int mf = 0; mf < 4; ++mf) {
        #pragma unroll
        for (int j = 0; j < 4; ++j) {
          const int rowg = m0 + wm * 64 + mf * 16 + kh * 4 + j;
          float v = acc[mf][nf][j] + bv;
          if (isGate) v = 1.0f / (1.0f + __expf(-v));
          Cout[(size_t)rowg * 512 + col] = f2bf(v);
        }
      }
    }
    return;
  }

  // ---------------- split-K flash attention -------------------------------
  const int id = 79 - bx;   // heavy splits first
  int qt, s, ns;
  if (id < 8)       { qt = id;                s = 0;            ns = 1; }
  else if (id < 24) { int t = id - 8;  qt = 8 + (t >> 1);  s = t & 1;  ns = 2; }
  else if (id < 48) { int t = id - 24; int q3 = t / 3; qt = 16 + q3; s = t - q3 * 3; ns = 3; }
  else              { int t = id - 48; qt = 24 + (t >> 2); s = t & 3;  ns = 4; }
  const int kt0 = s * 8;
  const int kt1 = min(kt0 + 8, qt + 1);

  const int w = tid >> 6, lane = tid & 63;
  const int c = lane & 15, kh = lane >> 4;
  constexpr float TS = 0.125f * 1.44269504088896f;   // scale * log2(e)

  const size_t bbase = (size_t)b * Sq;

  s16x8 aq[2];
  {
    const u16* qg = qkv + (bbase + qt * 64 + w * 16 + c) * 1536 + h * 64 + kh * 8;
    aq[0] = *reinterpret_cast<const s16x8*>(qg);
    aq[1] = *reinterpret_cast<const s16x8*>(qg + 32);
  }

  f32x4 o_acc[4] = {};
  float mrow[4] = { -INFINITY, -INFINITY, -INFINITY, -INFINITY };
  float lrow[4] = { 0.f, 0.f, 0.f, 0.f };   // lane-partial; reduced once at end
  const int qbase = qt * 64 + w * 16 + kh * 4;   // qp[j] = qbase + j

  const int g2 = tid >> 3, cc = tid & 7;
  const int srow2 = g2 * 2;
  const u16* kg0 = qkv + (bbase + srow2) * 1536 + 512 + h * 64 + cc * 8;
  const size_t tilestep = (size_t)64 * 1536;

  u16x8 ka, kb2, va, vb;
  {
    const u16* p = kg0 + (size_t)kt0 * tilestep;
    ka  = *reinterpret_cast<const u16x8*>(p);
    kb2 = *reinterpret_cast<const u16x8*>(p + 1536);
    va  = *reinterpret_cast<const u16x8*>(p + 512);
    vb  = *reinterpret_cast<const u16x8*>(p + 1536 + 512);
  }

  for (int kt = kt0; kt < kt1; ++kt) {
    __syncthreads();
    {
      *reinterpret_cast<u16x8*>(&Kb[srow2][cc * 8])     = ka;
      *reinterpret_cast<u16x8*>(&Kb[srow2 + 1][cc * 8]) = kb2;
      const int sw = srow2 ^ (cc * 8);
      #pragma unroll
      for (int i = 0; i < 8; ++i) {
        uint32_t pk = (uint32_t)va[i] | ((uint32_t)vb[i] << 16);
        *reinterpret_cast<uint32_t*>(&Vt[cc * 8 + i][sw]) = pk;
      }
    }
    __syncthreads();
    if (kt + 1 < kt1) {
      const u16* p = kg0 + (size_t)(kt + 1) * tilestep;
      ka  = *reinterpret_cast<const u16x8*>(p);
      kb2 = *reinterpret_cast<const u16x8*>(p + 1536);
      va  = *reinterpret_cast<const u16x8*>(p + 512);
      vb  = *reinterpret_cast<const u16x8*>(p + 1536 + 512);
    }

    // ---- QK^T ----
    f32x4 s_acc[4] = {};
    #pragma unroll
    for (int nb = 0; nb < 4; ++nb) {
      #pragma unroll
      for (int kk = 0; kk < 2; ++kk) {
        s16x8 bk = *reinterpret_cast<const s16x8*>(&Kb[nb * 16 + c][kk * 32 + kh * 8]);
        s_acc[nb] = __builtin_amdgcn_mfma_f32_16x16x32_bf16(aq[kk], bk, s_acc[nb], 0, 0, 0);
      }
    }

    // ---- softmax (base-2 domain); diagonal masking in a uniform branch ----
    float p[4][4];
    #pragma unroll
    for (int nb = 0; nb < 4; ++nb)
      #pragma unroll
      for (int j = 0; j < 4; ++j)
        p[nb][j] = s_acc[nb][j] * TS;
    if (kt == qt) {   // uniform: only the diagonal tile pays for masks
      #pragma unroll
      for (int nb = 0; nb < 4; ++nb) {
        const int kp = kt * 64 + nb * 16 + c;
        #pragma unroll
        for (int j = 0; j < 4; ++j)
          if (kp > qbase + j) p[nb][j] = -INFINITY;
      }
    }
    float tm[4];
    #pragma unroll
    for (int j = 0; j < 4; ++j)
      tm[j] = fmaxf(fmaxf(p[0][j], p[1][j]), fmaxf(p[2][j], p[3][j]));
    #pragma unroll
    for (int o = 1; o < 16; o <<= 1) {
      #pragma unroll
      for (int j = 0; j < 4; ++j) tm[j] = fmaxf(tm[j], __shfl_xor(tm[j], o));
    }
    #pragma unroll
    for (int j = 0; j < 4; ++j) {
      const float mnew = fmaxf(mrow[j], tm[j]);
      const float corr = exp2f(mrow[j] - mnew);
      mrow[j] = mnew;
      float ps = 0.f;
      #pragma unroll
      for (int nb = 0; nb < 4; ++nb) {
        p[nb][j] = exp2f(p[nb][j] - mnew);
        ps += p[nb][j];
      }
      lrow[j] = lrow[j] * corr + ps;
      #pragma unroll
      for (int nb2 = 0; nb2 < 4; ++nb2) o_acc[nb2][j] *= corr;
    }

    // P -> bf16 by truncation (P in [0,1]; rel err <= 2^-8)
    #pragma unroll
    for (int nb = 0; nb < 4; ++nb)
      #pragma unroll
      for (int j = 0; j < 4; ++j)
        Pw[w][kh * 4 + j][nb * 16 + c] = (u16)(__float_as_uint(p[nb][j]) >> 16);

    // ---- PV ----
    #pragma unroll
    for (int kk = 0; kk < 2; ++kk) {
      s16x8 ap = *reinterpret_cast<const s16x8*>(&Pw[w][c][kk * 32 + kh * 8]);
      #pragma unroll
      for (int nb2 = 0; nb2 < 4; ++nb2) {
        const int dh = nb2 * 16 + c;
        const int f8 = ((dh >> 3) & 7) * 8;
        s16x8 bv = *reinterpret_cast<const s16x8*>(&Vt[dh][(kk * 32 + kh * 8) ^ f8]);
        o_acc[nb2] = __builtin_amdgcn_mfma_f32_16x16x32_bf16(ap, bv, o_acc[nb2], 0, 0, 0);
      }
    }
  }

  // final l reduce across the 16 lanes of each row group
  #pragma unroll
  for (int o = 1; o < 16; o <<= 1) {
    #pragma unroll
    for (int j = 0; j < 4; ++j) lrow[j] += __shfl_xor(lrow[j], o);
  }

  if (ns == 1) {
    float invl[4];
    #pragma unroll
    for (int j = 0; j < 4; ++j) invl[j] = 1.0f / lrow[j];
    #pragma unroll
    for (int nb2 = 0; nb2 < 4; ++nb2)
      #pragma unroll
      for (int j = 0; j < 4; ++j) {
        const int qrow = qt * 64 + w * 16 + kh * 4 + j;
        outb[(bbase + qrow) * Dm + h * 64 + nb2 * 16 + c] = f2bf(o_acc[nb2][j] * invl[j]);
      }
  } else {
    const size_t pid = (size_t)(b * 8 + h) * 72 + (id - 8);
    float* op = opart + pid * 4096;
    #pragma unroll
    for (int nb2 = 0; nb2 < 4; ++nb2)
      #pragma unroll
      for (int j = 0; j < 4; ++j)
        op[(w * 16 + kh * 4 + j) * 64 + nb2 * 16 + c] = o_acc[nb2][j];
    if (c == 0) {
      #pragma unroll
      for (int j = 0; j < 4; ++j) {
        ml[pid * 128 + w * 16 + kh * 4 + j]      = mrow[j];
        ml[pid * 128 + 64 + w * 16 + kh * 4 + j] = lrow[j];
      }
    }
  }
}

// ---------------------------------------------------------------------------
// Flash split merge (base-2 m's): O = sum_s 2^{m_s-M} O_s / sum_s 2^{m_s-M} l_s
// ---------------------------------------------------------------------------
__global__ __launch_bounds__(256) void attn_combine_kernel(
    const float* __restrict__ opart, const float* __restrict__ ml,
    u16* __restrict__ outb) {
  const int qt = 8 + (int)blockIdx.x;
  const int h = blockIdx.y, b = blockIdx.z;
  int ns, idb;
  if (qt < 16)      { ns = 2; idb = (qt - 8) * 2; }
  else if (qt < 24) { ns = 3; idb = 16 + (qt - 16) * 3; }
  else              { ns = 4; idb = 40 + (qt - 24) * 4; }
  const int r  = threadIdx.x >> 2;
  const int d0 = (threadIdx.x & 3) * 16;
  const size_t pidb = (size_t)(b * 8 + h) * 72 + idb;

  float M = -INFINITY;
  for (int s2 = 0; s2 < ns; ++s2)
    M = fmaxf(M, ml[(pidb + s2) * 128 + r]);
  float L = 0.f;
  f32x4 o0 = {}, o1 = {}, o2 = {}, o3 = {};
  for (int s2 = 0; s2 < ns; ++s2) {
    const size_t pp = pidb + s2;
    const float wgt = exp2f(ml[pp * 128 + r] - M);
    L += wgt * ml[pp * 128 + 64 + r];
    const float* op = opart + pp * 4096 + (size_t)r * 64 + d0;
    f32x4 a0 = *reinterpret_cast<const f32x4*>(op);
    f32x4 a1 = *reinterpret_cast<const f32x4*>(op + 4);
    f32x4 a2 = *reinterpret_cast<const f32x4*>(op + 8);
    f32x4 a3 = *reinterpret_cast<const f32x4*>(op + 12);
    #pragma unroll
    for (int i = 0; i < 4; ++i) {
      o0[i] += wgt * a0[i]; o1[i] += wgt * a1[i];
      o2[i] += wgt * a2[i]; o3[i] += wgt * a3[i];
    }
  }
  const float invL = 1.0f / L;
  u16* dst = outb + ((size_t)b * Sq + qt * 64 + r) * Dm + h * 64 + d0;
  u16x4 w0 = { f2bf(o0[0]*invL), f2bf(o0[1]*invL), f2bf(o0[2]*invL), f2bf(o0[3]*invL) };
  u16x4 w1 = { f2bf(o1[0]*invL), f2bf(o1[1]*invL), f2bf(o1[2]*invL), f2bf(o1[3]*invL) };
  u16x4 w2 = { f2bf(o2[0]*invL), f2bf(o2[1]*invL), f2bf(o2[2]*invL), f2bf(o2[3]*invL) };
  u16x4 w3 = { f2bf(o3[0]*invL), f2bf(o3[1]*invL), f2bf(o3[2]*invL), f2bf(o3[3]*invL) };
  *reinterpret_cast<u16x4*>(dst)      = w0;
  *reinterpret_cast<u16x4*>(dst + 4)  = w1;
  *reinterpret_cast<u16x4*>(dst + 8)  = w2;
  *reinterpret_cast<u16x4*>(dst + 12) = w3;
}

// ---------------------------------------------------------------------------
// Local window-2 attention (reads qkvl [Mrows][1536]).
// ---------------------------------------------------------------------------
__global__ __launch_bounds__(256) void attn_local_kernel(
    const u16* __restrict__ qkvl, u16* __restrict__ outb) {
  const int unit = blockIdx.x * 4 + (threadIdx.x >> 6);  // (pair<<3)|h
  const int lane = threadIdx.x & 63;
  const int h = unit & 7;
  const size_t pair = (size_t)(unit >> 3);
  const u16* r0 = qkvl + pair * 2 * 1536;
  const u16* r1 = r0 + 1536;
  const int off = h * 64 + lane;
  const float q0 = b2f(r0[off]), k0 = b2f(r0[512 + off]), v0 = b2f(r0[1024 + off]);
  const float q1 = b2f(r1[off]), k1 = b2f(r1[512 + off]), v1 = b2f(r1[1024 + off]);
  float s00 = q0 * k0, s01 = q0 * k1, s10 = q1 * k0, s11 = q1 * k1;
  #pragma unroll
  for (int o = 1; o < 64; o <<= 1) {
    s00 += __shfl_xor(s00, o); s01 += __shfl_xor(s01, o);
    s10 += __shfl_xor(s10, o); s11 += __shfl_xor(s11, o);
  }
  s00 *= 0.125f; s01 *= 0.125f; s10 *= 0.125f; s11 *= 0.125f;
  const float m0 = fmaxf(s00, s01), m1 = fmaxf(s10, s11);
  const float e00 = expf(s00 - m0), e01 = expf(s01 - m0);
  const float e10 = expf(s10 - m1), e11 = expf(s11 - m1);
  const float w0 = 1.0f / (e00 + e01), w1 = 1.0f / (e10 + e11);
  outb[pair * 2 * Dm + off]       = f2bf((e00 * v0 + e01 * v1) * w0);
  outb[(pair * 2 + 1) * Dm + off] = f2bf((e10 * v0 + e11 * v1) * w1);
}

// ---------------------------------------------------------------------------
extern "C" void kernel_launch(void* const* d_in, const int* in_sizes, int n_in,
                              void* d_out, int out_size, void* d_ws, size_t ws_size,
                              hipStream_t stream) {
  const float* x      = (const float*)d_in[0];
  const float* ln1_g  = (const float*)d_in[1];
  const float* ln1_b  = (const float*)d_in[2];
  const float* ln2_g  = (const float*)d_in[3];
  const float* ln2_b  = (const float*)d_in[4];
  const float* ln3_g  = (const float*)d_in[5];
  const float* ln3_b  = (const float*)d_in[6];
  const float* gw_in  = (const float*)d_in[7];
  const float* gb_in  = (const float*)d_in[8];
  const float* gw_out = (const float*)d_in[9];
  const float* gb_out = (const float*)d_in[10];
  const float* lw_in  = (const float*)d_in[11];
  const float* lb_in  = (const float*)d_in[12];
  const float* lw_out = (const float*)d_in[13];
  const float* lb_out = (const float*)d_in[14];
  const float* gate_w = (const float*)d_in[15];
  const float* gate_b = (const float*)d_in[16];
  const float* ff_w1  = (const float*)d_in[17];
  const float* ff_b1  = (const float*)d_in[18];
  const float* ff_w2  = (const float*)d_in[19];
  const float* ff_b2  = (const float*)d_in[20];
  float* out = (float*)d_out;
  char* wsb  = (char*)d_ws;

  // workspace layout (bytes), peak 123.3 MB <= 134.2 proven budget.
  // overlays are liveness-disjoint (noted inline).
  u16*   xnb   = (u16*)(wsb + 0);             //  8.39 MB
  u16*   qkvg  = (u16*)(wsb + 8388608);       // 25.17 MB [8192][1536] global qkv
  u16*   qkvl  = (u16*)(wsb + 33554432);      // 25.17 MB local qkv (dead after attn_local)
  u16*   gateb = (u16*)(wsb + 33554432);      //  8.39 MB bf16 (overlays dead qkvl)
  u16*   plb   = (u16*)(wsb + 41943040);      //  8.39 MB bf16 (overlays dead qkvl)
  u16*   attgb = (u16*)(wsb + 58720256);      //  8.39 MB
  u16*   attlb = (u16*)(wsb + 67108864);      //  8.39 MB
  u16*   wb    = (u16*)(wsb + 75497472);      //  8.91 MB weights
  float* opart = (float*)(wsb + 84410368);    // 37.75 MB (dead after combine)
  float* ml    = (float*)(wsb + 122159104);   //  1.18 MB
  float* x2    = (float*)(wsb + 84410368);    // 16.78 MB (overlays dead opart)
  float* h2a   = (float*)(wsb + 101187584);   // 16.78 MB (overlays dead opart)
  float* h2b   = (float*)(wsb + 41943040);    // 16.78 MB (overlays dead plb+spare)
  u16*   ff1b  = (u16*)(wsb + 8388608);       // 33.55 MB (overlays dead qkvg+gateb)

  // 0. weights -> bf16
  wconv_kernel<<<(W_TOTAL / 4 + 255) / 256, 256, 0, stream>>>(
      gw_in, lw_in, gw_out, lw_out, gate_w, ff_w1, ff_w2, wb);
  // 1. x_norm = LN1(x)
  ln_kernel<true><<<Mrows, 128, 0, stream>>>(x, nullptr, nullptr, ln1_g, ln1_b, xnb);
  // 2. merged qkv GEMM, split outputs (global | local), dual bias
  mfma_gemm<0, true, true><<<dim3(3072 / 128, Mrows / 128), 256, 0, stream>>>(
      xnb, wb, gb_in, lb_in, 1536, qkvg, qkvl, 3072, 512);
  // 3. local window-2 attention
  attn_local_kernel<<<(Mrows / 2) * 8 / 4, 256, 0, stream>>>(qkvl, attlb);
  // 4. FAT dispatch: split-K flash attn + gate GEMM + pl GEMM (tail-fill)
  attn_fat_kernel<<<dim3(96, 8, Bc), 256, 0, stream>>>(
      qkvg, attgb, opart, ml, xnb, attlb,
      wb + W_GATE, wb + W_LWOUT, gate_b, lb_out, gateb, plb);
  attn_combine_kernel<<<dim3(24, 8, Bc), 256, 0, stream>>>(opart, ml, attgb);
  // 5. fuse1: x2 = x + g*(attg@Wgo^T+bgo) + (1-g)*pl
  fuse1_kernel<<<dim3(512 / 128, Mrows / 128), 256, 0, stream>>>(
      attgb, wb + W_GWOUT, gb_out, gateb, plb, x, x2);
  // 6. h_norm = LN2(x2)
  ln_kernel<true><<<Mrows, 128, 0, stream>>>(x2, nullptr, nullptr, ln2_g, ln2_b, xnb);
  // 7. ff1 = gelu(hn @ ff_w1^T)
  mfma_gemm<2, true, false><<<dim3(2048 / 128, Mrows / 128), 256, 0, stream>>>(
      xnb, wb + W_FF1, ff_b1, nullptr, 0, ff1b, nullptr, 2048, 512);
  // 8. h2a/h2b = split-K halves of ff1 @ ff_w2^T
  mfma_gemm_sk<<<dim3(512 / 128, Mrows / 128, 2), 256, 0, stream>>>(
      ff1b, wb + W_FF2, ff_b2, h2a, h2b, 512, 2048);
  // 9. out = LN3(x2 + h2a + h2b)
  ln_kernel<false><<<Mrows, 128, 0, stream>>>(x2, h2a, h2b, ln3_g, ln3_b, out);
}